// Round 7
// baseline (21684.000 us; speedup 1.0000x reference)
//
#include <hip/hip_runtime.h>
#include <math.h>

#define DI __device__ __forceinline__

// ---- problem constants ----
#define BB 32
#define SEQ 512
#define KF 101
#define EE 128
#define HH 8
#define EHH 1024
#define LL 3
#define ADIM 200
#define NTOK (BB*SEQ)   // 16384
#define CB 8            // batches per chunk
#define NCHUNK (BB/CB)  // 4
#define CTOK (CB*SEQ)   // 4096 tokens per chunk

// R6 post-mortem: interface confirmed (sizes/dtype/ws sentinels passed).
// ROOT CAUSE of R1/R4/R6 failures: Qb/Kb/Vb allocated NTOK*EE (8MB) but
// indexed as (B,H,SEQ,E) = NTOK*EHH (64MB) -> 56MB OOB writes corrupting
// neighboring ws buffers; corruption pattern tracked each round's layout.
// Fix: batch-chunked qkv scratch (token-major, no scatter), correct sizes.
//   out==99999 -> input-order/shape model wrong
//   out==12345 -> ws_size too small (~110MB needed; R6 proved >=135MB ok)

// =================== sentinel ===================
__global__ void sentinel_k(float* out, float v, int n){
  int i = blockIdx.x*64 + threadIdx.x;
  if (i < n) out[i] = v;
}

// =================== embed ===================
__global__ __launch_bounds__(128) void embed_k(
    const float* __restrict__ str_fea, const int* __restrict__ comp_fea,
    const float* __restrict__ atom_table, const float* __restrict__ comp_W,
    const float* __restrict__ comp_b, const float* __restrict__ pdd_W,
    const float* __restrict__ pdd_b,
    float* __restrict__ x, float* __restrict__ x_init, float* __restrict__ w)
{
  const int t = blockIdx.x;
  const int e = threadIdx.x;
  __shared__ float sAtom[ADIM];
  __shared__ float sStr[104];
  const int idx = comp_fea[t];
  for (int a=e;a<ADIM;a+=128) sAtom[a] = atom_table[idx*ADIM+a];
  for (int a=e;a<KF;a+=128)  sStr[a]  = str_fea[(size_t)t*KF+a];
  __syncthreads();
  float acc = comp_b[e] + pdd_b[e];
  #pragma unroll 4
  for (int a=0;a<ADIM;a++) acc = fmaf(sAtom[a], comp_W[a*EE+e], acc);
  #pragma unroll 4
  for (int j=0;j<KF-1;j++) acc = fmaf(sStr[1+j], pdd_W[j*EE+e], acc);
  x[(size_t)t*EE+e] = acc;
  x_init[(size_t)t*EE+e] = acc;
  if (e==0) w[t] = sStr[0];
}

// =================== layernorm (E=128), optional add ===================
__global__ __launch_bounds__(128) void ln_k(
    const float* __restrict__ in, const float* __restrict__ add,
    const float* __restrict__ g, const float* __restrict__ bta,
    float* __restrict__ out)
{
  const int t = blockIdx.x;
  const int e = threadIdx.x;
  __shared__ float red[128];
  float v = in[(size_t)t*EE+e];
  if (add) v += add[(size_t)t*EE+e];
  red[e] = v; __syncthreads();
  for (int s=64;s>0;s>>=1){ if (e<s) red[e]+=red[e+s]; __syncthreads(); }
  const float mean = red[0]*(1.0f/128.0f);
  __syncthreads();
  const float d = v-mean;
  red[e] = d*d; __syncthreads();
  for (int s=64;s>0;s>>=1){ if (e<s) red[e]+=red[e+s]; __syncthreads(); }
  const float var = red[0]*(1.0f/128.0f);
  out[(size_t)t*EE+e] = d*rsqrtf(var+1e-5f)*g[e] + bta[e];
}

// =================== naive GEMM: one thread per output element ===================
// A: Mrows x Kk (row-major, local). B: Kk x Nn (row-major).
// EPI 1: C[m*Nn+n] = acc                       (qkv chunk, local rows)
// EPI 2: C[(m0+m)*Nn+n] = acc + resid[(m0+m)*Nn+n]   (global rows)
// EPI 3: C[m*Nn+n] = mish(acc)
template<int EPI>
__global__ __launch_bounds__(256) void ngemm_k(
    const float* __restrict__ A, const float* __restrict__ B,
    const float* __restrict__ bias, const float* __restrict__ resid,
    float* __restrict__ C, int Mrows, int Nn, int Kk, int m0)
{
  const long long idx = (long long)blockIdx.x*256 + threadIdx.x;
  if (idx >= (long long)Mrows*Nn) return;
  const int m = (int)(idx / Nn);
  const int n = (int)(idx - (long long)m*Nn);
  const float* a = A + (size_t)m*Kk;
  const float* b = B + n;
  float acc = 0.f;
  #pragma unroll 8
  for (int k=0;k<Kk;k++) acc = fmaf(a[k], b[(size_t)k*Nn], acc);
  acc += bias[n];
  if constexpr (EPI==1){
    C[(size_t)m*Nn+n] = acc;
  } else if constexpr (EPI==2){
    const size_t gi = (size_t)(m0+m)*Nn + n;
    C[gi] = acc + resid[gi];
  } else {
    const float sp = (acc>20.f)?acc:log1pf(expf(acc));
    C[(size_t)m*Nn+n] = acc*tanhf(sp);
  }
}

// =================== fused projection precompute: fw = o_W @ out_W ; fb = o_b@out_W + out_b ===================
// exact algebra: x + (vals@o_W + o_b)@out_W + out_b == x + vals@fw + fb
__global__ __launch_bounds__(256) void fuse_w_k(
    const float* __restrict__ oW, const float* __restrict__ outW, float* __restrict__ fw)
{
  const int idx = blockIdx.x*256 + threadIdx.x;   // EHH*EE = 131072
  if (idx >= EHH*EE) return;
  const int k1 = idx >> 7, n = idx & 127;
  float acc = 0.f;
  #pragma unroll 8
  for (int k2=0;k2<EHH;k2++) acc = fmaf(oW[(size_t)k1*EHH+k2], outW[(size_t)k2*EE+n], acc);
  fw[(size_t)k1*EE+n] = acc;
}
__global__ __launch_bounds__(128) void fuse_b_k(
    const float* __restrict__ ob, const float* __restrict__ outW,
    const float* __restrict__ outb, float* __restrict__ fb)
{
  const int n = threadIdx.x;
  float acc = outb[n];
  for (int k2=0;k2<EHH;k2++) acc = fmaf(ob[k2], outW[(size_t)k2*EE+n], acc);
  fb[n] = acc;
}

// =================== naive attention over a batch chunk ===================
// qkvc: (CTOK, 3072) token-major; token t_local=bl*SEQ+n, col h*384 + {0:q,128:k,256:v} + d.
// One wave per (q-row, h, b_local). Exact reference softmax semantics.
__global__ __launch_bounds__(64) void attn_c_k(
    const float* __restrict__ qkvc, const float* __restrict__ w,
    float* __restrict__ vals_c, int b0)
{
  const int q  = blockIdx.x;    // 0..511
  const int h  = blockIdx.y;    // 0..7
  const int bl = blockIdx.z;    // 0..CB-1
  const int bg = b0 + bl;
  const int lane = threadIdx.x;
  __shared__ float p_sh[SEQ];

  const size_t rowstride = 3072;
  const float* base = qkvc + (size_t)bl*SEQ*rowstride + h*384;
  const float qw = w[bg*SEQ+q];
  const bool keepq = qw > 0.f;
  const float scale = 0.08838834764831845f;   // 1/sqrt(128)

  const float* qrow = base + (size_t)q*rowstride;        // q at +0
  float s[8];
  #pragma unroll
  for (int j=0;j<8;j++){
    const int k = lane + 64*j;
    const float* krow = base + (size_t)k*rowstride + 128; // k at +128
    float acc = 0.f;
    #pragma unroll 8
    for (int d=0;d<EE;d++) acc = fmaf(qrow[d], krow[d], acc);
    const float kw = w[bg*SEQ+k];
    s[j] = (keepq && kw > 0.f) ? acc*scale : -9.0e15f;
  }
  float m = s[0];
  #pragma unroll
  for (int j=1;j<8;j++) m = fmaxf(m, s[j]);
  #pragma unroll
  for (int off=32;off;off>>=1) m = fmaxf(m, __shfl_xor(m, off));
  float lsum = 0.f;
  #pragma unroll
  for (int j=0;j<8;j++){
    const int k = lane + 64*j;
    const float e = w[bg*SEQ+k]*expf(s[j]-m);
    p_sh[k] = e; lsum += e;
  }
  #pragma unroll
  for (int off=32;off;off>>=1) lsum += __shfl_xor(lsum, off);
  __syncthreads();
  const float inv = 1.0f/lsum;
  float o0=0.f, o1=0.f;
  for (int k=0;k<SEQ;k++){
    const float p = p_sh[k];
    const float* vrow = base + (size_t)k*rowstride + 256; // v at +256
    o0 = fmaf(p, vrow[lane],    o0);
    o1 = fmaf(p, vrow[lane+64], o1);
  }
  float* orow = vals_c + ((size_t)(bl*SEQ+q))*EHH + h*EE;
  orow[lane]    = o0*inv;
  orow[lane+64] = o1*inv;
}

// =================== pool + LN + head ===================
__global__ __launch_bounds__(128) void pool_head_k(
    const float* __restrict__ x, const float* __restrict__ x_init,
    const float* __restrict__ w, const float* __restrict__ g2, const float* __restrict__ b2,
    const float* __restrict__ head_W, const float* __restrict__ head_b,
    float* __restrict__ out)
{
  const int b = blockIdx.x;
  const int e = threadIdx.x;
  __shared__ float red[128];
  float acc = 0.f;
  for (int n=0;n<SEQ;n++){
    const size_t idx = ((size_t)(b*SEQ+n))*EE + e;
    acc = fmaf(w[b*SEQ+n], x[idx]+x_init[idx], acc);
  }
  red[e]=acc; __syncthreads();
  for (int s=64;s>0;s>>=1){ if(e<s) red[e]+=red[e+s]; __syncthreads(); }
  const float mean = red[0]*(1.0f/128.0f);
  __syncthreads();
  const float d = acc-mean;
  red[e]=d*d; __syncthreads();
  for (int s=64;s>0;s>>=1){ if(e<s) red[e]+=red[e+s]; __syncthreads(); }
  const float var = red[0]*(1.0f/128.0f);
  const float p = d*rsqrtf(var+1e-5f)*g2[e]+b2[e];
  __syncthreads();
  red[e] = p*head_W[e]; __syncthreads();
  for (int s=64;s>0;s>>=1){ if(e<s) red[e]+=red[e+s]; __syncthreads(); }
  if (e==0) out[b] = red[0] + head_b[0];
}

// =================== launch ===================
extern "C" void kernel_launch(void* const* d_in, const int* in_sizes, int n_in,
                              void* d_out, int out_size, void* d_ws, size_t ws_size,
                              hipStream_t stream)
{
  const float* str_fea   = (const float*)d_in[0];
  const int*   comp_fea  = (const int*)  d_in[1];
  // d_in[2] cell_fea unused by reference
  const float* atom_table= (const float*)d_in[3];
  const float* comp_W    = (const float*)d_in[4];
  const float* comp_b    = (const float*)d_in[5];
  const float* pdd_W     = (const float*)d_in[6];
  const float* pdd_b     = (const float*)d_in[7];
  const float* enc_ln_g  = (const float*)d_in[8];
  const float* enc_ln_b  = (const float*)d_in[9];
  const float* qkv_W     = (const float*)d_in[10];
  const float* qkv_b     = (const float*)d_in[11];
  const float* o_W       = (const float*)d_in[12];
  const float* o_b       = (const float*)d_in[13];
  const float* out_W     = (const float*)d_in[14];
  const float* out_b     = (const float*)d_in[15];
  const float* ffn_W     = (const float*)d_in[16];
  const float* ffn_b     = (const float*)d_in[17];
  const float* ln2_g     = (const float*)d_in[18];
  const float* ln2_b     = (const float*)d_in[19];
  const float* head_W    = (const float*)d_in[20];
  const float* head_b    = (const float*)d_in[21];
  float* out = (float*)d_out;

  // ---- diagnostic 1: input layout model ----
  bool sizes_ok = (n_in >= 22);
  if (sizes_ok){
    sizes_ok = in_sizes[0]==BB*SEQ*KF && in_sizes[1]==NTOK &&
               in_sizes[3]==119*ADIM  && in_sizes[4]==ADIM*EE &&
               in_sizes[10]==LL*EE*3*EHH && in_sizes[12]==LL*EHH*EHH &&
               in_sizes[14]==LL*EHH*EE   && in_sizes[16]==LL*EE*EE &&
               in_sizes[20]==EE;
  }
  if (!sizes_ok){
    sentinel_k<<<(out_size+63)/64,64,0,stream>>>(out, 99999.0f, out_size);
    return;
  }

  // ---- workspace layout (~110 MB; R6 proved ws_size >= ~135 MB) ----
  char* p = (char*)d_ws;
  size_t off = 0;
  auto alloc = [&](size_t bytes)->void*{
    off = (off + 255) & ~(size_t)255;
    void* r = p + off; off += bytes; return r;
  };
  float* w      = (float*)alloc((size_t)NTOK*4);
  float* x      = (float*)alloc((size_t)NTOK*EE*4);
  float* x_init = (float*)alloc((size_t)NTOK*EE*4);
  float* xn     = (float*)alloc((size_t)NTOK*EE*4);
  float* out1   = (float*)alloc((size_t)NTOK*EE*4);
  float* out2   = (float*)alloc((size_t)NTOK*EE*4);
  float* qkvc   = (float*)alloc((size_t)CTOK*3*EHH*4);   // 50.3 MB chunk
  float* vals_c = (float*)alloc((size_t)CTOK*EHH*4);     // 16.8 MB chunk
  float* fw     = (float*)alloc((size_t)EHH*EE*4);
  float* fb     = (float*)alloc((size_t)EE*4);

  // ---- diagnostic 2: workspace size ----
  if (off > ws_size){
    sentinel_k<<<(out_size+63)/64,64,0,stream>>>(out, 12345.0f, out_size);
    return;
  }

  embed_k<<<NTOK,128,0,stream>>>(str_fea, comp_fea, atom_table, comp_W, comp_b,
                                 pdd_W, pdd_b, x, x_init, w);
  for (int i=0;i<LL;i++){
    const float* gi = enc_ln_g + i*EE;
    const float* bi = enc_ln_b + i*EE;
    ln_k<<<NTOK,128,0,stream>>>(x, nullptr, gi, bi, xn);
    fuse_w_k<<<(EHH*EE+255)/256,256,0,stream>>>(
        o_W + (size_t)i*EHH*EHH, out_W + (size_t)i*EHH*EE, fw);
    fuse_b_k<<<1,128,0,stream>>>(
        o_b + (size_t)i*EHH, out_W + (size_t)i*EHH*EE, out_b + (size_t)i*EE, fb);
    for (int cb=0; cb<NCHUNK; cb++){
      const int t0 = cb*CTOK;
      const int b0 = cb*CB;
      {
        const long long tot = (long long)CTOK*3*EHH;
        ngemm_k<1><<<(int)((tot+255)/256),256,0,stream>>>(
            xn + (size_t)t0*EE, qkv_W + (size_t)i*EE*3*EHH,
            qkv_b + (size_t)i*3*EHH, nullptr, qkvc, CTOK, 3*EHH, EE, 0);
      }
      attn_c_k<<<dim3(SEQ,HH,CB),64,0,stream>>>(qkvc, w, vals_c, b0);
      {
        const long long tot = (long long)CTOK*EE;
        ngemm_k<2><<<(int)((tot+255)/256),256,0,stream>>>(
            vals_c, fw, fb, x, out1, CTOK, EE, EHH, t0);
      }
    }
    ln_k<<<NTOK,128,0,stream>>>(out1, nullptr, gi, bi, xn);
    {
      const long long tot = (long long)NTOK*EE;
      ngemm_k<3><<<(int)((tot+255)/256),256,0,stream>>>(
          xn, ffn_W + (size_t)i*EE*EE, ffn_b + (size_t)i*EE, nullptr,
          out2, NTOK, EE, EE, 0);
    }
    ln_k<<<NTOK,128,0,stream>>>(out1, out2, gi, bi, x);
  }
  pool_head_k<<<BB,128,0,stream>>>(x, x_init, w, ln2_g, ln2_b, head_W, head_b, out);
}

// Round 8
// 11290.431 us; speedup vs baseline: 1.9206x; 1.9206x over previous
//
#include <hip/hip_runtime.h>
#include <math.h>

#define DI __device__ __forceinline__

// ---- problem constants ----
#define BB 32
#define SEQ 512
#define KF 101
#define EE 128
#define HH 8
#define EHH 1024
#define LL 3
#define ADIM 200
#define NTOK (BB*SEQ)   // 16384
#define CB 8            // batches per chunk
#define NCHUNK (BB/CB)  // 4
#define CTOK (CB*SEQ)   // 4096 tokens per chunk

// R7: PASSED (absmax 0.0, 21.68 ms). Bottleneck: naive attention (16.6ms,
// VALUBusy 12%, latency-bound uncoalesced K reads). R8: flash attention with
// LDS-staged K/V tiles + tiled GEMMs. All-f32 compute preserved.

// =================== sentinel ===================
__global__ void sentinel_k(float* out, float v, int n){
  int i = blockIdx.x*64 + threadIdx.x;
  if (i < n) out[i] = v;
}

// =================== embed ===================
__global__ __launch_bounds__(128) void embed_k(
    const float* __restrict__ str_fea, const int* __restrict__ comp_fea,
    const float* __restrict__ atom_table, const float* __restrict__ comp_W,
    const float* __restrict__ comp_b, const float* __restrict__ pdd_W,
    const float* __restrict__ pdd_b,
    float* __restrict__ x, float* __restrict__ x_init, float* __restrict__ w)
{
  const int t = blockIdx.x;
  const int e = threadIdx.x;
  __shared__ float sAtom[ADIM];
  __shared__ float sStr[104];
  const int idx = comp_fea[t];
  for (int a=e;a<ADIM;a+=128) sAtom[a] = atom_table[idx*ADIM+a];
  for (int a=e;a<KF;a+=128)  sStr[a]  = str_fea[(size_t)t*KF+a];
  __syncthreads();
  float acc = comp_b[e] + pdd_b[e];
  #pragma unroll 4
  for (int a=0;a<ADIM;a++) acc = fmaf(sAtom[a], comp_W[a*EE+e], acc);
  #pragma unroll 4
  for (int j=0;j<KF-1;j++) acc = fmaf(sStr[1+j], pdd_W[j*EE+e], acc);
  x[(size_t)t*EE+e] = acc;
  x_init[(size_t)t*EE+e] = acc;
  if (e==0) w[t] = sStr[0];
}

// =================== layernorm (E=128), optional add ===================
__global__ __launch_bounds__(128) void ln_k(
    const float* __restrict__ in, const float* __restrict__ add,
    const float* __restrict__ g, const float* __restrict__ bta,
    float* __restrict__ out)
{
  const int t = blockIdx.x;
  const int e = threadIdx.x;
  __shared__ float red[128];
  float v = in[(size_t)t*EE+e];
  if (add) v += add[(size_t)t*EE+e];
  red[e] = v; __syncthreads();
  for (int s=64;s>0;s>>=1){ if (e<s) red[e]+=red[e+s]; __syncthreads(); }
  const float mean = red[0]*(1.0f/128.0f);
  __syncthreads();
  const float d = v-mean;
  red[e] = d*d; __syncthreads();
  for (int s=64;s>0;s>>=1){ if (e<s) red[e]+=red[e+s]; __syncthreads(); }
  const float var = red[0]*(1.0f/128.0f);
  out[(size_t)t*EE+e] = d*rsqrtf(var+1e-5f)*g[e] + bta[e];
}

// =================== tiled fp32 GEMM, templated epilogue ===================
// A: M x Kk row-major (M = grid.y*BM), B: Kk x Nn row-major.
// EPI 1: C[row*Nn+col] = acc+bias               (plain store, local rows)
// EPI 2: C[row*Nn+col] = acc+bias + resid[...]  (C/resid pre-offset by caller)
// EPI 3: C[row*Nn+col] = mish(acc+bias)
template<int EPI, int BM, int BN, int TM, int TN>
__global__ __launch_bounds__(256) void gemm_k(
    const float* __restrict__ A, const float* __restrict__ B,
    const float* __restrict__ bias, const float* __restrict__ resid,
    float* __restrict__ C, int Nn, int Kk)
{
  constexpr int BK = 16;
  __shared__ float As[BK][BM+4];
  __shared__ float Bs[BK][BN+4];
  const int m0 = blockIdx.y*BM, n0 = blockIdx.x*BN;
  const int tid = threadIdx.x;
  const int r0 = (tid>>4)*4, c0 = (tid&15)*4;
  float acc[TM][TN];
  #pragma unroll
  for (int i=0;i<TM;i++)
    #pragma unroll
    for (int j=0;j<TN;j++) acc[i][j]=0.f;

  constexpr int AI = BM/64;
  constexpr int BI = BN/64;

  for (int k0=0;k0<Kk;k0+=BK){
    float4 a_ld[AI]; float4 b_ld[BI];
    #pragma unroll
    for (int it=0; it<AI; it++){
      const int cid = it*256 + tid;
      const int am = cid>>2, ak = (cid&3)*4;
      a_ld[it] = *(const float4*)(A + (size_t)(m0+am)*Kk + k0 + ak);
    }
    #pragma unroll
    for (int it=0; it<BI; it++){
      const int cid = it*256 + tid;
      const int bk = cid/(BN/4), bn = (cid%(BN/4))*4;
      b_ld[it] = *(const float4*)(B + (size_t)(k0+bk)*Nn + n0 + bn);
    }
    __syncthreads();
    #pragma unroll
    for (int it=0; it<AI; it++){
      const int cid = it*256 + tid;
      const int am = cid>>2, ak = (cid&3)*4;
      As[ak+0][am]=a_ld[it].x; As[ak+1][am]=a_ld[it].y;
      As[ak+2][am]=a_ld[it].z; As[ak+3][am]=a_ld[it].w;
    }
    #pragma unroll
    for (int it=0; it<BI; it++){
      const int cid = it*256 + tid;
      const int bk = cid/(BN/4), bn = (cid%(BN/4))*4;
      *(float4*)&Bs[bk][bn] = b_ld[it];
    }
    __syncthreads();
    #pragma unroll
    for (int kk=0; kk<BK; kk++){
      float a[TM], bv[TN];
      #pragma unroll
      for (int hh=0; hh<TM/4; hh++){
        float4 f = *(const float4*)&As[kk][r0 + hh*(BM/2)];
        a[hh*4+0]=f.x; a[hh*4+1]=f.y; a[hh*4+2]=f.z; a[hh*4+3]=f.w;
      }
      #pragma unroll
      for (int hh=0; hh<TN/4; hh++){
        float4 f = *(const float4*)&Bs[kk][c0 + hh*(BN/2)];
        bv[hh*4+0]=f.x; bv[hh*4+1]=f.y; bv[hh*4+2]=f.z; bv[hh*4+3]=f.w;
      }
      #pragma unroll
      for (int i=0;i<TM;i++)
        #pragma unroll
        for (int j=0;j<TN;j++)
          acc[i][j] = fmaf(a[i], bv[j], acc[i][j]);
    }
    __syncthreads();
  }
  #pragma unroll
  for (int i=0;i<TM;i++){
    const int row = m0 + r0 + (i&3) + (i>>2)*(BM/2);
    #pragma unroll
    for (int j=0;j<TN;j++){
      const int col = n0 + c0 + (j&3) + (j>>2)*(BN/2);
      float v = acc[i][j] + bias[col];
      const size_t gi = (size_t)row*Nn + col;
      if constexpr (EPI==1){
        C[gi] = v;
      } else if constexpr (EPI==2){
        C[gi] = v + resid[gi];
      } else {
        const float sp = (v>20.f)?v:log1pf(expf(v));
        C[gi] = v*tanhf(sp);
      }
    }
  }
}

// =================== fused projection precompute ===================
__global__ __launch_bounds__(256) void fuse_w_k(
    const float* __restrict__ oW, const float* __restrict__ outW, float* __restrict__ fw)
{
  const int idx = blockIdx.x*256 + threadIdx.x;   // EHH*EE = 131072
  if (idx >= EHH*EE) return;
  const int k1 = idx >> 7, n = idx & 127;
  float acc = 0.f;
  #pragma unroll 8
  for (int k2=0;k2<EHH;k2++) acc = fmaf(oW[(size_t)k1*EHH+k2], outW[(size_t)k2*EE+n], acc);
  fw[(size_t)k1*EE+n] = acc;
}
__global__ __launch_bounds__(128) void fuse_b_k(
    const float* __restrict__ ob, const float* __restrict__ outW,
    const float* __restrict__ outb, float* __restrict__ fb)
{
  const int n = threadIdx.x;
  float acc = outb[n];
  for (int k2=0;k2<EHH;k2++) acc = fmaf(ob[k2], outW[(size_t)k2*EE+n], acc);
  fb[n] = acc;
}

// =================== flash attention over a batch chunk ===================
// qkvc: (CTOK, 3072) token-major; token bl*SEQ+n, col h*384 + {0:q,128:k,256:v}+d.
// Block = (q-tile 64, h, bl), 256 threads: tid = qi*4+pp; thread owns q-row qi,
// dims d = pp+4j (interleaved => conflict-free LDS broadcast reads).
// Online softmax state replicated across the 4 threads of a row.
__global__ __launch_bounds__(256) void attn_f_k(
    const float* __restrict__ qkvc, const float* __restrict__ w,
    float* __restrict__ vals_c, int b0)
{
  const int qt = blockIdx.x;   // 0..7
  const int h  = blockIdx.y;   // 0..7
  const int bl = blockIdx.z;   // 0..CB-1
  const int tid = threadIdx.x;
  const int qi = tid >> 2;     // 0..63
  const int pp = tid & 3;      // dim phase
  __shared__ float Ks[64][132];   // K tile, then V tile (reused)
  __shared__ float wt[64], qwt[64];
  const size_t rs = 3072;
  const float* base = qkvc + (size_t)bl*SEQ*rs + h*384;
  const int q0 = qt*64;

  float qreg[32];
  {
    const float* qrow = base + (size_t)(q0+qi)*rs;
    #pragma unroll
    for (int j=0;j<32;j++) qreg[j] = qrow[pp + 4*j];
  }
  if (tid < 64) qwt[tid] = w[(b0+bl)*SEQ + q0 + tid];
  __syncthreads();
  const bool keepq = qwt[qi] > 0.f;
  float oacc[32];
  #pragma unroll
  for (int j=0;j<32;j++) oacc[j]=0.f;
  float m = -INFINITY, l = 0.f;
  const float scale = 0.08838834764831845f;  // 1/sqrt(128)

  for (int kt=0; kt<8; kt++){
    __syncthreads();   // prior PV done reading Ks
    for (int fi=tid; fi<64*32; fi+=256){
      const int r = fi>>5, c4 = (fi&31)*4;
      *(float4*)&Ks[r][c4] = *(const float4*)(base + (size_t)(kt*64+r)*rs + 128 + c4);
    }
    if (tid<64) wt[tid] = w[(b0+bl)*SEQ + kt*64 + tid];
    __syncthreads();
    float s[64];
    #pragma unroll
    for (int k=0;k<64;k++){
      float part = 0.f;
      #pragma unroll
      for (int j=0;j<32;j++) part = fmaf(qreg[j], Ks[k][pp+4*j], part);
      part += __shfl_xor(part, 1, 4);
      part += __shfl_xor(part, 2, 4);
      s[k] = (keepq && wt[k]>0.f) ? part*scale : -9.0e15f;
    }
    float tm = s[0];
    #pragma unroll
    for (int k=1;k<64;k++) tm = fmaxf(tm, s[k]);
    const float newm = fmaxf(m, tm);
    const float alpha = expf(m - newm);
    float lsum = 0.f;
    #pragma unroll
    for (int k=0;k<64;k++){
      const float p = wt[k]*expf(s[k]-newm);
      s[k] = p; lsum += p;
    }
    l = l*alpha + lsum;
    m = newm;
    __syncthreads();   // everyone done reading K
    for (int fi=tid; fi<64*32; fi+=256){
      const int r = fi>>5, c4 = (fi&31)*4;
      *(float4*)&Ks[r][c4] = *(const float4*)(base + (size_t)(kt*64+r)*rs + 256 + c4);
    }
    __syncthreads();
    #pragma unroll
    for (int j=0;j<32;j++) oacc[j] *= alpha;
    #pragma unroll
    for (int k=0;k<64;k++){
      const float p = s[k];
      #pragma unroll
      for (int j=0;j<32;j++) oacc[j] = fmaf(p, Ks[k][pp+4*j], oacc[j]);
    }
  }
  const float inv = 1.0f/l;
  float* orow = vals_c + ((size_t)(bl*SEQ+q0+qi))*EHH + h*EE;
  #pragma unroll
  for (int j=0;j<32;j++) orow[pp+4*j] = oacc[j]*inv;
}

// =================== pool + LN + head ===================
__global__ __launch_bounds__(128) void pool_head_k(
    const float* __restrict__ x, const float* __restrict__ x_init,
    const float* __restrict__ w, const float* __restrict__ g2, const float* __restrict__ b2,
    const float* __restrict__ head_W, const float* __restrict__ head_b,
    float* __restrict__ out)
{
  const int b = blockIdx.x;
  const int e = threadIdx.x;
  __shared__ float red[128];
  float acc = 0.f;
  for (int n=0;n<SEQ;n++){
    const size_t idx = ((size_t)(b*SEQ+n))*EE + e;
    acc = fmaf(w[b*SEQ+n], x[idx]+x_init[idx], acc);
  }
  red[e]=acc; __syncthreads();
  for (int s=64;s>0;s>>=1){ if(e<s) red[e]+=red[e+s]; __syncthreads(); }
  const float mean = red[0]*(1.0f/128.0f);
  __syncthreads();
  const float d = acc-mean;
  red[e]=d*d; __syncthreads();
  for (int s=64;s>0;s>>=1){ if(e<s) red[e]+=red[e+s]; __syncthreads(); }
  const float var = red[0]*(1.0f/128.0f);
  const float p = d*rsqrtf(var+1e-5f)*g2[e]+b2[e];
  __syncthreads();
  red[e] = p*head_W[e]; __syncthreads();
  for (int s=64;s>0;s>>=1){ if(e<s) red[e]+=red[e+s]; __syncthreads(); }
  if (e==0) out[b] = red[0] + head_b[0];
}

// =================== launch ===================
extern "C" void kernel_launch(void* const* d_in, const int* in_sizes, int n_in,
                              void* d_out, int out_size, void* d_ws, size_t ws_size,
                              hipStream_t stream)
{
  const float* str_fea   = (const float*)d_in[0];
  const int*   comp_fea  = (const int*)  d_in[1];
  // d_in[2] cell_fea unused by reference
  const float* atom_table= (const float*)d_in[3];
  const float* comp_W    = (const float*)d_in[4];
  const float* comp_b    = (const float*)d_in[5];
  const float* pdd_W     = (const float*)d_in[6];
  const float* pdd_b     = (const float*)d_in[7];
  const float* enc_ln_g  = (const float*)d_in[8];
  const float* enc_ln_b  = (const float*)d_in[9];
  const float* qkv_W     = (const float*)d_in[10];
  const float* qkv_b     = (const float*)d_in[11];
  const float* o_W       = (const float*)d_in[12];
  const float* o_b       = (const float*)d_in[13];
  const float* out_W     = (const float*)d_in[14];
  const float* out_b     = (const float*)d_in[15];
  const float* ffn_W     = (const float*)d_in[16];
  const float* ffn_b     = (const float*)d_in[17];
  const float* ln2_g     = (const float*)d_in[18];
  const float* ln2_b     = (const float*)d_in[19];
  const float* head_W    = (const float*)d_in[20];
  const float* head_b    = (const float*)d_in[21];
  float* out = (float*)d_out;

  // ---- diagnostic 1: input layout model ----
  bool sizes_ok = (n_in >= 22);
  if (sizes_ok){
    sizes_ok = in_sizes[0]==BB*SEQ*KF && in_sizes[1]==NTOK &&
               in_sizes[3]==119*ADIM  && in_sizes[4]==ADIM*EE &&
               in_sizes[10]==LL*EE*3*EHH && in_sizes[12]==LL*EHH*EHH &&
               in_sizes[14]==LL*EHH*EE   && in_sizes[16]==LL*EE*EE &&
               in_sizes[20]==EE;
  }
  if (!sizes_ok){
    sentinel_k<<<(out_size+63)/64,64,0,stream>>>(out, 99999.0f, out_size);
    return;
  }

  // ---- workspace layout (~108 MB; R6 proved ws_size >= ~129 MB) ----
  char* p = (char*)d_ws;
  size_t off = 0;
  auto alloc = [&](size_t bytes)->void*{
    off = (off + 255) & ~(size_t)255;
    void* r = p + off; off += bytes; return r;
  };
  float* w      = (float*)alloc((size_t)NTOK*4);
  float* x      = (float*)alloc((size_t)NTOK*EE*4);
  float* x_init = (float*)alloc((size_t)NTOK*EE*4);
  float* xn     = (float*)alloc((size_t)NTOK*EE*4);
  float* out1   = (float*)alloc((size_t)NTOK*EE*4);
  float* out2   = (float*)alloc((size_t)NTOK*EE*4);
  float* qkvc   = (float*)alloc((size_t)CTOK*3*EHH*4);   // 50.3 MB chunk
  float* vals_c = (float*)alloc((size_t)CTOK*EHH*4);     // 16.8 MB chunk
  float* fw     = (float*)alloc((size_t)EHH*EE*4);
  float* fb     = (float*)alloc((size_t)EE*4);

  // ---- diagnostic 2: workspace size ----
  if (off > ws_size){
    sentinel_k<<<(out_size+63)/64,64,0,stream>>>(out, 12345.0f, out_size);
    return;
  }

  embed_k<<<NTOK,128,0,stream>>>(str_fea, comp_fea, atom_table, comp_W, comp_b,
                                 pdd_W, pdd_b, x, x_init, w);
  for (int i=0;i<LL;i++){
    const float* gi = enc_ln_g + i*EE;
    const float* bi = enc_ln_b + i*EE;
    ln_k<<<NTOK,128,0,stream>>>(x, nullptr, gi, bi, xn);
    fuse_w_k<<<(EHH*EE+255)/256,256,0,stream>>>(
        o_W + (size_t)i*EHH*EHH, out_W + (size_t)i*EHH*EE, fw);
    fuse_b_k<<<1,128,0,stream>>>(
        o_b + (size_t)i*EHH, out_W + (size_t)i*EHH*EE, out_b + (size_t)i*EE, fb);
    for (int cb=0; cb<NCHUNK; cb++){
      const int t0 = cb*CTOK;
      const int b0 = cb*CB;
      // QKV: (CTOK x 128) @ (128 x 3072) -> qkvc
      gemm_k<1,128,128,8,8><<<dim3(3*EHH/128, CTOK/128),256,0,stream>>>(
          xn + (size_t)t0*EE, qkv_W + (size_t)i*EE*3*EHH,
          qkv_b + (size_t)i*3*EHH, nullptr, qkvc, 3*EHH, EE);
      attn_f_k<<<dim3(SEQ/64,HH,CB),256,0,stream>>>(qkvc, w, vals_c, b0);
      // proj: (CTOK x 1024) @ (1024 x 128) + resid -> out1
      gemm_k<2,64,64,4,4><<<dim3(EE/64, CTOK/64),256,0,stream>>>(
          vals_c, fw, fb, x + (size_t)t0*EE, out1 + (size_t)t0*EE, EE, EHH);
    }
    ln_k<<<NTOK,128,0,stream>>>(out1, nullptr, gi, bi, xn);
    // ffn: (NTOK x 128) @ (128 x 128) + mish -> out2
    gemm_k<3,64,64,4,4><<<dim3(EE/64, NTOK/64),256,0,stream>>>(
        xn, ffn_W + (size_t)i*EE*EE, ffn_b + (size_t)i*EE, nullptr,
        out2, EE, EE);
    ln_k<<<NTOK,128,0,stream>>>(out1, out2, gi, bi, x);
  }
  pool_head_k<<<BB,128,0,stream>>>(x, x_init, w, ln2_g, ln2_b, head_W, head_b, out);
}

// Round 9
// 3455.558 us; speedup vs baseline: 6.2751x; 3.2673x over previous
//
#include <hip/hip_runtime.h>
#include <math.h>

#define DI __device__ __forceinline__

// ---- problem constants ----
#define BB 32
#define SEQ 512
#define KF 101
#define EE 128
#define HH 8
#define EHH 1024
#define LL 3
#define ADIM 200
#define NTOK (BB*SEQ)   // 16384
#define CB 8            // batches per chunk
#define NCHUNK (BB/CB)  // 4
#define CTOK (CB*SEQ)   // 4096 tokens per chunk

// R8 post-mortem: attention LDS-pipe bound (4096 b32 reads/thread/kt,
// VALUBusy 15%). R9: register-blocked 4q x 4k flash attention, b128 LDS
// reads, XOR-swizzled tiles (conflict-free), P via LDS bf16. ~4 B/FLOP ->
// ~1 B/FLOP LDS traffic. All other kernels unchanged (R8 passed, absmax 0).

typedef unsigned short u16;
DI float bf2f(u16 s){ union{unsigned int u; float f;} x; x.u = ((unsigned int)s)<<16; return x.f; }
DI u16 f2bf(float f){
  union{float f; unsigned int u;} x; x.f = f;
  unsigned int u = x.u;
  u += 0x7fffu + ((u>>16)&1u);           // RNE
  return (u16)(u>>16);
}

// swizzle: float4-group g of row r stored at group g ^ ((r>>2)&7)
#define SW(r,g) ((g) ^ (((r)>>2)&7))

// =================== sentinel ===================
__global__ void sentinel_k(float* out, float v, int n){
  int i = blockIdx.x*64 + threadIdx.x;
  if (i < n) out[i] = v;
}

// =================== embed ===================
__global__ __launch_bounds__(128) void embed_k(
    const float* __restrict__ str_fea, const int* __restrict__ comp_fea,
    const float* __restrict__ atom_table, const float* __restrict__ comp_W,
    const float* __restrict__ comp_b, const float* __restrict__ pdd_W,
    const float* __restrict__ pdd_b,
    float* __restrict__ x, float* __restrict__ x_init, float* __restrict__ w)
{
  const int t = blockIdx.x;
  const int e = threadIdx.x;
  __shared__ float sAtom[ADIM];
  __shared__ float sStr[104];
  const int idx = comp_fea[t];
  for (int a=e;a<ADIM;a+=128) sAtom[a] = atom_table[idx*ADIM+a];
  for (int a=e;a<KF;a+=128)  sStr[a]  = str_fea[(size_t)t*KF+a];
  __syncthreads();
  float acc = comp_b[e] + pdd_b[e];
  #pragma unroll 4
  for (int a=0;a<ADIM;a++) acc = fmaf(sAtom[a], comp_W[a*EE+e], acc);
  #pragma unroll 4
  for (int j=0;j<KF-1;j++) acc = fmaf(sStr[1+j], pdd_W[j*EE+e], acc);
  x[(size_t)t*EE+e] = acc;
  x_init[(size_t)t*EE+e] = acc;
  if (e==0) w[t] = sStr[0];
}

// =================== layernorm (E=128), optional add ===================
__global__ __launch_bounds__(128) void ln_k(
    const float* __restrict__ in, const float* __restrict__ add,
    const float* __restrict__ g, const float* __restrict__ bta,
    float* __restrict__ out)
{
  const int t = blockIdx.x;
  const int e = threadIdx.x;
  __shared__ float red[128];
  float v = in[(size_t)t*EE+e];
  if (add) v += add[(size_t)t*EE+e];
  red[e] = v; __syncthreads();
  for (int s=64;s>0;s>>=1){ if (e<s) red[e]+=red[e+s]; __syncthreads(); }
  const float mean = red[0]*(1.0f/128.0f);
  __syncthreads();
  const float d = v-mean;
  red[e] = d*d; __syncthreads();
  for (int s=64;s>0;s>>=1){ if (e<s) red[e]+=red[e+s]; __syncthreads(); }
  const float var = red[0]*(1.0f/128.0f);
  out[(size_t)t*EE+e] = d*rsqrtf(var+1e-5f)*g[e] + bta[e];
}

// =================== tiled fp32 GEMM, templated epilogue ===================
template<int EPI, int BM, int BN, int TM, int TN>
__global__ __launch_bounds__(256) void gemm_k(
    const float* __restrict__ A, const float* __restrict__ B,
    const float* __restrict__ bias, const float* __restrict__ resid,
    float* __restrict__ C, int Nn, int Kk)
{
  constexpr int BK = 16;
  __shared__ float As[BK][BM+4];
  __shared__ float Bs[BK][BN+4];
  const int m0 = blockIdx.y*BM, n0 = blockIdx.x*BN;
  const int tid = threadIdx.x;
  const int r0 = (tid>>4)*4, c0 = (tid&15)*4;
  float acc[TM][TN];
  #pragma unroll
  for (int i=0;i<TM;i++)
    #pragma unroll
    for (int j=0;j<TN;j++) acc[i][j]=0.f;

  constexpr int AI = BM/64;
  constexpr int BI = BN/64;

  for (int k0=0;k0<Kk;k0+=BK){
    float4 a_ld[AI]; float4 b_ld[BI];
    #pragma unroll
    for (int it=0; it<AI; it++){
      const int cid = it*256 + tid;
      const int am = cid>>2, ak = (cid&3)*4;
      a_ld[it] = *(const float4*)(A + (size_t)(m0+am)*Kk + k0 + ak);
    }
    #pragma unroll
    for (int it=0; it<BI; it++){
      const int cid = it*256 + tid;
      const int bk = cid/(BN/4), bn = (cid%(BN/4))*4;
      b_ld[it] = *(const float4*)(B + (size_t)(k0+bk)*Nn + n0 + bn);
    }
    __syncthreads();
    #pragma unroll
    for (int it=0; it<AI; it++){
      const int cid = it*256 + tid;
      const int am = cid>>2, ak = (cid&3)*4;
      As[ak+0][am]=a_ld[it].x; As[ak+1][am]=a_ld[it].y;
      As[ak+2][am]=a_ld[it].z; As[ak+3][am]=a_ld[it].w;
    }
    #pragma unroll
    for (int it=0; it<BI; it++){
      const int cid = it*256 + tid;
      const int bk = cid/(BN/4), bn = (cid%(BN/4))*4;
      *(float4*)&Bs[bk][bn] = b_ld[it];
    }
    __syncthreads();
    #pragma unroll
    for (int kk=0; kk<BK; kk++){
      float a[TM], bv[TN];
      #pragma unroll
      for (int hh=0; hh<TM/4; hh++){
        float4 f = *(const float4*)&As[kk][r0 + hh*(BM/2)];
        a[hh*4+0]=f.x; a[hh*4+1]=f.y; a[hh*4+2]=f.z; a[hh*4+3]=f.w;
      }
      #pragma unroll
      for (int hh=0; hh<TN/4; hh++){
        float4 f = *(const float4*)&Bs[kk][c0 + hh*(BN/2)];
        bv[hh*4+0]=f.x; bv[hh*4+1]=f.y; bv[hh*4+2]=f.z; bv[hh*4+3]=f.w;
      }
      #pragma unroll
      for (int i=0;i<TM;i++)
        #pragma unroll
        for (int j=0;j<TN;j++)
          acc[i][j] = fmaf(a[i], bv[j], acc[i][j]);
    }
    __syncthreads();
  }
  #pragma unroll
  for (int i=0;i<TM;i++){
    const int row = m0 + r0 + (i&3) + (i>>2)*(BM/2);
    #pragma unroll
    for (int j=0;j<TN;j++){
      const int col = n0 + c0 + (j&3) + (j>>2)*(BN/2);
      float v = acc[i][j] + bias[col];
      const size_t gi = (size_t)row*Nn + col;
      if constexpr (EPI==1){
        C[gi] = v;
      } else if constexpr (EPI==2){
        C[gi] = v + resid[gi];
      } else {
        const float sp = (v>20.f)?v:log1pf(expf(v));
        C[gi] = v*tanhf(sp);
      }
    }
  }
}

// =================== fused projection precompute ===================
__global__ __launch_bounds__(256) void fuse_w_k(
    const float* __restrict__ oW, const float* __restrict__ outW, float* __restrict__ fw)
{
  const int idx = blockIdx.x*256 + threadIdx.x;   // EHH*EE = 131072
  if (idx >= EHH*EE) return;
  const int k1 = idx >> 7, n = idx & 127;
  float acc = 0.f;
  #pragma unroll 8
  for (int k2=0;k2<EHH;k2++) acc = fmaf(oW[(size_t)k1*EHH+k2], outW[(size_t)k2*EE+n], acc);
  fw[(size_t)k1*EE+n] = acc;
}
__global__ __launch_bounds__(128) void fuse_b_k(
    const float* __restrict__ ob, const float* __restrict__ outW,
    const float* __restrict__ outb, float* __restrict__ fb)
{
  const int n = threadIdx.x;
  float acc = outb[n];
  for (int k2=0;k2<EHH;k2++) acc = fmaf(ob[k2], outW[(size_t)k2*EE+n], acc);
  fb[n] = acc;
}

// =================== register-blocked flash attention over a batch chunk ===================
// qkvc: (CTOK, 3072) token-major; token bl*SEQ+n, col h*384 + {0:q,128:k,256:v}+d.
// Block = (64q-tile, h, bl), 256 threads: tq=tid>>4 (q rows tq*4..+3),
// tk=tid&15 (k cols tk*4..+3 in QK; d cols {tk*4..+3, 64+tk*4..+3} in PV).
// LDS tiles swizzled row-major (SW) -> all hot reads <=2-way (free).
// P goes through LDS as bf16 (only numeric delta vs f32 reference path).
__global__ __launch_bounds__(256) void attn_rb_k(
    const float* __restrict__ qkvc, const float* __restrict__ w,
    float* __restrict__ vals_c, int b0)
{
  const int qt = blockIdx.x;   // 0..7
  const int h  = blockIdx.y;   // 0..7
  const int bl = blockIdx.z;   // 0..CB-1
  const int tid = threadIdx.x;
  const int tq = tid >> 4;
  const int tk = tid & 15;

  __shared__ float Qs[64][132];
  __shared__ float KVs[64][132];
  __shared__ u16   Pts[64][68];
  __shared__ float wt[64], qwt[64];

  const size_t rs = 3072;
  const float* base = qkvc + (size_t)bl*SEQ*rs + (size_t)h*384;
  const int q0 = qt*64;

  // ---- stage Q tile (swizzled) ----
  #pragma unroll
  for (int it=0; it<8; it++){
    const int fi = it*256 + tid;
    const int r = fi >> 5, g = fi & 31;
    const float4 v = *(const float4*)(base + (size_t)(q0+r)*rs + g*4);
    *(float4*)&Qs[r][SW(r,g)*4] = v;
  }
  if (tid < 64) qwt[tid] = w[(b0+bl)*SEQ + q0 + tid];
  __syncthreads();

  float kq[4];
  #pragma unroll
  for (int i=0;i<4;i++) kq[i] = qwt[tq*4+i];

  float oacc[4][8];
  #pragma unroll
  for (int i=0;i<4;i++)
    #pragma unroll
    for (int j=0;j<8;j++) oacc[i][j]=0.f;
  float mrow[4], lrow[4];
  #pragma unroll
  for (int i=0;i<4;i++){ mrow[i]=-INFINITY; lrow[i]=0.f; }
  const float scale = 0.08838834764831845f;  // 1/sqrt(128)

  for (int kt=0; kt<8; kt++){
    __syncthreads();   // prior PV done with KVs
    // ---- stage K tile (swizzled) ----
    #pragma unroll
    for (int it=0; it<8; it++){
      const int fi = it*256 + tid;
      const int r = fi >> 5, g = fi & 31;
      const float4 v = *(const float4*)(base + (size_t)(kt*64+r)*rs + 128 + g*4);
      *(float4*)&KVs[r][SW(r,g)*4] = v;
    }
    if (tid < 64) wt[tid] = w[(b0+bl)*SEQ + kt*64 + tid];
    __syncthreads();

    // ---- S = Q K^T (4q x 4k per thread) ----
    float s[4][4];
    #pragma unroll
    for (int i=0;i<4;i++)
      #pragma unroll
      for (int j=0;j<4;j++) s[i][j]=0.f;
    for (int g=0; g<32; g++){
      float4 qa[4], ka[4];
      #pragma unroll
      for (int i=0;i<4;i++) qa[i] = *(const float4*)&Qs[tq*4+i][SW(tq*4+i, g)*4];
      #pragma unroll
      for (int j=0;j<4;j++) ka[j] = *(const float4*)&KVs[tk*4+j][SW(tk*4+j, g)*4];
      #pragma unroll
      for (int i=0;i<4;i++)
        #pragma unroll
        for (int j=0;j<4;j++){
          s[i][j] = fmaf(qa[i].x, ka[j].x, s[i][j]);
          s[i][j] = fmaf(qa[i].y, ka[j].y, s[i][j]);
          s[i][j] = fmaf(qa[i].z, ka[j].z, s[i][j]);
          s[i][j] = fmaf(qa[i].w, ka[j].w, s[i][j]);
        }
    }
    // ---- mask + scale ----
    float wkj[4];
    #pragma unroll
    for (int j=0;j<4;j++) wkj[j] = wt[tk*4+j];
    #pragma unroll
    for (int i=0;i<4;i++)
      #pragma unroll
      for (int j=0;j<4;j++){
        const bool keep = (kq[i] > 0.f) && (wkj[j] > 0.f);
        s[i][j] = keep ? s[i][j]*scale : -9.0e15f;
      }
    // ---- online softmax per row (reduce over 16 tk lanes; tq bits untouched) ----
    float alpha[4];
    #pragma unroll
    for (int i=0;i<4;i++){
      float rm = fmaxf(fmaxf(s[i][0], s[i][1]), fmaxf(s[i][2], s[i][3]));
      rm = fmaxf(rm, __shfl_xor(rm, 1));
      rm = fmaxf(rm, __shfl_xor(rm, 2));
      rm = fmaxf(rm, __shfl_xor(rm, 4));
      rm = fmaxf(rm, __shfl_xor(rm, 8));
      const float newm = fmaxf(mrow[i], rm);
      alpha[i] = expf(mrow[i] - newm);
      #pragma unroll
      for (int j=0;j<4;j++) s[i][j] = wkj[j]*expf(s[i][j]-newm);
      float ls = s[i][0]+s[i][1]+s[i][2]+s[i][3];
      ls += __shfl_xor(ls, 1);
      ls += __shfl_xor(ls, 2);
      ls += __shfl_xor(ls, 4);
      ls += __shfl_xor(ls, 8);
      lrow[i] = lrow[i]*alpha[i] + ls;
      mrow[i] = newm;
    }
    // ---- write P (bf16) transposed: Pts[kcol][qrow] ----
    #pragma unroll
    for (int j=0;j<4;j++){
      ushort4 pu;
      pu.x = f2bf(s[0][j]); pu.y = f2bf(s[1][j]);
      pu.z = f2bf(s[2][j]); pu.w = f2bf(s[3][j]);
      *(ushort4*)&Pts[tk*4+j][tq*4] = pu;
    }
    #pragma unroll
    for (int i=0;i<4;i++)
      #pragma unroll
      for (int j=0;j<8;j++) oacc[i][j] *= alpha[i];

    __syncthreads();   // QK reads + Pt writes done; overwrite K with V
    #pragma unroll
    for (int it=0; it<8; it++){
      const int fi = it*256 + tid;
      const int r = fi >> 5, g = fi & 31;
      const float4 v = *(const float4*)(base + (size_t)(kt*64+r)*rs + 256 + g*4);
      *(float4*)&KVs[r][SW(r,g)*4] = v;
    }
    __syncthreads();

    // ---- O += P V (4q x 8d per thread) ----
    for (int k=0;k<64;k++){
      const ushort4 pu = *(const ushort4*)&Pts[k][tq*4];
      const float pr0 = bf2f(pu.x), pr1 = bf2f(pu.y), pr2 = bf2f(pu.z), pr3 = bf2f(pu.w);
      const float4 v0 = *(const float4*)&KVs[k][SW(k, tk)*4];
      const float4 v1 = *(const float4*)&KVs[k][SW(k, tk+16)*4];
      float pr[4] = {pr0, pr1, pr2, pr3};
      #pragma unroll
      for (int i=0;i<4;i++){
        oacc[i][0] = fmaf(pr[i], v0.x, oacc[i][0]);
        oacc[i][1] = fmaf(pr[i], v0.y, oacc[i][1]);
        oacc[i][2] = fmaf(pr[i], v0.z, oacc[i][2]);
        oacc[i][3] = fmaf(pr[i], v0.w, oacc[i][3]);
        oacc[i][4] = fmaf(pr[i], v1.x, oacc[i][4]);
        oacc[i][5] = fmaf(pr[i], v1.y, oacc[i][5]);
        oacc[i][6] = fmaf(pr[i], v1.z, oacc[i][6]);
        oacc[i][7] = fmaf(pr[i], v1.w, oacc[i][7]);
      }
    }
  }
  // ---- normalize + write: d cols tk*4..+3 and 64+tk*4..+3 ----
  #pragma unroll
  for (int i=0;i<4;i++){
    const float inv = 1.0f / lrow[i];
    float* orow = vals_c + ((size_t)(bl*SEQ + q0 + tq*4 + i))*EHH + h*EE;
    float4 a, b;
    a.x = oacc[i][0]*inv; a.y = oacc[i][1]*inv; a.z = oacc[i][2]*inv; a.w = oacc[i][3]*inv;
    b.x = oacc[i][4]*inv; b.y = oacc[i][5]*inv; b.z = oacc[i][6]*inv; b.w = oacc[i][7]*inv;
    *(float4*)(orow + tk*4) = a;
    *(float4*)(orow + 64 + tk*4) = b;
  }
}

// =================== pool + LN + head ===================
__global__ __launch_bounds__(128) void pool_head_k(
    const float* __restrict__ x, const float* __restrict__ x_init,
    const float* __restrict__ w, const float* __restrict__ g2, const float* __restrict__ b2,
    const float* __restrict__ head_W, const float* __restrict__ head_b,
    float* __restrict__ out)
{
  const int b = blockIdx.x;
  const int e = threadIdx.x;
  __shared__ float red[128];
  float acc = 0.f;
  for (int n=0;n<SEQ;n++){
    const size_t idx = ((size_t)(b*SEQ+n))*EE + e;
    acc = fmaf(w[b*SEQ+n], x[idx]+x_init[idx], acc);
  }
  red[e]=acc; __syncthreads();
  for (int s=64;s>0;s>>=1){ if(e<s) red[e]+=red[e+s]; __syncthreads(); }
  const float mean = red[0]*(1.0f/128.0f);
  __syncthreads();
  const float d = acc-mean;
  red[e]=d*d; __syncthreads();
  for (int s=64;s>0;s>>=1){ if(e<s) red[e]+=red[e+s]; __syncthreads(); }
  const float var = red[0]*(1.0f/128.0f);
  const float p = d*rsqrtf(var+1e-5f)*g2[e]+b2[e];
  __syncthreads();
  red[e] = p*head_W[e]; __syncthreads();
  for (int s=64;s>0;s>>=1){ if(e<s) red[e]+=red[e+s]; __syncthreads(); }
  if (e==0) out[b] = red[0] + head_b[0];
}

// =================== launch ===================
extern "C" void kernel_launch(void* const* d_in, const int* in_sizes, int n_in,
                              void* d_out, int out_size, void* d_ws, size_t ws_size,
                              hipStream_t stream)
{
  const float* str_fea   = (const float*)d_in[0];
  const int*   comp_fea  = (const int*)  d_in[1];
  // d_in[2] cell_fea unused by reference
  const float* atom_table= (const float*)d_in[3];
  const float* comp_W    = (const float*)d_in[4];
  const float* comp_b    = (const float*)d_in[5];
  const float* pdd_W     = (const float*)d_in[6];
  const float* pdd_b     = (const float*)d_in[7];
  const float* enc_ln_g  = (const float*)d_in[8];
  const float* enc_ln_b  = (const float*)d_in[9];
  const float* qkv_W     = (const float*)d_in[10];
  const float* qkv_b     = (const float*)d_in[11];
  const float* o_W       = (const float*)d_in[12];
  const float* o_b       = (const float*)d_in[13];
  const float* out_W     = (const float*)d_in[14];
  const float* out_b     = (const float*)d_in[15];
  const float* ffn_W     = (const float*)d_in[16];
  const float* ffn_b     = (const float*)d_in[17];
  const float* ln2_g     = (const float*)d_in[18];
  const float* ln2_b     = (const float*)d_in[19];
  const float* head_W    = (const float*)d_in[20];
  const float* head_b    = (const float*)d_in[21];
  float* out = (float*)d_out;

  // ---- diagnostic 1: input layout model ----
  bool sizes_ok = (n_in >= 22);
  if (sizes_ok){
    sizes_ok = in_sizes[0]==BB*SEQ*KF && in_sizes[1]==NTOK &&
               in_sizes[3]==119*ADIM  && in_sizes[4]==ADIM*EE &&
               in_sizes[10]==LL*EE*3*EHH && in_sizes[12]==LL*EHH*EHH &&
               in_sizes[14]==LL*EHH*EE   && in_sizes[16]==LL*EE*EE &&
               in_sizes[20]==EE;
  }
  if (!sizes_ok){
    sentinel_k<<<(out_size+63)/64,64,0,stream>>>(out, 99999.0f, out_size);
    return;
  }

  // ---- workspace layout (~108 MB; proven fits) ----
  char* p = (char*)d_ws;
  size_t off = 0;
  auto alloc = [&](size_t bytes)->void*{
    off = (off + 255) & ~(size_t)255;
    void* r = p + off; off += bytes; return r;
  };
  float* w      = (float*)alloc((size_t)NTOK*4);
  float* x      = (float*)alloc((size_t)NTOK*EE*4);
  float* x_init = (float*)alloc((size_t)NTOK*EE*4);
  float* xn     = (float*)alloc((size_t)NTOK*EE*4);
  float* out1   = (float*)alloc((size_t)NTOK*EE*4);
  float* out2   = (float*)alloc((size_t)NTOK*EE*4);
  float* qkvc   = (float*)alloc((size_t)CTOK*3*EHH*4);   // 50.3 MB chunk
  float* vals_c = (float*)alloc((size_t)CTOK*EHH*4);     // 16.8 MB chunk
  float* fw     = (float*)alloc((size_t)EHH*EE*4);
  float* fb     = (float*)alloc((size_t)EE*4);

  // ---- diagnostic 2: workspace size ----
  if (off > ws_size){
    sentinel_k<<<(out_size+63)/64,64,0,stream>>>(out, 12345.0f, out_size);
    return;
  }

  embed_k<<<NTOK,128,0,stream>>>(str_fea, comp_fea, atom_table, comp_W, comp_b,
                                 pdd_W, pdd_b, x, x_init, w);
  for (int i=0;i<LL;i++){
    const float* gi = enc_ln_g + i*EE;
    const float* bi = enc_ln_b + i*EE;
    ln_k<<<NTOK,128,0,stream>>>(x, nullptr, gi, bi, xn);
    fuse_w_k<<<(EHH*EE+255)/256,256,0,stream>>>(
        o_W + (size_t)i*EHH*EHH, out_W + (size_t)i*EHH*EE, fw);
    fuse_b_k<<<1,128,0,stream>>>(
        o_b + (size_t)i*EHH, out_W + (size_t)i*EHH*EE, out_b + (size_t)i*EE, fb);
    for (int cb=0; cb<NCHUNK; cb++){
      const int t0 = cb*CTOK;
      const int b0 = cb*CB;
      // QKV: (CTOK x 128) @ (128 x 3072) -> qkvc
      gemm_k<1,128,128,8,8><<<dim3(3*EHH/128, CTOK/128),256,0,stream>>>(
          xn + (size_t)t0*EE, qkv_W + (size_t)i*EE*3*EHH,
          qkv_b + (size_t)i*3*EHH, nullptr, qkvc, 3*EHH, EE);
      attn_rb_k<<<dim3(SEQ/64,HH,CB),256,0,stream>>>(qkvc, w, vals_c, b0);
      // proj: (CTOK x 1024) @ (1024 x 128) + resid -> out1
      gemm_k<2,64,64,4,4><<<dim3(EE/64, CTOK/64),256,0,stream>>>(
          vals_c, fw, fb, x + (size_t)t0*EE, out1 + (size_t)t0*EE, EE, EHH);
    }
    ln_k<<<NTOK,128,0,stream>>>(out1, nullptr, gi, bi, xn);
    // ffn: (NTOK x 128) @ (128 x 128) + mish -> out2
    gemm_k<3,64,64,4,4><<<dim3(EE/64, NTOK/64),256,0,stream>>>(
        xn, ffn_W + (size_t)i*EE*EE, ffn_b + (size_t)i*EE, nullptr,
        out2, EE, EE);
    ln_k<<<NTOK,128,0,stream>>>(out1, out2, gi, bi, x);
  }
  pool_head_k<<<BB,128,0,stream>>>(x, x_init, w, ln2_g, ln2_b, head_W, head_b, out);
}

// Round 10
// 2826.248 us; speedup vs baseline: 7.6724x; 1.2227x over previous
//
#include <hip/hip_runtime.h>
#include <math.h>

#define DI __device__ __forceinline__

// ---- problem constants ----
#define BB 32
#define SEQ 512
#define KF 101
#define EE 128
#define HH 8
#define EHH 1024
#define LL 3
#define ADIM 200
#define NTOK (BB*SEQ)   // 16384
#define CB 8            // batches per chunk
#define NCHUNK (BB/CB)  // 4
#define CTOK (CB*SEQ)   // 4096 tokens per chunk

// R9 post-mortem: attn 165us x12 (~2.0ms, 52 TF f32), GEMMs ~1.2ms fp32 VALU.
// R10: QKV/proj/FFN -> bf16 MFMA (16x16x32), B pre-transposed N x K so A/B
// fragments are identical contiguous ds_read_b128 (LDS stride 72 u16 = 2-way
// = free). Residuals/attention stay f32; LN->GEMM activations + vals go bf16.

typedef unsigned short u16;
typedef __attribute__((ext_vector_type(8))) short bf16x8;
typedef __attribute__((ext_vector_type(4))) float f32x4;

DI float bf2f(u16 s){ union{unsigned int u; float f;} x; x.u = ((unsigned int)s)<<16; return x.f; }
DI u16 f2bf(float f){
  union{float f; unsigned int u;} x; x.f = f;
  unsigned int u = x.u;
  u += 0x7fffu + ((u>>16)&1u);           // RNE
  return (u16)(u>>16);
}

// swizzle for attention f32 tiles: float4-group g of row r -> g ^ ((r>>2)&7)
#define SW(r,g) ((g) ^ (((r)>>2)&7))

// =================== sentinel ===================
__global__ void sentinel_k(float* out, float v, int n){
  int i = blockIdx.x*64 + threadIdx.x;
  if (i < n) out[i] = v;
}

// =================== embed ===================
__global__ __launch_bounds__(128) void embed_k(
    const float* __restrict__ str_fea, const int* __restrict__ comp_fea,
    const float* __restrict__ atom_table, const float* __restrict__ comp_W,
    const float* __restrict__ comp_b, const float* __restrict__ pdd_W,
    const float* __restrict__ pdd_b,
    float* __restrict__ x, float* __restrict__ x_init, float* __restrict__ w)
{
  const int t = blockIdx.x;
  const int e = threadIdx.x;
  __shared__ float sAtom[ADIM];
  __shared__ float sStr[104];
  const int idx = comp_fea[t];
  for (int a=e;a<ADIM;a+=128) sAtom[a] = atom_table[idx*ADIM+a];
  for (int a=e;a<KF;a+=128)  sStr[a]  = str_fea[(size_t)t*KF+a];
  __syncthreads();
  float acc = comp_b[e] + pdd_b[e];
  #pragma unroll 4
  for (int a=0;a<ADIM;a++) acc = fmaf(sAtom[a], comp_W[a*EE+e], acc);
  #pragma unroll 4
  for (int j=0;j<KF-1;j++) acc = fmaf(sStr[1+j], pdd_W[j*EE+e], acc);
  x[(size_t)t*EE+e] = acc;
  x_init[(size_t)t*EE+e] = acc;
  if (e==0) w[t] = sStr[0];
}

// =================== layernorm (E=128), optional add; f32 or bf16 output ===================
template<bool OBF>
__global__ __launch_bounds__(128) void ln_k(
    const float* __restrict__ in, const float* __restrict__ add,
    const float* __restrict__ g, const float* __restrict__ bta,
    void* __restrict__ outv)
{
  const int t = blockIdx.x;
  const int e = threadIdx.x;
  __shared__ float red[128];
  float v = in[(size_t)t*EE+e];
  if (add) v += add[(size_t)t*EE+e];
  red[e] = v; __syncthreads();
  for (int s=64;s>0;s>>=1){ if (e<s) red[e]+=red[e+s]; __syncthreads(); }
  const float mean = red[0]*(1.0f/128.0f);
  __syncthreads();
  const float d = v-mean;
  red[e] = d*d; __syncthreads();
  for (int s=64;s>0;s>>=1){ if (e<s) red[e]+=red[e+s]; __syncthreads(); }
  const float var = red[0]*(1.0f/128.0f);
  const float r = d*rsqrtf(var+1e-5f)*g[e] + bta[e];
  if constexpr (OBF) ((u16*)outv)[(size_t)t*EE+e] = f2bf(r);
  else               ((float*)outv)[(size_t)t*EE+e] = r;
}

// =================== weight convert+transpose: W (Kk x Nn f32) -> WT (Nn x Kk bf16) ===================
__global__ __launch_bounds__(256) void tconv_k(
    const float* __restrict__ W, u16* __restrict__ WT, int Kk, int Nn)
{
  const int idx = blockIdx.x*256 + threadIdx.x;
  if (idx >= Kk*Nn) return;
  const int k = idx / Nn, n = idx - k*Nn;
  WT[(size_t)n*Kk + k] = f2bf(W[idx]);
}

// =================== MFMA bf16 GEMM ===================
// A: M x Kk bf16 row-major. BT: Nn x Kk bf16 row-major (pre-transposed B).
// C: f32 M x Nn. EPI 1: store; 2: +resid; 3: mish.
// Fragment layouts (guide 3, m89/m120 verified):
//   A: lane holds A[lane&15][(lane>>4)*8 + e]  (e=0..7)  -> contiguous in As
//   B: lane holds B[(lane>>4)*8+e][lane&15] == BT[lane&15][(lane>>4)*8+e]
//   D: lane holds D[(lane>>4)*4 + r][lane&15]
template<int EPI, int BM, int BN>
__global__ __launch_bounds__(256) void mgemm_k(
    const u16* __restrict__ A, const u16* __restrict__ BT,
    const float* __restrict__ bias, const float* __restrict__ resid,
    float* __restrict__ C, int Nn, int Kk)
{
  constexpr int BK  = 64;
  constexpr int LDK = BK + 8;     // u16 stride 72 = 144 B (16B-aligned, 2-way banks)
  __shared__ u16 As[BM*LDK];
  __shared__ u16 Bs[BN*LDK];
  const int tid = threadIdx.x;
  const int m0 = blockIdx.y*BM, n0 = blockIdx.x*BN;
  constexpr int WMN = (BM>=128)?2:1;      // waves along M
  constexpr int WNN = 4/WMN;              // waves along N
  constexpr int WM = BM/WMN;              // 64
  constexpr int WN = BN/WNN;              // 64 or 32
  constexpr int FM = WM/16, FN = WN/16;
  const int wv = tid>>6, lane = tid&63;
  const int wm = (wv/WNN)*WM;
  const int wn = (wv%WNN)*WN;
  const int lm = lane&15, lq = lane>>4;

  f32x4 acc[FM][FN];
  #pragma unroll
  for (int i=0;i<FM;i++)
    #pragma unroll
    for (int j=0;j<FN;j++) acc[i][j] = (f32x4){0.f,0.f,0.f,0.f};

  constexpr int ACH = BM*BK/8;   // 8-bf16 chunks
  constexpr int BCH = BN*BK/8;

  for (int k0=0; k0<Kk; k0+=BK){
    #pragma unroll
    for (int c = tid; c < ACH; c += 256){
      const int r = c/(BK/8), kg = c - r*(BK/8);
      const float4 v = *(const float4*)(A + (size_t)(m0+r)*Kk + k0 + kg*8);
      *(float4*)&As[r*LDK + kg*8] = v;
    }
    #pragma unroll
    for (int c = tid; c < BCH; c += 256){
      const int r = c/(BK/8), kg = c - r*(BK/8);
      const float4 v = *(const float4*)(BT + (size_t)(n0+r)*Kk + k0 + kg*8);
      *(float4*)&Bs[r*LDK + kg*8] = v;
    }
    __syncthreads();
    #pragma unroll
    for (int kk=0; kk<BK/32; kk++){
      bf16x8 af[FM], bfr[FN];
      #pragma unroll
      for (int i=0;i<FM;i++)
        af[i] = *(const bf16x8*)&As[(wm + i*16 + lm)*LDK + kk*32 + lq*8];
      #pragma unroll
      for (int j=0;j<FN;j++)
        bfr[j] = *(const bf16x8*)&Bs[(wn + j*16 + lm)*LDK + kk*32 + lq*8];
      #pragma unroll
      for (int i=0;i<FM;i++)
        #pragma unroll
        for (int j=0;j<FN;j++)
          acc[i][j] = __builtin_amdgcn_mfma_f32_16x16x32_bf16(af[i], bfr[j], acc[i][j], 0, 0, 0);
    }
    __syncthreads();
  }
  #pragma unroll
  for (int i=0;i<FM;i++){
    #pragma unroll
    for (int j=0;j<FN;j++){
      const int col = n0 + wn + j*16 + lm;
      const float bv = bias[col];
      #pragma unroll
      for (int r=0;r<4;r++){
        const int row = m0 + wm + i*16 + lq*4 + r;
        float v = acc[i][j][r] + bv;
        const size_t gi = (size_t)row*Nn + col;
        if constexpr (EPI==1)      C[gi] = v;
        else if constexpr (EPI==2) C[gi] = v + resid[gi];
        else { const float sp=(v>20.f)?v:log1pf(expf(v)); C[gi]=v*tanhf(sp); }
      }
    }
  }
}

// =================== fused projection precompute (writes fwT bf16, N x K) ===================
__global__ __launch_bounds__(256) void fuse_w_k(
    const float* __restrict__ oW, const float* __restrict__ outW, u16* __restrict__ fwT)
{
  const int idx = blockIdx.x*256 + threadIdx.x;   // EHH*EE = 131072
  if (idx >= EHH*EE) return;
  const int k1 = idx >> 7, n = idx & 127;
  float acc = 0.f;
  #pragma unroll 8
  for (int k2=0;k2<EHH;k2++) acc = fmaf(oW[(size_t)k1*EHH+k2], outW[(size_t)k2*EE+n], acc);
  fwT[(size_t)n*EHH + k1] = f2bf(acc);
}
__global__ __launch_bounds__(128) void fuse_b_k(
    const float* __restrict__ ob, const float* __restrict__ outW,
    const float* __restrict__ outb, float* __restrict__ fb)
{
  const int n = threadIdx.x;
  float acc = outb[n];
  for (int k2=0;k2<EHH;k2++) acc = fmaf(ob[k2], outW[(size_t)k2*EE+n], acc);
  fb[n] = acc;
}

// =================== register-blocked flash attention over a batch chunk ===================
// (unchanged from R9 except: writes vals as bf16)
__global__ __launch_bounds__(256) void attn_rb_k(
    const float* __restrict__ qkvc, const float* __restrict__ w,
    u16* __restrict__ vals_c, int b0)
{
  const int qt = blockIdx.x;   // 0..7
  const int h  = blockIdx.y;   // 0..7
  const int bl = blockIdx.z;   // 0..CB-1
  const int tid = threadIdx.x;
  const int tq = tid >> 4;
  const int tk = tid & 15;

  __shared__ float Qs[64][132];
  __shared__ float KVs[64][132];
  __shared__ u16   Pts[64][68];
  __shared__ float wt[64], qwt[64];

  const size_t rs = 3072;
  const float* base = qkvc + (size_t)bl*SEQ*rs + (size_t)h*384;
  const int q0 = qt*64;

  #pragma unroll
  for (int it=0; it<8; it++){
    const int fi = it*256 + tid;
    const int r = fi >> 5, g = fi & 31;
    const float4 v = *(const float4*)(base + (size_t)(q0+r)*rs + g*4);
    *(float4*)&Qs[r][SW(r,g)*4] = v;
  }
  if (tid < 64) qwt[tid] = w[(b0+bl)*SEQ + q0 + tid];
  __syncthreads();

  float kq[4];
  #pragma unroll
  for (int i=0;i<4;i++) kq[i] = qwt[tq*4+i];

  float oacc[4][8];
  #pragma unroll
  for (int i=0;i<4;i++)
    #pragma unroll
    for (int j=0;j<8;j++) oacc[i][j]=0.f;
  float mrow[4], lrow[4];
  #pragma unroll
  for (int i=0;i<4;i++){ mrow[i]=-INFINITY; lrow[i]=0.f; }
  const float scale = 0.08838834764831845f;  // 1/sqrt(128)

  for (int kt=0; kt<8; kt++){
    __syncthreads();
    #pragma unroll
    for (int it=0; it<8; it++){
      const int fi = it*256 + tid;
      const int r = fi >> 5, g = fi & 31;
      const float4 v = *(const float4*)(base + (size_t)(kt*64+r)*rs + 128 + g*4);
      *(float4*)&KVs[r][SW(r,g)*4] = v;
    }
    if (tid < 64) wt[tid] = w[(b0+bl)*SEQ + kt*64 + tid];
    __syncthreads();

    float s[4][4];
    #pragma unroll
    for (int i=0;i<4;i++)
      #pragma unroll
      for (int j=0;j<4;j++) s[i][j]=0.f;
    for (int g=0; g<32; g++){
      float4 qa[4], ka[4];
      #pragma unroll
      for (int i=0;i<4;i++) qa[i] = *(const float4*)&Qs[tq*4+i][SW(tq*4+i, g)*4];
      #pragma unroll
      for (int j=0;j<4;j++) ka[j] = *(const float4*)&KVs[tk*4+j][SW(tk*4+j, g)*4];
      #pragma unroll
      for (int i=0;i<4;i++)
        #pragma unroll
        for (int j=0;j<4;j++){
          s[i][j] = fmaf(qa[i].x, ka[j].x, s[i][j]);
          s[i][j] = fmaf(qa[i].y, ka[j].y, s[i][j]);
          s[i][j] = fmaf(qa[i].z, ka[j].z, s[i][j]);
          s[i][j] = fmaf(qa[i].w, ka[j].w, s[i][j]);
        }
    }
    float wkj[4];
    #pragma unroll
    for (int j=0;j<4;j++) wkj[j] = wt[tk*4+j];
    #pragma unroll
    for (int i=0;i<4;i++)
      #pragma unroll
      for (int j=0;j<4;j++){
        const bool keep = (kq[i] > 0.f) && (wkj[j] > 0.f);
        s[i][j] = keep ? s[i][j]*scale : -9.0e15f;
      }
    float alpha[4];
    #pragma unroll
    for (int i=0;i<4;i++){
      float rm = fmaxf(fmaxf(s[i][0], s[i][1]), fmaxf(s[i][2], s[i][3]));
      rm = fmaxf(rm, __shfl_xor(rm, 1));
      rm = fmaxf(rm, __shfl_xor(rm, 2));
      rm = fmaxf(rm, __shfl_xor(rm, 4));
      rm = fmaxf(rm, __shfl_xor(rm, 8));
      const float newm = fmaxf(mrow[i], rm);
      alpha[i] = expf(mrow[i] - newm);
      #pragma unroll
      for (int j=0;j<4;j++) s[i][j] = wkj[j]*expf(s[i][j]-newm);
      float ls = s[i][0]+s[i][1]+s[i][2]+s[i][3];
      ls += __shfl_xor(ls, 1);
      ls += __shfl_xor(ls, 2);
      ls += __shfl_xor(ls, 4);
      ls += __shfl_xor(ls, 8);
      lrow[i] = lrow[i]*alpha[i] + ls;
      mrow[i] = newm;
    }
    #pragma unroll
    for (int j=0;j<4;j++){
      ushort4 pu;
      pu.x = f2bf(s[0][j]); pu.y = f2bf(s[1][j]);
      pu.z = f2bf(s[2][j]); pu.w = f2bf(s[3][j]);
      *(ushort4*)&Pts[tk*4+j][tq*4] = pu;
    }
    #pragma unroll
    for (int i=0;i<4;i++)
      #pragma unroll
      for (int j=0;j<8;j++) oacc[i][j] *= alpha[i];

    __syncthreads();
    #pragma unroll
    for (int it=0; it<8; it++){
      const int fi = it*256 + tid;
      const int r = fi >> 5, g = fi & 31;
      const float4 v = *(const float4*)(base + (size_t)(kt*64+r)*rs + 256 + g*4);
      *(float4*)&KVs[r][SW(r,g)*4] = v;
    }
    __syncthreads();

    for (int k=0;k<64;k++){
      const ushort4 pu = *(const ushort4*)&Pts[k][tq*4];
      const float4 v0 = *(const float4*)&KVs[k][SW(k, tk)*4];
      const float4 v1 = *(const float4*)&KVs[k][SW(k, tk+16)*4];
      float pr[4] = {bf2f(pu.x), bf2f(pu.y), bf2f(pu.z), bf2f(pu.w)};
      #pragma unroll
      for (int i=0;i<4;i++){
        oacc[i][0] = fmaf(pr[i], v0.x, oacc[i][0]);
        oacc[i][1] = fmaf(pr[i], v0.y, oacc[i][1]);
        oacc[i][2] = fmaf(pr[i], v0.z, oacc[i][2]);
        oacc[i][3] = fmaf(pr[i], v0.w, oacc[i][3]);
        oacc[i][4] = fmaf(pr[i], v1.x, oacc[i][4]);
        oacc[i][5] = fmaf(pr[i], v1.y, oacc[i][5]);
        oacc[i][6] = fmaf(pr[i], v1.z, oacc[i][6]);
        oacc[i][7] = fmaf(pr[i], v1.w, oacc[i][7]);
      }
    }
  }
  #pragma unroll
  for (int i=0;i<4;i++){
    const float inv = 1.0f / lrow[i];
    u16* orow = vals_c + ((size_t)(bl*SEQ + q0 + tq*4 + i))*EHH + h*EE;
    ushort4 a, b;
    a.x = f2bf(oacc[i][0]*inv); a.y = f2bf(oacc[i][1]*inv);
    a.z = f2bf(oacc[i][2]*inv); a.w = f2bf(oacc[i][3]*inv);
    b.x = f2bf(oacc[i][4]*inv); b.y = f2bf(oacc[i][5]*inv);
    b.z = f2bf(oacc[i][6]*inv); b.w = f2bf(oacc[i][7]*inv);
    *(ushort4*)(orow + tk*4) = a;
    *(ushort4*)(orow + 64 + tk*4) = b;
  }
}

// =================== pool + LN + head ===================
__global__ __launch_bounds__(128) void pool_head_k(
    const float* __restrict__ x, const float* __restrict__ x_init,
    const float* __restrict__ w, const float* __restrict__ g2, const float* __restrict__ b2,
    const float* __restrict__ head_W, const float* __restrict__ head_b,
    float* __restrict__ out)
{
  const int b = blockIdx.x;
  const int e = threadIdx.x;
  __shared__ float red[128];
  float acc = 0.f;
  for (int n=0;n<SEQ;n++){
    const size_t idx = ((size_t)(b*SEQ+n))*EE + e;
    acc = fmaf(w[b*SEQ+n], x[idx]+x_init[idx], acc);
  }
  red[e]=acc; __syncthreads();
  for (int s=64;s>0;s>>=1){ if(e<s) red[e]+=red[e+s]; __syncthreads(); }
  const float mean = red[0]*(1.0f/128.0f);
  __syncthreads();
  const float d = acc-mean;
  red[e]=d*d; __syncthreads();
  for (int s=64;s>0;s>>=1){ if(e<s) red[e]+=red[e+s]; __syncthreads(); }
  const float var = red[0]*(1.0f/128.0f);
  const float p = d*rsqrtf(var+1e-5f)*g2[e]+b2[e];
  __syncthreads();
  red[e] = p*head_W[e]; __syncthreads();
  for (int s=64;s>0;s>>=1){ if(e<s) red[e]+=red[e+s]; __syncthreads(); }
  if (e==0) out[b] = red[0] + head_b[0];
}

// =================== launch ===================
extern "C" void kernel_launch(void* const* d_in, const int* in_sizes, int n_in,
                              void* d_out, int out_size, void* d_ws, size_t ws_size,
                              hipStream_t stream)
{
  const float* str_fea   = (const float*)d_in[0];
  const int*   comp_fea  = (const int*)  d_in[1];
  // d_in[2] cell_fea unused by reference
  const float* atom_table= (const float*)d_in[3];
  const float* comp_W    = (const float*)d_in[4];
  const float* comp_b    = (const float*)d_in[5];
  const float* pdd_W     = (const float*)d_in[6];
  const float* pdd_b     = (const float*)d_in[7];
  const float* enc_ln_g  = (const float*)d_in[8];
  const float* enc_ln_b  = (const float*)d_in[9];
  const float* qkv_W     = (const float*)d_in[10];
  const float* qkv_b     = (const float*)d_in[11];
  const float* o_W       = (const float*)d_in[12];
  const float* o_b       = (const float*)d_in[13];
  const float* out_W     = (const float*)d_in[14];
  const float* out_b     = (const float*)d_in[15];
  const float* ffn_W     = (const float*)d_in[16];
  const float* ffn_b     = (const float*)d_in[17];
  const float* ln2_g     = (const float*)d_in[18];
  const float* ln2_b     = (const float*)d_in[19];
  const float* head_W    = (const float*)d_in[20];
  const float* head_b    = (const float*)d_in[21];
  float* out = (float*)d_out;

  // ---- diagnostic 1: input layout model ----
  bool sizes_ok = (n_in >= 22);
  if (sizes_ok){
    sizes_ok = in_sizes[0]==BB*SEQ*KF && in_sizes[1]==NTOK &&
               in_sizes[3]==119*ADIM  && in_sizes[4]==ADIM*EE &&
               in_sizes[10]==LL*EE*3*EHH && in_sizes[12]==LL*EHH*EHH &&
               in_sizes[14]==LL*EHH*EE   && in_sizes[16]==LL*EE*EE &&
               in_sizes[20]==EE;
  }
  if (!sizes_ok){
    sentinel_k<<<(out_size+63)/64,64,0,stream>>>(out, 99999.0f, out_size);
    return;
  }

  // ---- workspace layout (~97.6 MB; <= 109.6 MB proven) ----
  char* p = (char*)d_ws;
  size_t off = 0;
  auto alloc = [&](size_t bytes)->void*{
    off = (off + 255) & ~(size_t)255;
    void* r = p + off; off += bytes; return r;
  };
  float* w      = (float*)alloc((size_t)NTOK*4);
  float* x      = (float*)alloc((size_t)NTOK*EE*4);
  float* x_init = (float*)alloc((size_t)NTOK*EE*4);
  u16*   xn_bf  = (u16*)  alloc((size_t)NTOK*EE*2);
  float* out1   = (float*)alloc((size_t)NTOK*EE*4);
  float* out2   = (float*)alloc((size_t)NTOK*EE*4);
  float* qkvc   = (float*)alloc((size_t)CTOK*3*EHH*4);   // 50.3 MB chunk
  u16*   vals_bf= (u16*)  alloc((size_t)CTOK*EHH*2);     // 8.4 MB chunk
  u16*   qkvWT  = (u16*)  alloc((size_t)3*EHH*EE*2);     // 3072 x 128 bf16
  u16*   fwT    = (u16*)  alloc((size_t)EE*EHH*2);       // 128 x 1024 bf16
  u16*   ffnWT  = (u16*)  alloc((size_t)EE*EE*2);        // 128 x 128 bf16
  float* fb     = (float*)alloc((size_t)EE*4);

  // ---- diagnostic 2: workspace size ----
  if (off > ws_size){
    sentinel_k<<<(out_size+63)/64,64,0,stream>>>(out, 12345.0f, out_size);
    return;
  }

  embed_k<<<NTOK,128,0,stream>>>(str_fea, comp_fea, atom_table, comp_W, comp_b,
                                 pdd_W, pdd_b, x, x_init, w);
  for (int i=0;i<LL;i++){
    const float* gi = enc_ln_g + i*EE;
    const float* bi = enc_ln_b + i*EE;
    ln_k<true><<<NTOK,128,0,stream>>>(x, nullptr, gi, bi, xn_bf);
    tconv_k<<<(EE*3*EHH+255)/256,256,0,stream>>>(
        qkv_W + (size_t)i*EE*3*EHH, qkvWT, EE, 3*EHH);
    fuse_w_k<<<(EHH*EE+255)/256,256,0,stream>>>(
        o_W + (size_t)i*EHH*EHH, out_W + (size_t)i*EHH*EE, fwT);
    fuse_b_k<<<1,128,0,stream>>>(
        o_b + (size_t)i*EHH, out_W + (size_t)i*EHH*EE, out_b + (size_t)i*EE, fb);
    tconv_k<<<(EE*EE+255)/256,256,0,stream>>>(
        ffn_W + (size_t)i*EE*EE, ffnWT, EE, EE);
    for (int cb=0; cb<NCHUNK; cb++){
      const int t0 = cb*CTOK;
      const int b0 = cb*CB;
      // QKV: (CTOK x 128) @ (128 x 3072) -> qkvc f32   [MFMA]
      mgemm_k<1,128,128><<<dim3(3*EHH/128, CTOK/128),256,0,stream>>>(
          xn_bf + (size_t)t0*EE, qkvWT, qkv_b + (size_t)i*3*EHH, nullptr,
          qkvc, 3*EHH, EE);
      attn_rb_k<<<dim3(SEQ/64,HH,CB),256,0,stream>>>(qkvc, w, vals_bf, b0);
      // proj: (CTOK x 1024) @ (1024 x 128) + resid -> out1   [MFMA]
      mgemm_k<2,64,128><<<dim3(1, CTOK/64),256,0,stream>>>(
          vals_bf, fwT, fb, x + (size_t)t0*EE, out1 + (size_t)t0*EE, EE, EHH);
    }
    ln_k<true><<<NTOK,128,0,stream>>>(out1, nullptr, gi, bi, xn_bf);
    // ffn: (NTOK x 128) @ (128 x 128) + mish -> out2   [MFMA]
    mgemm_k<3,64,128><<<dim3(1, NTOK/64),256,0,stream>>>(
        xn_bf, ffnWT, ffn_b + (size_t)i*EE, nullptr, out2, EE, EE);
    ln_k<false><<<NTOK,128,0,stream>>>(out1, out2, gi, bi, x);
  }
  pool_head_k<<<BB,128,0,stream>>>(x, x_init, w, ln2_g, ln2_b, head_W, head_b, out);
}

// Round 11
// 1376.374 us; speedup vs baseline: 15.7544x; 2.0534x over previous
//
#include <hip/hip_runtime.h>
#include <math.h>

#define DI __device__ __forceinline__

// ---- problem constants ----
#define BB 32
#define SEQ 512
#define KF 101
#define EE 128
#define HH 8
#define EHH 1024
#define LL 3
#define ADIM 200
#define NTOK (BB*SEQ)   // 16384
#define CB 8            // batches per chunk
#define NCHUNK (BB/CB)  // 4
#define CTOK (CB*SEQ)   // 4096 tokens per chunk

// R10 post-mortem: MFMA GEMMs good (2.83ms, absmax 9.8e-4); attention is 70%
// (12x163us, f32 VALU). R11: bf16 qkvc + full-MFMA attention (S=QK^T and PV
// via mfma_16x16x32_bf16, layouts validated by R10's passing mgemm), V
// transposed to LDS with conflict-free scatter, P via LDS bf16. vals_bf goes
// full-size so proj/FFN run once per layer (grid 256).

typedef unsigned short u16;
typedef __attribute__((ext_vector_type(8))) short bf16x8;
typedef __attribute__((ext_vector_type(4))) float f32x4;

DI float bf2f(u16 s){ union{unsigned int u; float f;} x; x.u = ((unsigned int)s)<<16; return x.f; }
DI u16 f2bf(float f){
  union{float f; unsigned int u;} x; x.f = f;
  unsigned int u = x.u;
  u += 0x7fffu + ((u>>16)&1u);           // RNE
  return (u16)(u>>16);
}

// =================== sentinel ===================
__global__ void sentinel_k(float* out, float v, int n){
  int i = blockIdx.x*64 + threadIdx.x;
  if (i < n) out[i] = v;
}

// =================== embed ===================
__global__ __launch_bounds__(128) void embed_k(
    const float* __restrict__ str_fea, const int* __restrict__ comp_fea,
    const float* __restrict__ atom_table, const float* __restrict__ comp_W,
    const float* __restrict__ comp_b, const float* __restrict__ pdd_W,
    const float* __restrict__ pdd_b,
    float* __restrict__ x, float* __restrict__ x_init, float* __restrict__ w)
{
  const int t = blockIdx.x;
  const int e = threadIdx.x;
  __shared__ float sAtom[ADIM];
  __shared__ float sStr[104];
  const int idx = comp_fea[t];
  for (int a=e;a<ADIM;a+=128) sAtom[a] = atom_table[idx*ADIM+a];
  for (int a=e;a<KF;a+=128)  sStr[a]  = str_fea[(size_t)t*KF+a];
  __syncthreads();
  float acc = comp_b[e] + pdd_b[e];
  #pragma unroll 4
  for (int a=0;a<ADIM;a++) acc = fmaf(sAtom[a], comp_W[a*EE+e], acc);
  #pragma unroll 4
  for (int j=0;j<KF-1;j++) acc = fmaf(sStr[1+j], pdd_W[j*EE+e], acc);
  x[(size_t)t*EE+e] = acc;
  x_init[(size_t)t*EE+e] = acc;
  if (e==0) w[t] = sStr[0];
}

// =================== layernorm (E=128), optional add; f32 or bf16 output ===================
template<bool OBF>
__global__ __launch_bounds__(128) void ln_k(
    const float* __restrict__ in, const float* __restrict__ add,
    const float* __restrict__ g, const float* __restrict__ bta,
    void* __restrict__ outv)
{
  const int t = blockIdx.x;
  const int e = threadIdx.x;
  __shared__ float red[128];
  float v = in[(size_t)t*EE+e];
  if (add) v += add[(size_t)t*EE+e];
  red[e] = v; __syncthreads();
  for (int s=64;s>0;s>>=1){ if (e<s) red[e]+=red[e+s]; __syncthreads(); }
  const float mean = red[0]*(1.0f/128.0f);
  __syncthreads();
  const float d = v-mean;
  red[e] = d*d; __syncthreads();
  for (int s=64;s>0;s>>=1){ if (e<s) red[e]+=red[e+s]; __syncthreads(); }
  const float var = red[0]*(1.0f/128.0f);
  const float r = d*rsqrtf(var+1e-5f)*g[e] + bta[e];
  if constexpr (OBF) ((u16*)outv)[(size_t)t*EE+e] = f2bf(r);
  else               ((float*)outv)[(size_t)t*EE+e] = r;
}

// =================== weight convert+transpose: W (Kk x Nn f32) -> WT (Nn x Kk bf16) ===================
__global__ __launch_bounds__(256) void tconv_k(
    const float* __restrict__ W, u16* __restrict__ WT, int Kk, int Nn)
{
  const int idx = blockIdx.x*256 + threadIdx.x;
  if (idx >= Kk*Nn) return;
  const int k = idx / Nn, n = idx - k*Nn;
  WT[(size_t)n*Kk + k] = f2bf(W[idx]);
}

// =================== MFMA bf16 GEMM ===================
// A: M x Kk bf16 row-major. BT: Nn x Kk bf16 (pre-transposed B).
// EPI 0: store bf16; 2: f32 +resid; 3: f32 mish.
template<int EPI, int BM, int BN>
__global__ __launch_bounds__(256) void mgemm_k(
    const u16* __restrict__ A, const u16* __restrict__ BT,
    const float* __restrict__ bias, const float* __restrict__ resid,
    void* __restrict__ C, int Nn, int Kk)
{
  constexpr int BK  = 64;
  constexpr int LDK = BK + 8;
  __shared__ u16 As[BM*LDK];
  __shared__ u16 Bs[BN*LDK];
  const int tid = threadIdx.x;
  const int m0 = blockIdx.y*BM, n0 = blockIdx.x*BN;
  constexpr int WMN = (BM>=128)?2:1;
  constexpr int WNN = 4/WMN;
  constexpr int WM = BM/WMN;
  constexpr int WN = BN/WNN;
  constexpr int FM = WM/16, FN = WN/16;
  const int wv = tid>>6, lane = tid&63;
  const int wm = (wv/WNN)*WM;
  const int wn = (wv%WNN)*WN;
  const int lm = lane&15, lq = lane>>4;

  f32x4 acc[FM][FN];
  #pragma unroll
  for (int i=0;i<FM;i++)
    #pragma unroll
    for (int j=0;j<FN;j++) acc[i][j] = (f32x4){0.f,0.f,0.f,0.f};

  constexpr int ACH = BM*BK/8;
  constexpr int BCH = BN*BK/8;

  for (int k0=0; k0<Kk; k0+=BK){
    #pragma unroll
    for (int c = tid; c < ACH; c += 256){
      const int r = c/(BK/8), kg = c - r*(BK/8);
      const float4 v = *(const float4*)(A + (size_t)(m0+r)*Kk + k0 + kg*8);
      *(float4*)&As[r*LDK + kg*8] = v;
    }
    #pragma unroll
    for (int c = tid; c < BCH; c += 256){
      const int r = c/(BK/8), kg = c - r*(BK/8);
      const float4 v = *(const float4*)(BT + (size_t)(n0+r)*Kk + k0 + kg*8);
      *(float4*)&Bs[r*LDK + kg*8] = v;
    }
    __syncthreads();
    #pragma unroll
    for (int kk=0; kk<BK/32; kk++){
      bf16x8 af[FM], bfr[FN];
      #pragma unroll
      for (int i=0;i<FM;i++)
        af[i] = *(const bf16x8*)&As[(wm + i*16 + lm)*LDK + kk*32 + lq*8];
      #pragma unroll
      for (int j=0;j<FN;j++)
        bfr[j] = *(const bf16x8*)&Bs[(wn + j*16 + lm)*LDK + kk*32 + lq*8];
      #pragma unroll
      for (int i=0;i<FM;i++)
        #pragma unroll
        for (int j=0;j<FN;j++)
          acc[i][j] = __builtin_amdgcn_mfma_f32_16x16x32_bf16(af[i], bfr[j], acc[i][j], 0, 0, 0);
    }
    __syncthreads();
  }
  #pragma unroll
  for (int i=0;i<FM;i++){
    #pragma unroll
    for (int j=0;j<FN;j++){
      const int col = n0 + wn + j*16 + lm;
      const float bv = bias[col];
      #pragma unroll
      for (int r=0;r<4;r++){
        const int row = m0 + wm + i*16 + lq*4 + r;
        float v = acc[i][j][r] + bv;
        const size_t gi = (size_t)row*Nn + col;
        if constexpr (EPI==0)      ((u16*)C)[gi] = f2bf(v);
        else if constexpr (EPI==2) ((float*)C)[gi] = v + resid[gi];
        else { const float sp=(v>20.f)?v:log1pf(expf(v)); ((float*)C)[gi]=v*tanhf(sp); }
      }
    }
  }
}

// =================== fused projection precompute (fwT bf16, N x K) ===================
__global__ __launch_bounds__(256) void fuse_w_k(
    const float* __restrict__ oW, const float* __restrict__ outW, u16* __restrict__ fwT)
{
  const int idx = blockIdx.x*256 + threadIdx.x;   // EHH*EE = 131072
  if (idx >= EHH*EE) return;
  const int k1 = idx >> 7, n = idx & 127;
  float acc = 0.f;
  #pragma unroll 8
  for (int k2=0;k2<EHH;k2++) acc = fmaf(oW[(size_t)k1*EHH+k2], outW[(size_t)k2*EE+n], acc);
  fwT[(size_t)n*EHH + k1] = f2bf(acc);
}
__global__ __launch_bounds__(128) void fuse_b_k(
    const float* __restrict__ ob, const float* __restrict__ outW,
    const float* __restrict__ outb, float* __restrict__ fb)
{
  const int n = threadIdx.x;
  float acc = outb[n];
  for (int k2=0;k2<EHH;k2++) acc = fmaf(ob[k2], outW[(size_t)k2*EE+n], acc);
  fb[n] = acc;
}

// =================== MFMA flash attention over a batch chunk ===================
// qkvc: (CTOK, 3072) bf16 token-major; col h*384 + {0:q,128:k,256:v}+d.
// Block = (64q, h, bl); 4 waves, wave wv owns q rows wv*16..+15.
// S = QK^T: A-frag Qs rows, B-frag Ks rows (K tile IS the NxK operand).
// P: C-layout regs -> Ps bf16 [q][k] (A-layout for PV).
// PV: B-frag from Vts = V^T [d][k] (staged with conflict-free b16 scatter).
__global__ __launch_bounds__(256) void attn_mf_k(
    const u16* __restrict__ qkvc, const float* __restrict__ w,
    u16* __restrict__ vals_c, int b0)
{
  const int qt = blockIdx.x;   // 0..7
  const int h  = blockIdx.y;   // 0..7
  const int bl = blockIdx.z;   // 0..CB-1
  const int tid = threadIdx.x;
  const int wv = tid>>6, lane = tid&63;
  const int lm = lane&15, lq = lane>>4;

  __shared__ u16 Qs[64][136];
  __shared__ u16 Ks[64][136];
  __shared__ u16 Vts[128][72];
  __shared__ u16 Ps[64][72];
  __shared__ float wt[64], qwt[64];

  const size_t rs = 3072;
  const u16* base = qkvc + (size_t)bl*SEQ*rs + (size_t)h*384;
  const int q0 = qt*64;

  // ---- stage Q tile (bf16 rows, 16B chunks) ----
  #pragma unroll
  for (int it=0; it<4; it++){
    const int fi = it*256 + tid;
    const int r = fi >> 4, g = fi & 15;
    *(float4*)&Qs[r][g*8] = *(const float4*)(base + (size_t)(q0+r)*rs + g*8);
  }
  if (tid < 64) qwt[tid] = w[(b0+bl)*SEQ + q0 + tid];
  __syncthreads();

  float kq[4];
  #pragma unroll
  for (int r=0;r<4;r++) kq[r] = qwt[wv*16 + lq*4 + r];

  f32x4 oacc[8];
  #pragma unroll
  for (int j=0;j<8;j++) oacc[j] = (f32x4){0.f,0.f,0.f,0.f};
  float mrow[4], lrow[4];
  #pragma unroll
  for (int r=0;r<4;r++){ mrow[r]=-INFINITY; lrow[r]=0.f; }
  const float scale = 0.08838834764831845f;  // 1/sqrt(128)

  for (int kt=0; kt<8; kt++){
    __syncthreads();   // prior kt's MFMA reads done; restage
    // ---- stage K rows ----
    #pragma unroll
    for (int it=0; it<4; it++){
      const int fi = it*256 + tid;
      const int r = fi >> 4, g = fi & 15;
      *(float4*)&Ks[r][g*8] = *(const float4*)(base + (size_t)(kt*64+r)*rs + 128 + g*8);
    }
    // ---- stage V^T: k = lane (consec banks), d-group wave-uniform ----
    #pragma unroll
    for (int it=0; it<4; it++){
      const int fi = it*256 + tid;
      const int k = fi & 63, dg = fi >> 6;
      union { float4 f4; u16 u[8]; } cv;
      cv.f4 = *(const float4*)(base + (size_t)(kt*64+k)*rs + 256 + dg*8);
      #pragma unroll
      for (int e=0;e<8;e++) Vts[dg*8+e][k] = cv.u[e];
    }
    if (tid < 64) wt[tid] = w[(b0+bl)*SEQ + kt*64 + tid];
    __syncthreads();

    // ---- S = Q K^T ----
    f32x4 sacc[4];
    #pragma unroll
    for (int j=0;j<4;j++) sacc[j] = (f32x4){0.f,0.f,0.f,0.f};
    #pragma unroll
    for (int kk=0; kk<4; kk++){
      const bf16x8 af = *(const bf16x8*)&Qs[wv*16+lm][kk*32+lq*8];
      #pragma unroll
      for (int j=0;j<4;j++){
        const bf16x8 bf = *(const bf16x8*)&Ks[j*16+lm][kk*32+lq*8];
        sacc[j] = __builtin_amdgcn_mfma_f32_16x16x32_bf16(af, bf, sacc[j], 0, 0, 0);
      }
    }
    // ---- mask + scale (C-layout: row=wv*16+lq*4+r, col=j*16+lm) ----
    float wkj[4], s[4][4];
    #pragma unroll
    for (int j=0;j<4;j++) wkj[j] = wt[j*16+lm];
    #pragma unroll
    for (int j=0;j<4;j++)
      #pragma unroll
      for (int r=0;r<4;r++){
        const bool keep = (kq[r] > 0.f) && (wkj[j] > 0.f);
        s[j][r] = keep ? sacc[j][r]*scale : -9.0e15f;
      }
    // ---- online softmax per row (reduce over lm bits 1,2,4,8) ----
    float alpha[4];
    #pragma unroll
    for (int r=0;r<4;r++){
      float rm = fmaxf(fmaxf(s[0][r], s[1][r]), fmaxf(s[2][r], s[3][r]));
      rm = fmaxf(rm, __shfl_xor(rm, 1));
      rm = fmaxf(rm, __shfl_xor(rm, 2));
      rm = fmaxf(rm, __shfl_xor(rm, 4));
      rm = fmaxf(rm, __shfl_xor(rm, 8));
      const float newm = fmaxf(mrow[r], rm);
      alpha[r] = expf(mrow[r] - newm);
      float ls = 0.f;
      #pragma unroll
      for (int j=0;j<4;j++){
        const float pv = wkj[j]*expf(s[j][r]-newm);
        s[j][r] = pv; ls += pv;
      }
      ls += __shfl_xor(ls, 1);
      ls += __shfl_xor(ls, 2);
      ls += __shfl_xor(ls, 4);
      ls += __shfl_xor(ls, 8);
      lrow[r] = lrow[r]*alpha[r] + ls;
      mrow[r] = newm;
    }
    // ---- write P bf16 [q][k]; rescale O ----
    #pragma unroll
    for (int j=0;j<4;j++)
      #pragma unroll
      for (int r=0;r<4;r++)
        Ps[wv*16 + lq*4 + r][j*16+lm] = f2bf(s[j][r]);
    #pragma unroll
    for (int j=0;j<8;j++)
      #pragma unroll
      for (int r=0;r<4;r++) oacc[j][r] *= alpha[r];
    __syncthreads();   // P visible (and Vts staged)

    // ---- O += P V ----
    #pragma unroll
    for (int kk=0; kk<2; kk++){
      const bf16x8 pf = *(const bf16x8*)&Ps[wv*16+lm][kk*32+lq*8];
      #pragma unroll
      for (int j=0;j<8;j++){
        const bf16x8 vf = *(const bf16x8*)&Vts[j*16+lm][kk*32+lq*8];
        oacc[j] = __builtin_amdgcn_mfma_f32_16x16x32_bf16(pf, vf, oacc[j], 0, 0, 0);
      }
    }
  }
  // ---- normalize + write bf16 ----
  #pragma unroll
  for (int r=0;r<4;r++){
    const float inv = 1.0f / lrow[r];
    u16* orow = vals_c + ((size_t)(bl*SEQ + q0 + wv*16 + lq*4 + r))*EHH + h*EE;
    #pragma unroll
    for (int j=0;j<8;j++) orow[j*16+lm] = f2bf(oacc[j][r]*inv);
  }
}

// =================== pool + LN + head ===================
__global__ __launch_bounds__(128) void pool_head_k(
    const float* __restrict__ x, const float* __restrict__ x_init,
    const float* __restrict__ w, const float* __restrict__ g2, const float* __restrict__ b2,
    const float* __restrict__ head_W, const float* __restrict__ head_b,
    float* __restrict__ out)
{
  const int b = blockIdx.x;
  const int e = threadIdx.x;
  __shared__ float red[128];
  float acc = 0.f;
  for (int n=0;n<SEQ;n++){
    const size_t idx = ((size_t)(b*SEQ+n))*EE + e;
    acc = fmaf(w[b*SEQ+n], x[idx]+x_init[idx], acc);
  }
  red[e]=acc; __syncthreads();
  for (int s=64;s>0;s>>=1){ if(e<s) red[e]+=red[e+s]; __syncthreads(); }
  const float mean = red[0]*(1.0f/128.0f);
  __syncthreads();
  const float d = acc-mean;
  red[e]=d*d; __syncthreads();
  for (int s=64;s>0;s>>=1){ if(e<s) red[e]+=red[e+s]; __syncthreads(); }
  const float var = red[0]*(1.0f/128.0f);
  const float p = d*rsqrtf(var+1e-5f)*g2[e]+b2[e];
  __syncthreads();
  red[e] = p*head_W[e]; __syncthreads();
  for (int s=64;s>0;s>>=1){ if(e<s) red[e]+=red[e+s]; __syncthreads(); }
  if (e==0) out[b] = red[0] + head_b[0];
}

// =================== launch ===================
extern "C" void kernel_launch(void* const* d_in, const int* in_sizes, int n_in,
                              void* d_out, int out_size, void* d_ws, size_t ws_size,
                              hipStream_t stream)
{
  const float* str_fea   = (const float*)d_in[0];
  const int*   comp_fea  = (const int*)  d_in[1];
  // d_in[2] cell_fea unused by reference
  const float* atom_table= (const float*)d_in[3];
  const float* comp_W    = (const float*)d_in[4];
  const float* comp_b    = (const float*)d_in[5];
  const float* pdd_W     = (const float*)d_in[6];
  const float* pdd_b     = (const float*)d_in[7];
  const float* enc_ln_g  = (const float*)d_in[8];
  const float* enc_ln_b  = (const float*)d_in[9];
  const float* qkv_W     = (const float*)d_in[10];
  const float* qkv_b     = (const float*)d_in[11];
  const float* o_W       = (const float*)d_in[12];
  const float* o_b       = (const float*)d_in[13];
  const float* out_W     = (const float*)d_in[14];
  const float* out_b     = (const float*)d_in[15];
  const float* ffn_W     = (const float*)d_in[16];
  const float* ffn_b     = (const float*)d_in[17];
  const float* ln2_g     = (const float*)d_in[18];
  const float* ln2_b     = (const float*)d_in[19];
  const float* head_W    = (const float*)d_in[20];
  const float* head_b    = (const float*)d_in[21];
  float* out = (float*)d_out;

  // ---- diagnostic 1: input layout model ----
  bool sizes_ok = (n_in >= 22);
  if (sizes_ok){
    sizes_ok = in_sizes[0]==BB*SEQ*KF && in_sizes[1]==NTOK &&
               in_sizes[3]==119*ADIM  && in_sizes[4]==ADIM*EE &&
               in_sizes[10]==LL*EE*3*EHH && in_sizes[12]==LL*EHH*EHH &&
               in_sizes[14]==LL*EHH*EE   && in_sizes[16]==LL*EE*EE &&
               in_sizes[20]==EE;
  }
  if (!sizes_ok){
    sentinel_k<<<(out_size+63)/64,64,0,stream>>>(out, 99999.0f, out_size);
    return;
  }

  // ---- workspace layout (~96 MB; <= 107.7 MB proven) ----
  char* p = (char*)d_ws;
  size_t off = 0;
  auto alloc = [&](size_t bytes)->void*{
    off = (off + 255) & ~(size_t)255;
    void* r = p + off; off += bytes; return r;
  };
  float* w      = (float*)alloc((size_t)NTOK*4);
  float* x      = (float*)alloc((size_t)NTOK*EE*4);
  float* x_init = (float*)alloc((size_t)NTOK*EE*4);
  u16*   xn_bf  = (u16*)  alloc((size_t)NTOK*EE*2);
  float* out1   = (float*)alloc((size_t)NTOK*EE*4);
  float* out2   = (float*)alloc((size_t)NTOK*EE*4);
  u16*   qkvc   = (u16*)  alloc((size_t)CTOK*3*EHH*2);   // 25.2 MB chunk (bf16)
  u16*   vals_bf= (u16*)  alloc((size_t)NTOK*EHH*2);     // 33.6 MB full
  u16*   qkvWT  = (u16*)  alloc((size_t)3*EHH*EE*2);
  u16*   fwT    = (u16*)  alloc((size_t)EE*EHH*2);
  u16*   ffnWT  = (u16*)  alloc((size_t)EE*EE*2);
  float* fb     = (float*)alloc((size_t)EE*4);

  // ---- diagnostic 2: workspace size ----
  if (off > ws_size){
    sentinel_k<<<(out_size+63)/64,64,0,stream>>>(out, 12345.0f, out_size);
    return;
  }

  embed_k<<<NTOK,128,0,stream>>>(str_fea, comp_fea, atom_table, comp_W, comp_b,
                                 pdd_W, pdd_b, x, x_init, w);
  for (int i=0;i<LL;i++){
    const float* gi = enc_ln_g + i*EE;
    const float* bi = enc_ln_b + i*EE;
    ln_k<true><<<NTOK,128,0,stream>>>(x, nullptr, gi, bi, xn_bf);
    tconv_k<<<(EE*3*EHH+255)/256,256,0,stream>>>(
        qkv_W + (size_t)i*EE*3*EHH, qkvWT, EE, 3*EHH);
    fuse_w_k<<<(EHH*EE+255)/256,256,0,stream>>>(
        o_W + (size_t)i*EHH*EHH, out_W + (size_t)i*EHH*EE, fwT);
    fuse_b_k<<<1,128,0,stream>>>(
        o_b + (size_t)i*EHH, out_W + (size_t)i*EHH*EE, out_b + (size_t)i*EE, fb);
    tconv_k<<<(EE*EE+255)/256,256,0,stream>>>(
        ffn_W + (size_t)i*EE*EE, ffnWT, EE, EE);
    for (int cb=0; cb<NCHUNK; cb++){
      const int t0 = cb*CTOK;
      const int b0 = cb*CB;
      // QKV: (CTOK x 128) @ (128 x 3072) -> qkvc bf16   [MFMA]
      mgemm_k<0,128,128><<<dim3(3*EHH/128, CTOK/128),256,0,stream>>>(
          xn_bf + (size_t)t0*EE, qkvWT, qkv_b + (size_t)i*3*EHH, nullptr,
          qkvc, 3*EHH, EE);
      // attention (MFMA) -> vals_bf
      attn_mf_k<<<dim3(SEQ/64,HH,CB),256,0,stream>>>(
          qkvc, w, vals_bf + (size_t)t0*EHH, b0);
    }
    // proj: (NTOK x 1024) @ (1024 x 128) + resid -> out1   [MFMA, 256 blocks]
    mgemm_k<2,64,128><<<dim3(1, NTOK/64),256,0,stream>>>(
        vals_bf, fwT, fb, x, out1, EE, EHH);
    ln_k<true><<<NTOK,128,0,stream>>>(out1, nullptr, gi, bi, xn_bf);
    // ffn: (NTOK x 128) @ (128 x 128) + mish -> out2   [MFMA, 256 blocks]
    mgemm_k<3,64,128><<<dim3(1, NTOK/64),256,0,stream>>>(
        xn_bf, ffnWT, ffn_b + (size_t)i*EE, nullptr, out2, EE, EE);
    ln_k<false><<<NTOK,128,0,stream>>>(out1, out2, gi, bi, x);
  }
  pool_head_k<<<BB,128,0,stream>>>(x, x_init, w, ln2_g, ln2_b, head_W, head_b, out);
}

// Round 12
// 1285.278 us; speedup vs baseline: 16.8711x; 1.0709x over previous
//
#include <hip/hip_runtime.h>
#include <math.h>

#define DI __device__ __forceinline__

// ---- problem constants ----
#define BB 32
#define SEQ 512
#define KF 101
#define EE 128
#define HH 8
#define EHH 1024
#define LL 3
#define ADIM 200
#define NATOM 119
#define NTOK (BB*SEQ)   // 16384
#define CB 8            // batches per chunk
#define NCHUNK (BB/CB)  // 4
#define CTOK (CB*SEQ)   // 4096 tokens per chunk

// R11 post-mortem: 1376us; embed_k (106us serial K=300 GEMV) now top dispatch.
// R12: (1) atom_emb precompute (119 rows) -> embed = gather + K=100 GEMV;
// (2) fuse_w naive (uncoalesced 1024-loop) -> MFMA GEMM w/ transposed store;
// coalesced weight converts (LDS-tiled transpose); (3) LN wave-per-token
// (no barriers), two-phase pool. Attention/GEMM cores unchanged (R11 passed).

typedef unsigned short u16;
typedef __attribute__((ext_vector_type(8))) short bf16x8;
typedef __attribute__((ext_vector_type(4))) float f32x4;

DI float bf2f(u16 s){ union{unsigned int u; float f;} x; x.u = ((unsigned int)s)<<16; return x.f; }
DI u16 f2bf(float f){
  union{float f; unsigned int u;} x; x.f = f;
  unsigned int u = x.u;
  u += 0x7fffu + ((u>>16)&1u);           // RNE
  return (u16)(u>>16);
}

// =================== sentinel ===================
__global__ void sentinel_k(float* out, float v, int n){
  int i = blockIdx.x*64 + threadIdx.x;
  if (i < n) out[i] = v;
}

// =================== atom embedding precompute: atom_emb = atom_table@comp_W + comp_b + pdd_b ===================
__global__ __launch_bounds__(128) void atomemb_k(
    const float* __restrict__ atom_table, const float* __restrict__ comp_W,
    const float* __restrict__ comp_b, const float* __restrict__ pdd_b,
    float* __restrict__ atom_emb)
{
  const int a = blockIdx.x;      // 0..NATOM-1
  const int e = threadIdx.x;
  __shared__ float sAtom[ADIM];
  for (int d=e; d<ADIM; d+=128) sAtom[d] = atom_table[a*ADIM+d];
  __syncthreads();
  float acc = comp_b[e] + pdd_b[e];
  #pragma unroll 4
  for (int d=0; d<ADIM; d++) acc = fmaf(sAtom[d], comp_W[d*EE+e], acc);
  atom_emb[a*EE+e] = acc;
}

// =================== embed: x = atom_emb[idx] + str[1:]@pdd_W ===================
__global__ __launch_bounds__(128) void embed_k(
    const float* __restrict__ str_fea, const int* __restrict__ comp_fea,
    const float* __restrict__ atom_emb, const float* __restrict__ pdd_W,
    float* __restrict__ x, float* __restrict__ x_init, float* __restrict__ w)
{
  const int t = blockIdx.x;
  const int e = threadIdx.x;
  __shared__ float sStr[104];
  if (e < KF) sStr[e] = str_fea[(size_t)t*KF+e];
  __syncthreads();
  const int idx = comp_fea[t];
  float a0 = atom_emb[idx*EE+e], a1 = 0.f, a2 = 0.f, a3 = 0.f;
  #pragma unroll
  for (int j=0; j<100; j+=4){
    a0 = fmaf(sStr[1+j],   pdd_W[(j  )*EE+e], a0);
    a1 = fmaf(sStr[2+j],   pdd_W[(j+1)*EE+e], a1);
    a2 = fmaf(sStr[3+j],   pdd_W[(j+2)*EE+e], a2);
    a3 = fmaf(sStr[4+j],   pdd_W[(j+3)*EE+e], a3);
  }
  const float acc = (a0+a1)+(a2+a3);
  x[(size_t)t*EE+e] = acc;
  x_init[(size_t)t*EE+e] = acc;
  if (e==0) w[t] = sStr[0];
}

// =================== layernorm: wave per token (4 tokens / 256-block), no barriers ===================
template<bool OBF>
__global__ __launch_bounds__(256) void ln_k(
    const float* __restrict__ in, const float* __restrict__ add,
    const float* __restrict__ g, const float* __restrict__ bta,
    void* __restrict__ outv)
{
  const int wv = threadIdx.x >> 6, lane = threadIdx.x & 63;
  const int t = blockIdx.x*4 + wv;
  float2 v = ((const float2*)(in + (size_t)t*EE))[lane];
  if (add){
    const float2 a = ((const float2*)(add + (size_t)t*EE))[lane];
    v.x += a.x; v.y += a.y;
  }
  float s = v.x + v.y;
  #pragma unroll
  for (int off=32; off; off>>=1) s += __shfl_xor(s, off);
  const float mean = s*(1.0f/128.0f);
  const float d0 = v.x-mean, d1 = v.y-mean;
  float q = d0*d0 + d1*d1;
  #pragma unroll
  for (int off=32; off; off>>=1) q += __shfl_xor(q, off);
  const float rstd = rsqrtf(q*(1.0f/128.0f) + 1e-5f);
  const float2 gg = ((const float2*)g)[lane];
  const float2 bb = ((const float2*)bta)[lane];
  const float r0 = d0*rstd*gg.x + bb.x;
  const float r1 = d1*rstd*gg.y + bb.y;
  if constexpr (OBF){
    u16* o = (u16*)outv + (size_t)t*EE + lane*2;
    o[0] = f2bf(r0); o[1] = f2bf(r1);
  } else {
    float2* o = (float2*)((float*)outv + (size_t)t*EE);
    o[lane] = make_float2(r0, r1);
  }
}

// =================== coalesced convert: f32 -> bf16 (same layout) ===================
__global__ __launch_bounds__(256) void cconv_k(
    const float* __restrict__ W, u16* __restrict__ Wb, int n)
{
  const int i = blockIdx.x*256 + threadIdx.x;
  if (i < n) Wb[i] = f2bf(W[i]);
}

// =================== LDS-tiled transpose convert: W (Kk x Nn f32) -> WT (Nn x Kk bf16) ===================
__global__ __launch_bounds__(256) void tconvT_k(
    const float* __restrict__ W, u16* __restrict__ WT, int Kk, int Nn)
{
  __shared__ u16 tile[32][33];
  const int n0 = blockIdx.x*32, k0 = blockIdx.y*32;
  const int lr = threadIdx.x >> 5, lc = threadIdx.x & 31;
  #pragma unroll
  for (int i=0;i<4;i++){
    const int k = k0 + lr + i*8;
    tile[lr+i*8][lc] = f2bf(W[(size_t)k*Nn + n0 + lc]);
  }
  __syncthreads();
  #pragma unroll
  for (int i=0;i<4;i++){
    const int n = n0 + lr + i*8;
    WT[(size_t)n*Kk + k0 + lc] = tile[lc][lr+i*8];
  }
}

// =================== MFMA bf16 GEMM ===================
// A: M x Kk bf16 row-major. BT: Nn x Kk bf16 (pre-transposed B).
// EPI 0: store bf16; 2: f32 +resid; 3: f32 mish; 4: store bf16 TRANSPOSED
// (C[col*M + row], M passed via Mdim) with no bias.
template<int EPI, int BM, int BN>
__global__ __launch_bounds__(256) void mgemm_k(
    const u16* __restrict__ A, const u16* __restrict__ BT,
    const float* __restrict__ bias, const float* __restrict__ resid,
    void* __restrict__ C, int Nn, int Kk, int Mdim)
{
  constexpr int BK  = 64;
  constexpr int LDK = BK + 8;
  __shared__ u16 As[BM*LDK];
  __shared__ u16 Bs[BN*LDK];
  const int tid = threadIdx.x;
  const int m0 = blockIdx.y*BM, n0 = blockIdx.x*BN;
  constexpr int WMN = (BM>=128)?2:1;
  constexpr int WNN = 4/WMN;
  constexpr int WM = BM/WMN;
  constexpr int WN = BN/WNN;
  constexpr int FM = WM/16, FN = WN/16;
  const int wv = tid>>6, lane = tid&63;
  const int wm = (wv/WNN)*WM;
  const int wn = (wv%WNN)*WN;
  const int lm = lane&15, lq = lane>>4;

  f32x4 acc[FM][FN];
  #pragma unroll
  for (int i=0;i<FM;i++)
    #pragma unroll
    for (int j=0;j<FN;j++) acc[i][j] = (f32x4){0.f,0.f,0.f,0.f};

  constexpr int ACH = BM*BK/8;
  constexpr int BCH = BN*BK/8;

  for (int k0=0; k0<Kk; k0+=BK){
    #pragma unroll
    for (int c = tid; c < ACH; c += 256){
      const int r = c/(BK/8), kg = c - r*(BK/8);
      const float4 v = *(const float4*)(A + (size_t)(m0+r)*Kk + k0 + kg*8);
      *(float4*)&As[r*LDK + kg*8] = v;
    }
    #pragma unroll
    for (int c = tid; c < BCH; c += 256){
      const int r = c/(BK/8), kg = c - r*(BK/8);
      const float4 v = *(const float4*)(BT + (size_t)(n0+r)*Kk + k0 + kg*8);
      *(float4*)&Bs[r*LDK + kg*8] = v;
    }
    __syncthreads();
    #pragma unroll
    for (int kk=0; kk<BK/32; kk++){
      bf16x8 af[FM], bfr[FN];
      #pragma unroll
      for (int i=0;i<FM;i++)
        af[i] = *(const bf16x8*)&As[(wm + i*16 + lm)*LDK + kk*32 + lq*8];
      #pragma unroll
      for (int j=0;j<FN;j++)
        bfr[j] = *(const bf16x8*)&Bs[(wn + j*16 + lm)*LDK + kk*32 + lq*8];
      #pragma unroll
      for (int i=0;i<FM;i++)
        #pragma unroll
        for (int j=0;j<FN;j++)
          acc[i][j] = __builtin_amdgcn_mfma_f32_16x16x32_bf16(af[i], bfr[j], acc[i][j], 0, 0, 0);
    }
    __syncthreads();
  }
  #pragma unroll
  for (int i=0;i<FM;i++){
    #pragma unroll
    for (int j=0;j<FN;j++){
      const int col = n0 + wn + j*16 + lm;
      const float bv = (EPI==4) ? 0.f : bias[col];
      #pragma unroll
      for (int r=0;r<4;r++){
        const int row = m0 + wm + i*16 + lq*4 + r;
        float v = acc[i][j][r] + bv;
        if constexpr (EPI==4){
          ((u16*)C)[(size_t)col*Mdim + row] = f2bf(v);
        } else {
          const size_t gi = (size_t)row*Nn + col;
          if constexpr (EPI==0)      ((u16*)C)[gi] = f2bf(v);
          else if constexpr (EPI==2) ((float*)C)[gi] = v + resid[gi];
          else { const float sp=(v>20.f)?v:log1pf(expf(v)); ((float*)C)[gi]=v*tanhf(sp); }
        }
      }
    }
  }
}

// =================== fb = o_b@out_W + out_b ===================
__global__ __launch_bounds__(128) void fuse_b_k(
    const float* __restrict__ ob, const float* __restrict__ outW,
    const float* __restrict__ outb, float* __restrict__ fb)
{
  const int n = threadIdx.x;
  float acc = outb[n];
  for (int k2=0;k2<EHH;k2++) acc = fmaf(ob[k2], outW[(size_t)k2*EE+n], acc);
  fb[n] = acc;
}

// =================== MFMA flash attention over a batch chunk ===================
__global__ __launch_bounds__(256) void attn_mf_k(
    const u16* __restrict__ qkvc, const float* __restrict__ w,
    u16* __restrict__ vals_c, int b0)
{
  const int qt = blockIdx.x;   // 0..7
  const int h  = blockIdx.y;   // 0..7
  const int bl = blockIdx.z;   // 0..CB-1
  const int tid = threadIdx.x;
  const int wv = tid>>6, lane = tid&63;
  const int lm = lane&15, lq = lane>>4;

  __shared__ u16 Qs[64][136];
  __shared__ u16 Ks[64][136];
  __shared__ u16 Vts[128][72];
  __shared__ u16 Ps[64][72];
  __shared__ float wt[64], qwt[64];

  const size_t rs = 3072;
  const u16* base = qkvc + (size_t)bl*SEQ*rs + (size_t)h*384;
  const int q0 = qt*64;

  #pragma unroll
  for (int it=0; it<4; it++){
    const int fi = it*256 + tid;
    const int r = fi >> 4, g = fi & 15;
    *(float4*)&Qs[r][g*8] = *(const float4*)(base + (size_t)(q0+r)*rs + g*8);
  }
  if (tid < 64) qwt[tid] = w[(b0+bl)*SEQ + q0 + tid];
  __syncthreads();

  float kq[4];
  #pragma unroll
  for (int r=0;r<4;r++) kq[r] = qwt[wv*16 + lq*4 + r];

  f32x4 oacc[8];
  #pragma unroll
  for (int j=0;j<8;j++) oacc[j] = (f32x4){0.f,0.f,0.f,0.f};
  float mrow[4], lrow[4];
  #pragma unroll
  for (int r=0;r<4;r++){ mrow[r]=-INFINITY; lrow[r]=0.f; }
  const float scale = 0.08838834764831845f;  // 1/sqrt(128)

  for (int kt=0; kt<8; kt++){
    __syncthreads();
    #pragma unroll
    for (int it=0; it<4; it++){
      const int fi = it*256 + tid;
      const int r = fi >> 4, g = fi & 15;
      *(float4*)&Ks[r][g*8] = *(const float4*)(base + (size_t)(kt*64+r)*rs + 128 + g*8);
    }
    #pragma unroll
    for (int it=0; it<4; it++){
      const int fi = it*256 + tid;
      const int k = fi & 63, dg = fi >> 6;
      union { float4 f4; u16 u[8]; } cv;
      cv.f4 = *(const float4*)(base + (size_t)(kt*64+k)*rs + 256 + dg*8);
      #pragma unroll
      for (int e=0;e<8;e++) Vts[dg*8+e][k] = cv.u[e];
    }
    if (tid < 64) wt[tid] = w[(b0+bl)*SEQ + kt*64 + tid];
    __syncthreads();

    f32x4 sacc[4];
    #pragma unroll
    for (int j=0;j<4;j++) sacc[j] = (f32x4){0.f,0.f,0.f,0.f};
    #pragma unroll
    for (int kk=0; kk<4; kk++){
      const bf16x8 af = *(const bf16x8*)&Qs[wv*16+lm][kk*32+lq*8];
      #pragma unroll
      for (int j=0;j<4;j++){
        const bf16x8 bf = *(const bf16x8*)&Ks[j*16+lm][kk*32+lq*8];
        sacc[j] = __builtin_amdgcn_mfma_f32_16x16x32_bf16(af, bf, sacc[j], 0, 0, 0);
      }
    }
    float wkj[4], s[4][4];
    #pragma unroll
    for (int j=0;j<4;j++) wkj[j] = wt[j*16+lm];
    #pragma unroll
    for (int j=0;j<4;j++)
      #pragma unroll
      for (int r=0;r<4;r++){
        const bool keep = (kq[r] > 0.f) && (wkj[j] > 0.f);
        s[j][r] = keep ? sacc[j][r]*scale : -9.0e15f;
      }
    float alpha[4];
    #pragma unroll
    for (int r=0;r<4;r++){
      float rm = fmaxf(fmaxf(s[0][r], s[1][r]), fmaxf(s[2][r], s[3][r]));
      rm = fmaxf(rm, __shfl_xor(rm, 1));
      rm = fmaxf(rm, __shfl_xor(rm, 2));
      rm = fmaxf(rm, __shfl_xor(rm, 4));
      rm = fmaxf(rm, __shfl_xor(rm, 8));
      const float newm = fmaxf(mrow[r], rm);
      alpha[r] = expf(mrow[r] - newm);
      float ls = 0.f;
      #pragma unroll
      for (int j=0;j<4;j++){
        const float pv = wkj[j]*expf(s[j][r]-newm);
        s[j][r] = pv; ls += pv;
      }
      ls += __shfl_xor(ls, 1);
      ls += __shfl_xor(ls, 2);
      ls += __shfl_xor(ls, 4);
      ls += __shfl_xor(ls, 8);
      lrow[r] = lrow[r]*alpha[r] + ls;
      mrow[r] = newm;
    }
    #pragma unroll
    for (int j=0;j<4;j++)
      #pragma unroll
      for (int r=0;r<4;r++)
        Ps[wv*16 + lq*4 + r][j*16+lm] = f2bf(s[j][r]);
    #pragma unroll
    for (int j=0;j<8;j++)
      #pragma unroll
      for (int r=0;r<4;r++) oacc[j][r] *= alpha[r];
    __syncthreads();

    #pragma unroll
    for (int kk=0; kk<2; kk++){
      const bf16x8 pf = *(const bf16x8*)&Ps[wv*16+lm][kk*32+lq*8];
      #pragma unroll
      for (int j=0;j<8;j++){
        const bf16x8 vf = *(const bf16x8*)&Vts[j*16+lm][kk*32+lq*8];
        oacc[j] = __builtin_amdgcn_mfma_f32_16x16x32_bf16(pf, vf, oacc[j], 0, 0, 0);
      }
    }
  }
  #pragma unroll
  for (int r=0;r<4;r++){
    const float inv = 1.0f / lrow[r];
    u16* orow = vals_c + ((size_t)(bl*SEQ + q0 + wv*16 + lq*4 + r))*EHH + h*EE;
    #pragma unroll
    for (int j=0;j<8;j++) orow[j*16+lm] = f2bf(oacc[j][r]*inv);
  }
}

// =================== pool phase 1: partial weighted sums ===================
__global__ __launch_bounds__(128) void pool1_k(
    const float* __restrict__ x, const float* __restrict__ x_init,
    const float* __restrict__ w, float* __restrict__ part)
{
  const int bc = blockIdx.x;          // b*4 + c
  const int b = bc >> 2, c = bc & 3;
  const int e = threadIdx.x;
  float acc = 0.f;
  const int n0 = c*128;
  for (int n=0;n<128;n++){
    const int tok = b*SEQ + n0 + n;
    const size_t idx = (size_t)tok*EE + e;
    acc = fmaf(w[tok], x[idx]+x_init[idx], acc);
  }
  part[(size_t)bc*EE + e] = acc;
}

// =================== pool phase 2: sum parts + LN + head ===================
__global__ __launch_bounds__(128) void pool2_k(
    const float* __restrict__ part, const float* __restrict__ g2,
    const float* __restrict__ b2, const float* __restrict__ head_W,
    const float* __restrict__ head_b, float* __restrict__ out)
{
  const int b = blockIdx.x;
  const int e = threadIdx.x;
  __shared__ float red[128];
  float acc = part[(size_t)(b*4+0)*EE+e] + part[(size_t)(b*4+1)*EE+e]
            + part[(size_t)(b*4+2)*EE+e] + part[(size_t)(b*4+3)*EE+e];
  red[e]=acc; __syncthreads();
  for (int s=64;s>0;s>>=1){ if(e<s) red[e]+=red[e+s]; __syncthreads(); }
  const float mean = red[0]*(1.0f/128.0f);
  __syncthreads();
  const float d = acc-mean;
  red[e]=d*d; __syncthreads();
  for (int s=64;s>0;s>>=1){ if(e<s) red[e]+=red[e+s]; __syncthreads(); }
  const float var = red[0]*(1.0f/128.0f);
  const float p = d*rsqrtf(var+1e-5f)*g2[e]+b2[e];
  __syncthreads();
  red[e] = p*head_W[e]; __syncthreads();
  for (int s=64;s>0;s>>=1){ if(e<s) red[e]+=red[e+s]; __syncthreads(); }
  if (e==0) out[b] = red[0] + head_b[0];
}

// =================== launch ===================
extern "C" void kernel_launch(void* const* d_in, const int* in_sizes, int n_in,
                              void* d_out, int out_size, void* d_ws, size_t ws_size,
                              hipStream_t stream)
{
  const float* str_fea   = (const float*)d_in[0];
  const int*   comp_fea  = (const int*)  d_in[1];
  // d_in[2] cell_fea unused by reference
  const float* atom_table= (const float*)d_in[3];
  const float* comp_W    = (const float*)d_in[4];
  const float* comp_b    = (const float*)d_in[5];
  const float* pdd_W     = (const float*)d_in[6];
  const float* pdd_b     = (const float*)d_in[7];
  const float* enc_ln_g  = (const float*)d_in[8];
  const float* enc_ln_b  = (const float*)d_in[9];
  const float* qkv_W     = (const float*)d_in[10];
  const float* qkv_b     = (const float*)d_in[11];
  const float* o_W       = (const float*)d_in[12];
  const float* o_b       = (const float*)d_in[13];
  const float* out_W     = (const float*)d_in[14];
  const float* out_b     = (const float*)d_in[15];
  const float* ffn_W     = (const float*)d_in[16];
  const float* ffn_b     = (const float*)d_in[17];
  const float* ln2_g     = (const float*)d_in[18];
  const float* ln2_b     = (const float*)d_in[19];
  const float* head_W    = (const float*)d_in[20];
  const float* head_b    = (const float*)d_in[21];
  float* out = (float*)d_out;

  // ---- diagnostic 1: input layout model ----
  bool sizes_ok = (n_in >= 22);
  if (sizes_ok){
    sizes_ok = in_sizes[0]==BB*SEQ*KF && in_sizes[1]==NTOK &&
               in_sizes[3]==NATOM*ADIM && in_sizes[4]==ADIM*EE &&
               in_sizes[10]==LL*EE*3*EHH && in_sizes[12]==LL*EHH*EHH &&
               in_sizes[14]==LL*EHH*EE   && in_sizes[16]==LL*EE*EE &&
               in_sizes[20]==EE;
  }
  if (!sizes_ok){
    sentinel_k<<<(out_size+63)/64,64,0,stream>>>(out, 99999.0f, out_size);
    return;
  }

  // ---- workspace layout (~99 MB; <= 107.7 MB proven) ----
  char* p = (char*)d_ws;
  size_t off = 0;
  auto alloc = [&](size_t bytes)->void*{
    off = (off + 255) & ~(size_t)255;
    void* r = p + off; off += bytes; return r;
  };
  float* w       = (float*)alloc((size_t)NTOK*4);
  float* x       = (float*)alloc((size_t)NTOK*EE*4);
  float* x_init  = (float*)alloc((size_t)NTOK*EE*4);
  u16*   xn_bf   = (u16*)  alloc((size_t)NTOK*EE*2);
  float* out1    = (float*)alloc((size_t)NTOK*EE*4);
  float* out2    = (float*)alloc((size_t)NTOK*EE*4);
  u16*   qkvc    = (u16*)  alloc((size_t)CTOK*3*EHH*2);  // 25.2 MB chunk (bf16)
  u16*   vals_bf = (u16*)  alloc((size_t)NTOK*EHH*2);    // 33.6 MB full
  u16*   qkvWT   = (u16*)  alloc((size_t)3*EHH*EE*2);
  u16*   fwT     = (u16*)  alloc((size_t)EE*EHH*2);
  u16*   ffnWT   = (u16*)  alloc((size_t)EE*EE*2);
  u16*   oWb     = (u16*)  alloc((size_t)EHH*EHH*2);     // 2 MB
  u16*   outWT   = (u16*)  alloc((size_t)EE*EHH*2);
  float* fb      = (float*)alloc((size_t)EE*4);
  float* atom_emb= (float*)alloc((size_t)NATOM*EE*4);
  float* part    = (float*)alloc((size_t)BB*4*EE*4);

  // ---- diagnostic 2: workspace size ----
  if (off > ws_size){
    sentinel_k<<<(out_size+63)/64,64,0,stream>>>(out, 12345.0f, out_size);
    return;
  }

  atomemb_k<<<NATOM,128,0,stream>>>(atom_table, comp_W, comp_b, pdd_b, atom_emb);
  embed_k<<<NTOK,128,0,stream>>>(str_fea, comp_fea, atom_emb, pdd_W, x, x_init, w);
  for (int i=0;i<LL;i++){
    const float* gi = enc_ln_g + i*EE;
    const float* bi = enc_ln_b + i*EE;
    ln_k<true><<<NTOK/4,256,0,stream>>>(x, nullptr, gi, bi, xn_bf);
    // weight prep (coalesced converts + MFMA fuse GEMM)
    tconvT_k<<<dim3(3*EHH/32, EE/32),256,0,stream>>>(
        qkv_W + (size_t)i*EE*3*EHH, qkvWT, EE, 3*EHH);
    tconvT_k<<<dim3(EE/32, EE/32),256,0,stream>>>(
        ffn_W + (size_t)i*EE*EE, ffnWT, EE, EE);
    cconv_k<<<(EHH*EHH+255)/256,256,0,stream>>>(
        o_W + (size_t)i*EHH*EHH, oWb, EHH*EHH);
    tconvT_k<<<dim3(EE/32, EHH/32),256,0,stream>>>(
        out_W + (size_t)i*EHH*EE, outWT, EHH, EE);
    // fwT = (o_W @ out_W)^T : M=EHH, N=EE, K=EHH, stored transposed (EPI 4)
    mgemm_k<4,64,128><<<dim3(1, EHH/64),256,0,stream>>>(
        oWb, outWT, nullptr, nullptr, fwT, EE, EHH, EHH);
    fuse_b_k<<<1,128,0,stream>>>(
        o_b + (size_t)i*EHH, out_W + (size_t)i*EHH*EE, out_b + (size_t)i*EE, fb);
    for (int cb=0; cb<NCHUNK; cb++){
      const int t0 = cb*CTOK;
      const int b0 = cb*CB;
      // QKV: (CTOK x 128) @ (128 x 3072) -> qkvc bf16   [MFMA]
      mgemm_k<0,128,128><<<dim3(3*EHH/128, CTOK/128),256,0,stream>>>(
          xn_bf + (size_t)t0*EE, qkvWT, qkv_b + (size_t)i*3*EHH, nullptr,
          qkvc, 3*EHH, EE, 0);
      // attention (MFMA) -> vals_bf
      attn_mf_k<<<dim3(SEQ/64,HH,CB),256,0,stream>>>(
          qkvc, w, vals_bf + (size_t)t0*EHH, b0);
    }
    // proj: (NTOK x 1024) @ (1024 x 128) + resid -> out1   [MFMA]
    mgemm_k<2,64,128><<<dim3(1, NTOK/64),256,0,stream>>>(
        vals_bf, fwT, fb, x, out1, EE, EHH, 0);
    ln_k<true><<<NTOK/4,256,0,stream>>>(out1, nullptr, gi, bi, xn_bf);
    // ffn: (NTOK x 128) @ (128 x 128) + mish -> out2   [MFMA]
    mgemm_k<3,64,128><<<dim3(1, NTOK/64),256,0,stream>>>(
        xn_bf, ffnWT, ffn_b + (size_t)i*EE, nullptr, out2, EE, EE, 0);
    ln_k<false><<<NTOK/4,256,0,stream>>>(out1, out2, gi, bi, x);
  }
  pool1_k<<<BB*4,128,0,stream>>>(x, x_init, w, part);
  pool2_k<<<BB,128,0,stream>>>(part, ln2_g, ln2_b, head_W, head_b, out);
}

// Round 13
// 1258.383 us; speedup vs baseline: 17.2316x; 1.0214x over previous
//
#include <hip/hip_runtime.h>
#include <math.h>

#define DI __device__ __forceinline__

// ---- problem constants ----
#define BB 32
#define SEQ 512
#define KF 101
#define EE 128
#define HH 8
#define EHH 1024
#define LL 3
#define ADIM 200
#define NATOM 119
#define NTOK (BB*SEQ)   // 16384
#define CB 8            // batches per chunk
#define NCHUNK (BB/CB)  // 4
#define CTOK (CB*SEQ)   // 4096 tokens per chunk

// R12 post-mortem: attn 46us x12; FETCH 69.8MB vs 25.2MB unique => ~2.8x
// HBM over-fetch from qt-major grid spreading same-(h,bl) blocks across XCDs
// (per-XCD L2 not shared). R13: (1) grid (bl,h,qt) => all blocks of a batch
// on one XCD (id%8=bl), K/V dedup in L2; (2) LN fused: proj epilogue does
// row-LN (EPI5, out1 f32 + xn bf16), ln_dual does LN3+next-LN1 in one pass.

typedef unsigned short u16;
typedef __attribute__((ext_vector_type(8))) short bf16x8;
typedef __attribute__((ext_vector_type(4))) float f32x4;

DI float bf2f(u16 s){ union{unsigned int u; float f;} x; x.u = ((unsigned int)s)<<16; return x.f; }
DI u16 f2bf(float f){
  union{float f; unsigned int u;} x; x.f = f;
  unsigned int u = x.u;
  u += 0x7fffu + ((u>>16)&1u);           // RNE
  return (u16)(u>>16);
}

// =================== sentinel ===================
__global__ void sentinel_k(float* out, float v, int n){
  int i = blockIdx.x*64 + threadIdx.x;
  if (i < n) out[i] = v;
}

// =================== atom embedding precompute ===================
__global__ __launch_bounds__(128) void atomemb_k(
    const float* __restrict__ atom_table, const float* __restrict__ comp_W,
    const float* __restrict__ comp_b, const float* __restrict__ pdd_b,
    float* __restrict__ atom_emb)
{
  const int a = blockIdx.x;      // 0..NATOM-1
  const int e = threadIdx.x;
  __shared__ float sAtom[ADIM];
  for (int d=e; d<ADIM; d+=128) sAtom[d] = atom_table[a*ADIM+d];
  __syncthreads();
  float acc = comp_b[e] + pdd_b[e];
  #pragma unroll 4
  for (int d=0; d<ADIM; d++) acc = fmaf(sAtom[d], comp_W[d*EE+e], acc);
  atom_emb[a*EE+e] = acc;
}

// =================== embed: x = atom_emb[idx] + str[1:]@pdd_W ===================
__global__ __launch_bounds__(128) void embed_k(
    const float* __restrict__ str_fea, const int* __restrict__ comp_fea,
    const float* __restrict__ atom_emb, const float* __restrict__ pdd_W,
    float* __restrict__ x, float* __restrict__ x_init, float* __restrict__ w)
{
  const int t = blockIdx.x;
  const int e = threadIdx.x;
  __shared__ float sStr[104];
  if (e < KF) sStr[e] = str_fea[(size_t)t*KF+e];
  __syncthreads();
  const int idx = comp_fea[t];
  float a0 = atom_emb[idx*EE+e], a1 = 0.f, a2 = 0.f, a3 = 0.f;
  #pragma unroll
  for (int j=0; j<100; j+=4){
    a0 = fmaf(sStr[1+j],   pdd_W[(j  )*EE+e], a0);
    a1 = fmaf(sStr[2+j],   pdd_W[(j+1)*EE+e], a1);
    a2 = fmaf(sStr[3+j],   pdd_W[(j+2)*EE+e], a2);
    a3 = fmaf(sStr[4+j],   pdd_W[(j+3)*EE+e], a3);
  }
  const float acc = (a0+a1)+(a2+a3);
  x[(size_t)t*EE+e] = acc;
  x_init[(size_t)t*EE+e] = acc;
  if (e==0) w[t] = sStr[0];
}

// =================== layernorm: wave per token, single output ===================
template<bool OBF>
__global__ __launch_bounds__(256) void ln_k(
    const float* __restrict__ in, const float* __restrict__ add,
    const float* __restrict__ g, const float* __restrict__ bta,
    void* __restrict__ outv)
{
  const int wv = threadIdx.x >> 6, lane = threadIdx.x & 63;
  const int t = blockIdx.x*4 + wv;
  float2 v = ((const float2*)(in + (size_t)t*EE))[lane];
  if (add){
    const float2 a = ((const float2*)(add + (size_t)t*EE))[lane];
    v.x += a.x; v.y += a.y;
  }
  float s = v.x + v.y;
  #pragma unroll
  for (int off=32; off; off>>=1) s += __shfl_xor(s, off);
  const float mean = s*(1.0f/128.0f);
  const float d0 = v.x-mean, d1 = v.y-mean;
  float q = d0*d0 + d1*d1;
  #pragma unroll
  for (int off=32; off; off>>=1) q += __shfl_xor(q, off);
  const float rstd = rsqrtf(q*(1.0f/128.0f) + 1e-5f);
  const float2 gg = ((const float2*)g)[lane];
  const float2 bb = ((const float2*)bta)[lane];
  const float r0 = d0*rstd*gg.x + bb.x;
  const float r1 = d1*rstd*gg.y + bb.y;
  if constexpr (OBF){
    u16* o = (u16*)outv + (size_t)t*EE + lane*2;
    o[0] = f2bf(r0); o[1] = f2bf(r1);
  } else {
    float2* o = (float2*)((float*)outv + (size_t)t*EE);
    o[lane] = make_float2(r0, r1);
  }
}

// =================== dual layernorm: x = LN(in+add, g1,b1); xn = LN(x, g2,b2) ===================
__global__ __launch_bounds__(256) void ln_dual_k(
    const float* __restrict__ in, const float* __restrict__ add,
    const float* __restrict__ g1, const float* __restrict__ b1,
    const float* __restrict__ g2, const float* __restrict__ b2,
    float* __restrict__ xout, u16* __restrict__ xnout)
{
  const int wv = threadIdx.x >> 6, lane = threadIdx.x & 63;
  const int t = blockIdx.x*4 + wv;
  float2 v = ((const float2*)(in + (size_t)t*EE))[lane];
  const float2 a = ((const float2*)(add + (size_t)t*EE))[lane];
  v.x += a.x; v.y += a.y;
  float s = v.x + v.y;
  #pragma unroll
  for (int off=32; off; off>>=1) s += __shfl_xor(s, off);
  float mean = s*(1.0f/128.0f);
  float d0 = v.x-mean, d1 = v.y-mean;
  float q = d0*d0 + d1*d1;
  #pragma unroll
  for (int off=32; off; off>>=1) q += __shfl_xor(q, off);
  float rstd = rsqrtf(q*(1.0f/128.0f) + 1e-5f);
  const float2 gg1 = ((const float2*)g1)[lane];
  const float2 bb1 = ((const float2*)b1)[lane];
  const float x0 = d0*rstd*gg1.x + bb1.x;
  const float x1 = d1*rstd*gg1.y + bb1.y;
  ((float2*)(xout + (size_t)t*EE))[lane] = make_float2(x0, x1);
  // second LN on x
  s = x0 + x1;
  #pragma unroll
  for (int off=32; off; off>>=1) s += __shfl_xor(s, off);
  mean = s*(1.0f/128.0f);
  d0 = x0-mean; d1 = x1-mean;
  q = d0*d0 + d1*d1;
  #pragma unroll
  for (int off=32; off; off>>=1) q += __shfl_xor(q, off);
  rstd = rsqrtf(q*(1.0f/128.0f) + 1e-5f);
  const float2 gg2 = ((const float2*)g2)[lane];
  const float2 bb2 = ((const float2*)b2)[lane];
  u16* o = xnout + (size_t)t*EE + lane*2;
  o[0] = f2bf(d0*rstd*gg2.x + bb2.x);
  o[1] = f2bf(d1*rstd*gg2.y + bb2.y);
}

// =================== coalesced convert: f32 -> bf16 ===================
__global__ __launch_bounds__(256) void cconv_k(
    const float* __restrict__ W, u16* __restrict__ Wb, int n)
{
  const int i = blockIdx.x*256 + threadIdx.x;
  if (i < n) Wb[i] = f2bf(W[i]);
}

// =================== LDS-tiled transpose convert: W (Kk x Nn f32) -> WT (Nn x Kk bf16) ===================
__global__ __launch_bounds__(256) void tconvT_k(
    const float* __restrict__ W, u16* __restrict__ WT, int Kk, int Nn)
{
  __shared__ u16 tile[32][33];
  const int n0 = blockIdx.x*32, k0 = blockIdx.y*32;
  const int lr = threadIdx.x >> 5, lc = threadIdx.x & 31;
  #pragma unroll
  for (int i=0;i<4;i++){
    const int k = k0 + lr + i*8;
    tile[lr+i*8][lc] = f2bf(W[(size_t)k*Nn + n0 + lc]);
  }
  __syncthreads();
  #pragma unroll
  for (int i=0;i<4;i++){
    const int n = n0 + lr + i*8;
    WT[(size_t)n*Kk + k0 + lc] = tile[lc][lr+i*8];
  }
}

// =================== MFMA bf16 GEMM ===================
// A: M x Kk bf16 row-major. BT: Nn x Kk bf16 (pre-transposed B).
// EPI 0: store bf16; 2: f32 +resid; 3: f32 mish; 4: bf16 transposed store;
// EPI 5 (BM=64, BN=Nn=128 only): v = acc+bias+resid -> C (f32) AND
//        row-LN(v)*lng+lnb -> C2 (bf16).
template<int EPI, int BM, int BN>
__global__ __launch_bounds__(256) void mgemm_k(
    const u16* __restrict__ A, const u16* __restrict__ BT,
    const float* __restrict__ bias, const float* __restrict__ resid,
    void* __restrict__ C, int Nn, int Kk, int Mdim,
    void* __restrict__ C2, const float* __restrict__ lng,
    const float* __restrict__ lnb)
{
  constexpr int BK  = 64;
  constexpr int LDK = BK + 8;
  __shared__ u16 As[BM*LDK];
  __shared__ u16 Bs[BN*LDK];
  const int tid = threadIdx.x;
  const int m0 = blockIdx.y*BM, n0 = blockIdx.x*BN;
  constexpr int WMN = (BM>=128)?2:1;
  constexpr int WNN = 4/WMN;
  constexpr int WM = BM/WMN;
  constexpr int WN = BN/WNN;
  constexpr int FM = WM/16, FN = WN/16;
  const int wv = tid>>6, lane = tid&63;
  const int wm = (wv/WNN)*WM;
  const int wn = (wv%WNN)*WN;
  const int lm = lane&15, lq = lane>>4;

  f32x4 acc[FM][FN];
  #pragma unroll
  for (int i=0;i<FM;i++)
    #pragma unroll
    for (int j=0;j<FN;j++) acc[i][j] = (f32x4){0.f,0.f,0.f,0.f};

  constexpr int ACH = BM*BK/8;
  constexpr int BCH = BN*BK/8;

  for (int k0=0; k0<Kk; k0+=BK){
    #pragma unroll
    for (int c = tid; c < ACH; c += 256){
      const int r = c/(BK/8), kg = c - r*(BK/8);
      const float4 v = *(const float4*)(A + (size_t)(m0+r)*Kk + k0 + kg*8);
      *(float4*)&As[r*LDK + kg*8] = v;
    }
    #pragma unroll
    for (int c = tid; c < BCH; c += 256){
      const int r = c/(BK/8), kg = c - r*(BK/8);
      const float4 v = *(const float4*)(BT + (size_t)(n0+r)*Kk + k0 + kg*8);
      *(float4*)&Bs[r*LDK + kg*8] = v;
    }
    __syncthreads();
    #pragma unroll
    for (int kk=0; kk<BK/32; kk++){
      bf16x8 af[FM], bfr[FN];
      #pragma unroll
      for (int i=0;i<FM;i++)
        af[i] = *(const bf16x8*)&As[(wm + i*16 + lm)*LDK + kk*32 + lq*8];
      #pragma unroll
      for (int j=0;j<FN;j++)
        bfr[j] = *(const bf16x8*)&Bs[(wn + j*16 + lm)*LDK + kk*32 + lq*8];
      #pragma unroll
      for (int i=0;i<FM;i++)
        #pragma unroll
        for (int j=0;j<FN;j++)
          acc[i][j] = __builtin_amdgcn_mfma_f32_16x16x32_bf16(af[i], bfr[j], acc[i][j], 0, 0, 0);
    }
    __syncthreads();
  }
  if constexpr (EPI==5){
    // fused proj + residual + row-LN (assumes BM=64 => wm=0, BN=Nn=128)
    float vout[FM][FN][4];
    float ps[FM][4], qs[FM][4];
    #pragma unroll
    for (int i=0;i<FM;i++)
      #pragma unroll
      for (int r=0;r<4;r++){ ps[i][r]=0.f; qs[i][r]=0.f; }
    #pragma unroll
    for (int i=0;i<FM;i++){
      #pragma unroll
      for (int j=0;j<FN;j++){
        const int col = n0 + wn + j*16 + lm;
        const float bv = bias[col];
        #pragma unroll
        for (int r=0;r<4;r++){
          const int row = m0 + i*16 + lq*4 + r;
          const size_t gi = (size_t)row*Nn + col;
          const float v = acc[i][j][r] + bv + resid[gi];
          ((float*)C)[gi] = v;
          vout[i][j][r] = v;
          ps[i][r] += v; qs[i][r] += v*v;
        }
      }
    }
    float* sred = (float*)As;   // 512 floats (2KB) well within As
    #pragma unroll
    for (int i=0;i<FM;i++)
      #pragma unroll
      for (int r=0;r<4;r++){
        float s = ps[i][r], q = qs[i][r];
        s += __shfl_xor(s,1); s += __shfl_xor(s,2); s += __shfl_xor(s,4); s += __shfl_xor(s,8);
        q += __shfl_xor(q,1); q += __shfl_xor(q,2); q += __shfl_xor(q,4); q += __shfl_xor(q,8);
        if (lm==0){
          const int row = i*16 + lq*4 + r;
          sred[row*4 + wv] = s;
          sred[256 + row*4 + wv] = q;
        }
      }
    __syncthreads();
    #pragma unroll
    for (int i=0;i<FM;i++)
      #pragma unroll
      for (int r=0;r<4;r++){
        const int row = i*16 + lq*4 + r;
        const float s = sred[row*4+0]+sred[row*4+1]+sred[row*4+2]+sred[row*4+3];
        const float q = sred[256+row*4+0]+sred[256+row*4+1]+sred[256+row*4+2]+sred[256+row*4+3];
        const float mean = s*(1.0f/128.0f);
        const float var  = q*(1.0f/128.0f) - mean*mean;
        const float rstd = rsqrtf(var + 1e-5f);
        #pragma unroll
        for (int j=0;j<FN;j++){
          const int col = n0 + wn + j*16 + lm;
          const float xnv = (vout[i][j][r]-mean)*rstd*lng[col] + lnb[col];
          ((u16*)C2)[(size_t)(m0+row)*Nn + col] = f2bf(xnv);
        }
      }
  } else {
    #pragma unroll
    for (int i=0;i<FM;i++){
      #pragma unroll
      for (int j=0;j<FN;j++){
        const int col = n0 + wn + j*16 + lm;
        const float bv = (EPI==4) ? 0.f : bias[col];
        #pragma unroll
        for (int r=0;r<4;r++){
          const int row = m0 + wm + i*16 + lq*4 + r;
          float v = acc[i][j][r] + bv;
          if constexpr (EPI==4){
            ((u16*)C)[(size_t)col*Mdim + row] = f2bf(v);
          } else {
            const size_t gi = (size_t)row*Nn + col;
            if constexpr (EPI==0)      ((u16*)C)[gi] = f2bf(v);
            else if constexpr (EPI==2) ((float*)C)[gi] = v + resid[gi];
            else { const float sp=(v>20.f)?v:log1pf(expf(v)); ((float*)C)[gi]=v*tanhf(sp); }
          }
        }
      }
    }
  }
}

// =================== fb = o_b@out_W + out_b ===================
__global__ __launch_bounds__(128) void fuse_b_k(
    const float* __restrict__ ob, const float* __restrict__ outW,
    const float* __restrict__ outb, float* __restrict__ fb)
{
  const int n = threadIdx.x;
  float acc = outb[n];
  for (int k2=0;k2<EHH;k2++) acc = fmaf(ob[k2], outW[(size_t)k2*EE+n], acc);
  fb[n] = acc;
}

// =================== MFMA flash attention (XCD-local grid: bl,h,qt) ===================
__global__ __launch_bounds__(256) void attn_mf_k(
    const u16* __restrict__ qkvc, const float* __restrict__ w,
    u16* __restrict__ vals_c, int b0)
{
  const int bl = blockIdx.x;   // 0..CB-1  (fastest -> id%8 = bl -> one XCD/batch)
  const int h  = blockIdx.y;   // 0..7
  const int qt = blockIdx.z;   // 0..7
  const int tid = threadIdx.x;
  const int wv = tid>>6, lane = tid&63;
  const int lm = lane&15, lq = lane>>4;

  __shared__ u16 Qs[64][136];
  __shared__ u16 Ks[64][136];
  __shared__ u16 Vts[128][72];
  __shared__ u16 Ps[64][72];
  __shared__ float wt[64], qwt[64];

  const size_t rs = 3072;
  const u16* base = qkvc + (size_t)bl*SEQ*rs + (size_t)h*384;
  const int q0 = qt*64;

  #pragma unroll
  for (int it=0; it<4; it++){
    const int fi = it*256 + tid;
    const int r = fi >> 4, g = fi & 15;
    *(float4*)&Qs[r][g*8] = *(const float4*)(base + (size_t)(q0+r)*rs + g*8);
  }
  if (tid < 64) qwt[tid] = w[(b0+bl)*SEQ + q0 + tid];
  __syncthreads();

  float kq[4];
  #pragma unroll
  for (int r=0;r<4;r++) kq[r] = qwt[wv*16 + lq*4 + r];

  f32x4 oacc[8];
  #pragma unroll
  for (int j=0;j<8;j++) oacc[j] = (f32x4){0.f,0.f,0.f,0.f};
  float mrow[4], lrow[4];
  #pragma unroll
  for (int r=0;r<4;r++){ mrow[r]=-INFINITY; lrow[r]=0.f; }
  const float scale = 0.08838834764831845f;  // 1/sqrt(128)

  for (int kt=0; kt<8; kt++){
    __syncthreads();
    #pragma unroll
    for (int it=0; it<4; it++){
      const int fi = it*256 + tid;
      const int r = fi >> 4, g = fi & 15;
      *(float4*)&Ks[r][g*8] = *(const float4*)(base + (size_t)(kt*64+r)*rs + 128 + g*8);
    }
    #pragma unroll
    for (int it=0; it<4; it++){
      const int fi = it*256 + tid;
      const int k = fi & 63, dg = fi >> 6;
      union { float4 f4; u16 u[8]; } cv;
      cv.f4 = *(const float4*)(base + (size_t)(kt*64+k)*rs + 256 + dg*8);
      #pragma unroll
      for (int e=0;e<8;e++) Vts[dg*8+e][k] = cv.u[e];
    }
    if (tid < 64) wt[tid] = w[(b0+bl)*SEQ + kt*64 + tid];
    __syncthreads();

    f32x4 sacc[4];
    #pragma unroll
    for (int j=0;j<4;j++) sacc[j] = (f32x4){0.f,0.f,0.f,0.f};
    #pragma unroll
    for (int kk=0; kk<4; kk++){
      const bf16x8 af = *(const bf16x8*)&Qs[wv*16+lm][kk*32+lq*8];
      #pragma unroll
      for (int j=0;j<4;j++){
        const bf16x8 bf = *(const bf16x8*)&Ks[j*16+lm][kk*32+lq*8];
        sacc[j] = __builtin_amdgcn_mfma_f32_16x16x32_bf16(af, bf, sacc[j], 0, 0, 0);
      }
    }
    float wkj[4], s[4][4];
    #pragma unroll
    for (int j=0;j<4;j++) wkj[j] = wt[j*16+lm];
    #pragma unroll
    for (int j=0;j<4;j++)
      #pragma unroll
      for (int r=0;r<4;r++){
        const bool keep = (kq[r] > 0.f) && (wkj[j] > 0.f);
        s[j][r] = keep ? sacc[j][r]*scale : -9.0e15f;
      }
    float alpha[4];
    #pragma unroll
    for (int r=0;r<4;r++){
      float rm = fmaxf(fmaxf(s[0][r], s[1][r]), fmaxf(s[2][r], s[3][r]));
      rm = fmaxf(rm, __shfl_xor(rm, 1));
      rm = fmaxf(rm, __shfl_xor(rm, 2));
      rm = fmaxf(rm, __shfl_xor(rm, 4));
      rm = fmaxf(rm, __shfl_xor(rm, 8));
      const float newm = fmaxf(mrow[r], rm);
      alpha[r] = expf(mrow[r] - newm);
      float ls = 0.f;
      #pragma unroll
      for (int j=0;j<4;j++){
        const float pv = wkj[j]*expf(s[j][r]-newm);
        s[j][r] = pv; ls += pv;
      }
      ls += __shfl_xor(ls, 1);
      ls += __shfl_xor(ls, 2);
      ls += __shfl_xor(ls, 4);
      ls += __shfl_xor(ls, 8);
      lrow[r] = lrow[r]*alpha[r] + ls;
      mrow[r] = newm;
    }
    #pragma unroll
    for (int j=0;j<4;j++)
      #pragma unroll
      for (int r=0;r<4;r++)
        Ps[wv*16 + lq*4 + r][j*16+lm] = f2bf(s[j][r]);
    #pragma unroll
    for (int j=0;j<8;j++)
      #pragma unroll
      for (int r=0;r<4;r++) oacc[j][r] *= alpha[r];
    __syncthreads();

    #pragma unroll
    for (int kk=0; kk<2; kk++){
      const bf16x8 pf = *(const bf16x8*)&Ps[wv*16+lm][kk*32+lq*8];
      #pragma unroll
      for (int j=0;j<8;j++){
        const bf16x8 vf = *(const bf16x8*)&Vts[j*16+lm][kk*32+lq*8];
        oacc[j] = __builtin_amdgcn_mfma_f32_16x16x32_bf16(pf, vf, oacc[j], 0, 0, 0);
      }
    }
  }
  #pragma unroll
  for (int r=0;r<4;r++){
    const float inv = 1.0f / lrow[r];
    u16* orow = vals_c + ((size_t)(bl*SEQ + q0 + wv*16 + lq*4 + r))*EHH + h*EE;
    #pragma unroll
    for (int j=0;j<8;j++) orow[j*16+lm] = f2bf(oacc[j][r]*inv);
  }
}

// =================== pool phase 1: partial weighted sums ===================
__global__ __launch_bounds__(128) void pool1_k(
    const float* __restrict__ x, const float* __restrict__ x_init,
    const float* __restrict__ w, float* __restrict__ part)
{
  const int bc = blockIdx.x;          // b*4 + c
  const int b = bc >> 2, c = bc & 3;
  const int e = threadIdx.x;
  float acc = 0.f;
  const int n0 = c*128;
  for (int n=0;n<128;n++){
    const int tok = b*SEQ + n0 + n;
    const size_t idx = (size_t)tok*EE + e;
    acc = fmaf(w[tok], x[idx]+x_init[idx], acc);
  }
  part[(size_t)bc*EE + e] = acc;
}

// =================== pool phase 2: sum parts + LN + head ===================
__global__ __launch_bounds__(128) void pool2_k(
    const float* __restrict__ part, const float* __restrict__ g2,
    const float* __restrict__ b2, const float* __restrict__ head_W,
    const float* __restrict__ head_b, float* __restrict__ out)
{
  const int b = blockIdx.x;
  const int e = threadIdx.x;
  __shared__ float red[128];
  float acc = part[(size_t)(b*4+0)*EE+e] + part[(size_t)(b*4+1)*EE+e]
            + part[(size_t)(b*4+2)*EE+e] + part[(size_t)(b*4+3)*EE+e];
  red[e]=acc; __syncthreads();
  for (int s=64;s>0;s>>=1){ if(e<s) red[e]+=red[e+s]; __syncthreads(); }
  const float mean = red[0]*(1.0f/128.0f);
  __syncthreads();
  const float d = acc-mean;
  red[e]=d*d; __syncthreads();
  for (int s=64;s>0;s>>=1){ if(e<s) red[e]+=red[e+s]; __syncthreads(); }
  const float var = red[0]*(1.0f/128.0f);
  const float p = d*rsqrtf(var+1e-5f)*g2[e]+b2[e];
  __syncthreads();
  red[e] = p*head_W[e]; __syncthreads();
  for (int s=64;s>0;s>>=1){ if(e<s) red[e]+=red[e+s]; __syncthreads(); }
  if (e==0) out[b] = red[0] + head_b[0];
}

// =================== launch ===================
extern "C" void kernel_launch(void* const* d_in, const int* in_sizes, int n_in,
                              void* d_out, int out_size, void* d_ws, size_t ws_size,
                              hipStream_t stream)
{
  const float* str_fea   = (const float*)d_in[0];
  const int*   comp_fea  = (const int*)  d_in[1];
  // d_in[2] cell_fea unused by reference
  const float* atom_table= (const float*)d_in[3];
  const float* comp_W    = (const float*)d_in[4];
  const float* comp_b    = (const float*)d_in[5];
  const float* pdd_W     = (const float*)d_in[6];
  const float* pdd_b     = (const float*)d_in[7];
  const float* enc_ln_g  = (const float*)d_in[8];
  const float* enc_ln_b  = (const float*)d_in[9];
  const float* qkv_W     = (const float*)d_in[10];
  const float* qkv_b     = (const float*)d_in[11];
  const float* o_W       = (const float*)d_in[12];
  const float* o_b       = (const float*)d_in[13];
  const float* out_W     = (const float*)d_in[14];
  const float* out_b     = (const float*)d_in[15];
  const float* ffn_W     = (const float*)d_in[16];
  const float* ffn_b     = (const float*)d_in[17];
  const float* ln2_g     = (const float*)d_in[18];
  const float* ln2_b     = (const float*)d_in[19];
  const float* head_W    = (const float*)d_in[20];
  const float* head_b    = (const float*)d_in[21];
  float* out = (float*)d_out;

  // ---- diagnostic 1: input layout model ----
  bool sizes_ok = (n_in >= 22);
  if (sizes_ok){
    sizes_ok = in_sizes[0]==BB*SEQ*KF && in_sizes[1]==NTOK &&
               in_sizes[3]==NATOM*ADIM && in_sizes[4]==ADIM*EE &&
               in_sizes[10]==LL*EE*3*EHH && in_sizes[12]==LL*EHH*EHH &&
               in_sizes[14]==LL*EHH*EE   && in_sizes[16]==LL*EE*EE &&
               in_sizes[20]==EE;
  }
  if (!sizes_ok){
    sentinel_k<<<(out_size+63)/64,64,0,stream>>>(out, 99999.0f, out_size);
    return;
  }

  // ---- workspace layout (~99 MB; <= 107.7 MB proven) ----
  char* p = (char*)d_ws;
  size_t off = 0;
  auto alloc = [&](size_t bytes)->void*{
    off = (off + 255) & ~(size_t)255;
    void* r = p + off; off += bytes; return r;
  };
  float* w       = (float*)alloc((size_t)NTOK*4);
  float* x       = (float*)alloc((size_t)NTOK*EE*4);
  float* x_init  = (float*)alloc((size_t)NTOK*EE*4);
  u16*   xn_bf   = (u16*)  alloc((size_t)NTOK*EE*2);
  float* out1    = (float*)alloc((size_t)NTOK*EE*4);
  float* out2    = (float*)alloc((size_t)NTOK*EE*4);
  u16*   qkvc    = (u16*)  alloc((size_t)CTOK*3*EHH*2);  // 25.2 MB chunk (bf16)
  u16*   vals_bf = (u16*)  alloc((size_t)NTOK*EHH*2);    // 33.6 MB full
  u16*   qkvWT   = (u16*)  alloc((size_t)3*EHH*EE*2);
  u16*   fwT     = (u16*)  alloc((size_t)EE*EHH*2);
  u16*   ffnWT   = (u16*)  alloc((size_t)EE*EE*2);
  u16*   oWb     = (u16*)  alloc((size_t)EHH*EHH*2);     // 2 MB
  u16*   outWT   = (u16*)  alloc((size_t)EE*EHH*2);
  float* fb      = (float*)alloc((size_t)EE*4);
  float* atom_emb= (float*)alloc((size_t)NATOM*EE*4);
  float* part    = (float*)alloc((size_t)BB*4*EE*4);

  // ---- diagnostic 2: workspace size ----
  if (off > ws_size){
    sentinel_k<<<(out_size+63)/64,64,0,stream>>>(out, 12345.0f, out_size);
    return;
  }

  atomemb_k<<<NATOM,128,0,stream>>>(atom_table, comp_W, comp_b, pdd_b, atom_emb);
  embed_k<<<NTOK,128,0,stream>>>(str_fea, comp_fea, atom_emb, pdd_W, x, x_init, w);
  for (int i=0;i<LL;i++){
    const float* gi = enc_ln_g + i*EE;
    const float* bi = enc_ln_b + i*EE;
    // ln1: only layer 0 (later layers get xn from ln_dual)
    if (i==0) ln_k<true><<<NTOK/4,256,0,stream>>>(x, nullptr, gi, bi, xn_bf);
    // weight prep
    tconvT_k<<<dim3(3*EHH/32, EE/32),256,0,stream>>>(
        qkv_W + (size_t)i*EE*3*EHH, qkvWT, EE, 3*EHH);
    tconvT_k<<<dim3(EE/32, EE/32),256,0,stream>>>(
        ffn_W + (size_t)i*EE*EE, ffnWT, EE, EE);
    cconv_k<<<(EHH*EHH+255)/256,256,0,stream>>>(
        o_W + (size_t)i*EHH*EHH, oWb, EHH*EHH);
    tconvT_k<<<dim3(EE/32, EHH/32),256,0,stream>>>(
        out_W + (size_t)i*EHH*EE, outWT, EHH, EE);
    mgemm_k<4,64,128><<<dim3(1, EHH/64),256,0,stream>>>(
        oWb, outWT, nullptr, nullptr, fwT, EE, EHH, EHH, nullptr, nullptr, nullptr);
    fuse_b_k<<<1,128,0,stream>>>(
        o_b + (size_t)i*EHH, out_W + (size_t)i*EHH*EE, out_b + (size_t)i*EE, fb);
    for (int cb=0; cb<NCHUNK; cb++){
      const int t0 = cb*CTOK;
      const int b0 = cb*CB;
      mgemm_k<0,128,128><<<dim3(3*EHH/128, CTOK/128),256,0,stream>>>(
          xn_bf + (size_t)t0*EE, qkvWT, qkv_b + (size_t)i*3*EHH, nullptr,
          qkvc, 3*EHH, EE, 0, nullptr, nullptr, nullptr);
      // attention: grid (bl, h, qt) => all blocks of one batch on one XCD
      attn_mf_k<<<dim3(CB, HH, SEQ/64),256,0,stream>>>(
          qkvc, w, vals_bf + (size_t)t0*EHH, b0);
    }
    // proj + resid + fused LN -> out1 (f32) + xn_bf
    mgemm_k<5,64,128><<<dim3(1, NTOK/64),256,0,stream>>>(
        vals_bf, fwT, fb, x, out1, EE, EHH, 0, xn_bf, gi, bi);
    // ffn + mish -> out2
    mgemm_k<3,64,128><<<dim3(1, NTOK/64),256,0,stream>>>(
        xn_bf, ffnWT, ffn_b + (size_t)i*EE, nullptr, out2, EE, EE, 0,
        nullptr, nullptr, nullptr);
    // x = LN(out1+out2, g_i); xn = LN(x, g_{i+1}) for next layer
    const float* gn = (i<LL-1) ? enc_ln_g + (i+1)*EE : gi;
    const float* bn = (i<LL-1) ? enc_ln_b + (i+1)*EE : bi;
    ln_dual_k<<<NTOK/4,256,0,stream>>>(out1, out2, gi, bi, gn, bn, x, xn_bf);
  }
  pool1_k<<<BB*4,128,0,stream>>>(x, x_init, w, part);
  pool2_k<<<BB,128,0,stream>>>(part, ln2_g, ln2_b, head_W, head_b, out);
}

// Round 14
// 1072.299 us; speedup vs baseline: 20.2220x; 1.1735x over previous
//
#include <hip/hip_runtime.h>
#include <math.h>

#define DI __device__ __forceinline__

// ---- problem constants ----
#define BB 32
#define SEQ 512
#define KF 101
#define EE 128
#define HH 8
#define EHH 1024
#define LL 3
#define ADIM 200
#define NATOM 119
#define NTOK (BB*SEQ)   // 16384
#define CB 8            // batches per chunk
#define NCHUNK (BB/CB)  // 4
#define CTOK (CB*SEQ)   // 4096 tokens per chunk

// R13 post-mortem: proj EPI5 45.6us x3 at 10% occupancy (grid 256 = 1
// block/CU, all pipes idle). R14: BM=32 tiles for proj/FFN (grid 512,
// 2 blocks/CU, bitwise-same accumulation), weight prep hoisted+batched
// across layers (grid.z strides), fuse GEMM 16->96 blocks. Attention
// unchanged (R13's XCD-local grid kept).

typedef unsigned short u16;
typedef __attribute__((ext_vector_type(8))) short bf16x8;
typedef __attribute__((ext_vector_type(4))) float f32x4;

DI float bf2f(u16 s){ union{unsigned int u; float f;} x; x.u = ((unsigned int)s)<<16; return x.f; }
DI u16 f2bf(float f){
  union{float f; unsigned int u;} x; x.f = f;
  unsigned int u = x.u;
  u += 0x7fffu + ((u>>16)&1u);           // RNE
  return (u16)(u>>16);
}

// =================== sentinel ===================
__global__ void sentinel_k(float* out, float v, int n){
  int i = blockIdx.x*64 + threadIdx.x;
  if (i < n) out[i] = v;
}

// =================== atom embedding precompute ===================
__global__ __launch_bounds__(128) void atomemb_k(
    const float* __restrict__ atom_table, const float* __restrict__ comp_W,
    const float* __restrict__ comp_b, const float* __restrict__ pdd_b,
    float* __restrict__ atom_emb)
{
  const int a = blockIdx.x;      // 0..NATOM-1
  const int e = threadIdx.x;
  __shared__ float sAtom[ADIM];
  for (int d=e; d<ADIM; d+=128) sAtom[d] = atom_table[a*ADIM+d];
  __syncthreads();
  float acc = comp_b[e] + pdd_b[e];
  #pragma unroll 4
  for (int d=0; d<ADIM; d++) acc = fmaf(sAtom[d], comp_W[d*EE+e], acc);
  atom_emb[a*EE+e] = acc;
}

// =================== embed: x = atom_emb[idx] + str[1:]@pdd_W ===================
__global__ __launch_bounds__(128) void embed_k(
    const float* __restrict__ str_fea, const int* __restrict__ comp_fea,
    const float* __restrict__ atom_emb, const float* __restrict__ pdd_W,
    float* __restrict__ x, float* __restrict__ x_init, float* __restrict__ w)
{
  const int t = blockIdx.x;
  const int e = threadIdx.x;
  __shared__ float sStr[104];
  if (e < KF) sStr[e] = str_fea[(size_t)t*KF+e];
  __syncthreads();
  const int idx = comp_fea[t];
  float a0 = atom_emb[idx*EE+e], a1 = 0.f, a2 = 0.f, a3 = 0.f;
  #pragma unroll
  for (int j=0; j<100; j+=4){
    a0 = fmaf(sStr[1+j],   pdd_W[(j  )*EE+e], a0);
    a1 = fmaf(sStr[2+j],   pdd_W[(j+1)*EE+e], a1);
    a2 = fmaf(sStr[3+j],   pdd_W[(j+2)*EE+e], a2);
    a3 = fmaf(sStr[4+j],   pdd_W[(j+3)*EE+e], a3);
  }
  const float acc = (a0+a1)+(a2+a3);
  x[(size_t)t*EE+e] = acc;
  x_init[(size_t)t*EE+e] = acc;
  if (e==0) w[t] = sStr[0];
}

// =================== layernorm: wave per token ===================
template<bool OBF>
__global__ __launch_bounds__(256) void ln_k(
    const float* __restrict__ in, const float* __restrict__ add,
    const float* __restrict__ g, const float* __restrict__ bta,
    void* __restrict__ outv)
{
  const int wv = threadIdx.x >> 6, lane = threadIdx.x & 63;
  const int t = blockIdx.x*4 + wv;
  float2 v = ((const float2*)(in + (size_t)t*EE))[lane];
  if (add){
    const float2 a = ((const float2*)(add + (size_t)t*EE))[lane];
    v.x += a.x; v.y += a.y;
  }
  float s = v.x + v.y;
  #pragma unroll
  for (int off=32; off; off>>=1) s += __shfl_xor(s, off);
  const float mean = s*(1.0f/128.0f);
  const float d0 = v.x-mean, d1 = v.y-mean;
  float q = d0*d0 + d1*d1;
  #pragma unroll
  for (int off=32; off; off>>=1) q += __shfl_xor(q, off);
  const float rstd = rsqrtf(q*(1.0f/128.0f) + 1e-5f);
  const float2 gg = ((const float2*)g)[lane];
  const float2 bb = ((const float2*)bta)[lane];
  const float r0 = d0*rstd*gg.x + bb.x;
  const float r1 = d1*rstd*gg.y + bb.y;
  if constexpr (OBF){
    u16* o = (u16*)outv + (size_t)t*EE + lane*2;
    o[0] = f2bf(r0); o[1] = f2bf(r1);
  } else {
    float2* o = (float2*)((float*)outv + (size_t)t*EE);
    o[lane] = make_float2(r0, r1);
  }
}

// =================== dual layernorm ===================
__global__ __launch_bounds__(256) void ln_dual_k(
    const float* __restrict__ in, const float* __restrict__ add,
    const float* __restrict__ g1, const float* __restrict__ b1,
    const float* __restrict__ g2, const float* __restrict__ b2,
    float* __restrict__ xout, u16* __restrict__ xnout)
{
  const int wv = threadIdx.x >> 6, lane = threadIdx.x & 63;
  const int t = blockIdx.x*4 + wv;
  float2 v = ((const float2*)(in + (size_t)t*EE))[lane];
  const float2 a = ((const float2*)(add + (size_t)t*EE))[lane];
  v.x += a.x; v.y += a.y;
  float s = v.x + v.y;
  #pragma unroll
  for (int off=32; off; off>>=1) s += __shfl_xor(s, off);
  float mean = s*(1.0f/128.0f);
  float d0 = v.x-mean, d1 = v.y-mean;
  float q = d0*d0 + d1*d1;
  #pragma unroll
  for (int off=32; off; off>>=1) q += __shfl_xor(q, off);
  float rstd = rsqrtf(q*(1.0f/128.0f) + 1e-5f);
  const float2 gg1 = ((const float2*)g1)[lane];
  const float2 bb1 = ((const float2*)b1)[lane];
  const float x0 = d0*rstd*gg1.x + bb1.x;
  const float x1 = d1*rstd*gg1.y + bb1.y;
  ((float2*)(xout + (size_t)t*EE))[lane] = make_float2(x0, x1);
  s = x0 + x1;
  #pragma unroll
  for (int off=32; off; off>>=1) s += __shfl_xor(s, off);
  mean = s*(1.0f/128.0f);
  d0 = x0-mean; d1 = x1-mean;
  q = d0*d0 + d1*d1;
  #pragma unroll
  for (int off=32; off; off>>=1) q += __shfl_xor(q, off);
  rstd = rsqrtf(q*(1.0f/128.0f) + 1e-5f);
  const float2 gg2 = ((const float2*)g2)[lane];
  const float2 bb2 = ((const float2*)b2)[lane];
  u16* o = xnout + (size_t)t*EE + lane*2;
  o[0] = f2bf(d0*rstd*gg2.x + bb2.x);
  o[1] = f2bf(d1*rstd*gg2.y + bb2.y);
}

// =================== coalesced convert: f32 -> bf16 ===================
__global__ __launch_bounds__(256) void cconv_k(
    const float* __restrict__ W, u16* __restrict__ Wb, int n)
{
  const int i = blockIdx.x*256 + threadIdx.x;
  if (i < n) Wb[i] = f2bf(W[i]);
}

// =================== LDS-tiled transpose convert, layer-batched via z ===================
__global__ __launch_bounds__(256) void tconvT_k(
    const float* __restrict__ W, u16* __restrict__ WT, int Kk, int Nn,
    size_t sW, size_t sWT)
{
  W  += (size_t)blockIdx.z*sW;
  WT += (size_t)blockIdx.z*sWT;
  __shared__ u16 tile[32][33];
  const int n0 = blockIdx.x*32, k0 = blockIdx.y*32;
  const int lr = threadIdx.x >> 5, lc = threadIdx.x & 31;
  #pragma unroll
  for (int i=0;i<4;i++){
    const int k = k0 + lr + i*8;
    tile[lr+i*8][lc] = f2bf(W[(size_t)k*Nn + n0 + lc]);
  }
  __syncthreads();
  #pragma unroll
  for (int i=0;i<4;i++){
    const int n = n0 + lr + i*8;
    WT[(size_t)n*Kk + k0 + lc] = tile[lc][lr+i*8];
  }
}

// =================== MFMA bf16 GEMM (layer-batched via z strides) ===================
// A: M x Kk bf16 row-major. BT: Nn x Kk bf16 (pre-transposed B).
// EPI 0: store bf16; 2: f32 +resid; 3: f32 mish; 4: bf16 transposed store
// (no bias); EPI 5 (BM<=64, BN=Nn=128): v=acc+bias+resid -> C f32 AND
// row-LN(v)*lng+lnb -> C2 bf16.
template<int EPI, int BM, int BN>
__global__ __launch_bounds__(256) void mgemm_k(
    const u16* __restrict__ A, const u16* __restrict__ BT,
    const float* __restrict__ bias, const float* __restrict__ resid,
    void* __restrict__ Cv, int Nn, int Kk, int Mdim,
    void* __restrict__ C2, const float* __restrict__ lng,
    const float* __restrict__ lnb,
    size_t sA, size_t sBT, size_t sCb)
{
  const int lz = blockIdx.z;
  A  += (size_t)lz*sA;
  BT += (size_t)lz*sBT;
  void* C = (void*)((char*)Cv + (size_t)lz*sCb);

  constexpr int BK  = 64;
  constexpr int LDK = BK + 8;
  __shared__ u16 As[BM*LDK];
  __shared__ u16 Bs[BN*LDK];
  const int tid = threadIdx.x;
  const int m0 = blockIdx.y*BM, n0 = blockIdx.x*BN;
  constexpr int WMN = (BM>=128)?2:1;
  constexpr int WNN = 4/WMN;
  constexpr int WM = BM/WMN;
  constexpr int WN = BN/WNN;
  constexpr int FM = WM/16, FN = WN/16;
  const int wv = tid>>6, lane = tid&63;
  const int wm = (wv/WNN)*WM;
  const int wn = (wv%WNN)*WN;
  const int lm = lane&15, lq = lane>>4;

  f32x4 acc[FM][FN];
  #pragma unroll
  for (int i=0;i<FM;i++)
    #pragma unroll
    for (int j=0;j<FN;j++) acc[i][j] = (f32x4){0.f,0.f,0.f,0.f};

  constexpr int ACH = BM*BK/8;
  constexpr int BCH = BN*BK/8;

  for (int k0=0; k0<Kk; k0+=BK){
    #pragma unroll
    for (int c = tid; c < ACH; c += 256){
      const int r = c/(BK/8), kg = c - r*(BK/8);
      const float4 v = *(const float4*)(A + (size_t)(m0+r)*Kk + k0 + kg*8);
      *(float4*)&As[r*LDK + kg*8] = v;
    }
    #pragma unroll
    for (int c = tid; c < BCH; c += 256){
      const int r = c/(BK/8), kg = c - r*(BK/8);
      const float4 v = *(const float4*)(BT + (size_t)(n0+r)*Kk + k0 + kg*8);
      *(float4*)&Bs[r*LDK + kg*8] = v;
    }
    __syncthreads();
    #pragma unroll
    for (int kk=0; kk<BK/32; kk++){
      bf16x8 af[FM], bfr[FN];
      #pragma unroll
      for (int i=0;i<FM;i++)
        af[i] = *(const bf16x8*)&As[(wm + i*16 + lm)*LDK + kk*32 + lq*8];
      #pragma unroll
      for (int j=0;j<FN;j++)
        bfr[j] = *(const bf16x8*)&Bs[(wn + j*16 + lm)*LDK + kk*32 + lq*8];
      #pragma unroll
      for (int i=0;i<FM;i++)
        #pragma unroll
        for (int j=0;j<FN;j++)
          acc[i][j] = __builtin_amdgcn_mfma_f32_16x16x32_bf16(af[i], bfr[j], acc[i][j], 0, 0, 0);
    }
    __syncthreads();
  }
  if constexpr (EPI==5){
    // fused proj + residual + row-LN (wm==0, BN=Nn=128)
    float vout[FM][FN][4];
    float ps[FM][4], qs[FM][4];
    #pragma unroll
    for (int i=0;i<FM;i++)
      #pragma unroll
      for (int r=0;r<4;r++){ ps[i][r]=0.f; qs[i][r]=0.f; }
    #pragma unroll
    for (int i=0;i<FM;i++){
      #pragma unroll
      for (int j=0;j<FN;j++){
        const int col = n0 + wn + j*16 + lm;
        const float bv = bias[col];
        #pragma unroll
        for (int r=0;r<4;r++){
          const int row = m0 + i*16 + lq*4 + r;
          const size_t gi = (size_t)row*Nn + col;
          const float v = acc[i][j][r] + bv + resid[gi];
          ((float*)C)[gi] = v;
          vout[i][j][r] = v;
          ps[i][r] += v; qs[i][r] += v*v;
        }
      }
    }
    float* sred = (float*)As;
    #pragma unroll
    for (int i=0;i<FM;i++)
      #pragma unroll
      for (int r=0;r<4;r++){
        float s = ps[i][r], q = qs[i][r];
        s += __shfl_xor(s,1); s += __shfl_xor(s,2); s += __shfl_xor(s,4); s += __shfl_xor(s,8);
        q += __shfl_xor(q,1); q += __shfl_xor(q,2); q += __shfl_xor(q,4); q += __shfl_xor(q,8);
        if (lm==0){
          const int row = i*16 + lq*4 + r;
          sred[row*4 + wv] = s;
          sred[BM*4 + row*4 + wv] = q;
        }
      }
    __syncthreads();
    #pragma unroll
    for (int i=0;i<FM;i++)
      #pragma unroll
      for (int r=0;r<4;r++){
        const int row = i*16 + lq*4 + r;
        const float s = sred[row*4+0]+sred[row*4+1]+sred[row*4+2]+sred[row*4+3];
        const float q = sred[BM*4+row*4+0]+sred[BM*4+row*4+1]+sred[BM*4+row*4+2]+sred[BM*4+row*4+3];
        const float mean = s*(1.0f/128.0f);
        const float var  = q*(1.0f/128.0f) - mean*mean;
        const float rstd = rsqrtf(var + 1e-5f);
        #pragma unroll
        for (int j=0;j<FN;j++){
          const int col = n0 + wn + j*16 + lm;
          const float xnv = (vout[i][j][r]-mean)*rstd*lng[col] + lnb[col];
          ((u16*)C2)[(size_t)(m0+row)*Nn + col] = f2bf(xnv);
        }
      }
  } else {
    #pragma unroll
    for (int i=0;i<FM;i++){
      #pragma unroll
      for (int j=0;j<FN;j++){
        const int col = n0 + wn + j*16 + lm;
        const float bv = (EPI==4) ? 0.f : bias[col];
        #pragma unroll
        for (int r=0;r<4;r++){
          const int row = m0 + wm + i*16 + lq*4 + r;
          float v = acc[i][j][r] + bv;
          if constexpr (EPI==4){
            ((u16*)C)[(size_t)col*Mdim + row] = f2bf(v);
          } else {
            const size_t gi = (size_t)row*Nn + col;
            if constexpr (EPI==0)      ((u16*)C)[gi] = f2bf(v);
            else if constexpr (EPI==2) ((float*)C)[gi] = v + resid[gi];
            else { const float sp=(v>20.f)?v:log1pf(expf(v)); ((float*)C)[gi]=v*tanhf(sp); }
          }
        }
      }
    }
  }
}

// =================== fb = o_b@out_W + out_b (layer-batched) ===================
__global__ __launch_bounds__(128) void fuse_b_k(
    const float* __restrict__ ob, const float* __restrict__ outW,
    const float* __restrict__ outb, float* __restrict__ fb)
{
  const int ly = blockIdx.x;
  ob   += (size_t)ly*EHH;
  outW += (size_t)ly*EHH*EE;
  outb += (size_t)ly*EE;
  fb   += (size_t)ly*EE;
  const int n = threadIdx.x;
  float acc = outb[n];
  for (int k2=0;k2<EHH;k2++) acc = fmaf(ob[k2], outW[(size_t)k2*EE+n], acc);
  fb[n] = acc;
}

// =================== MFMA flash attention (XCD-local grid: bl,h,qt) ===================
__global__ __launch_bounds__(256) void attn_mf_k(
    const u16* __restrict__ qkvc, const float* __restrict__ w,
    u16* __restrict__ vals_c, int b0)
{
  const int bl = blockIdx.x;   // id%8 = bl -> one XCD per batch
  const int h  = blockIdx.y;
  const int qt = blockIdx.z;
  const int tid = threadIdx.x;
  const int wv = tid>>6, lane = tid&63;
  const int lm = lane&15, lq = lane>>4;

  __shared__ u16 Qs[64][136];
  __shared__ u16 Ks[64][136];
  __shared__ u16 Vts[128][72];
  __shared__ u16 Ps[64][72];
  __shared__ float wt[64], qwt[64];

  const size_t rs = 3072;
  const u16* base = qkvc + (size_t)bl*SEQ*rs + (size_t)h*384;
  const int q0 = qt*64;

  #pragma unroll
  for (int it=0; it<4; it++){
    const int fi = it*256 + tid;
    const int r = fi >> 4, g = fi & 15;
    *(float4*)&Qs[r][g*8] = *(const float4*)(base + (size_t)(q0+r)*rs + g*8);
  }
  if (tid < 64) qwt[tid] = w[(b0+bl)*SEQ + q0 + tid];
  __syncthreads();

  float kq[4];
  #pragma unroll
  for (int r=0;r<4;r++) kq[r] = qwt[wv*16 + lq*4 + r];

  f32x4 oacc[8];
  #pragma unroll
  for (int j=0;j<8;j++) oacc[j] = (f32x4){0.f,0.f,0.f,0.f};
  float mrow[4], lrow[4];
  #pragma unroll
  for (int r=0;r<4;r++){ mrow[r]=-INFINITY; lrow[r]=0.f; }
  const float scale = 0.08838834764831845f;  // 1/sqrt(128)

  for (int kt=0; kt<8; kt++){
    __syncthreads();
    #pragma unroll
    for (int it=0; it<4; it++){
      const int fi = it*256 + tid;
      const int r = fi >> 4, g = fi & 15;
      *(float4*)&Ks[r][g*8] = *(const float4*)(base + (size_t)(kt*64+r)*rs + 128 + g*8);
    }
    #pragma unroll
    for (int it=0; it<4; it++){
      const int fi = it*256 + tid;
      const int k = fi & 63, dg = fi >> 6;
      union { float4 f4; u16 u[8]; } cv;
      cv.f4 = *(const float4*)(base + (size_t)(kt*64+k)*rs + 256 + dg*8);
      #pragma unroll
      for (int e=0;e<8;e++) Vts[dg*8+e][k] = cv.u[e];
    }
    if (tid < 64) wt[tid] = w[(b0+bl)*SEQ + kt*64 + tid];
    __syncthreads();

    f32x4 sacc[4];
    #pragma unroll
    for (int j=0;j<4;j++) sacc[j] = (f32x4){0.f,0.f,0.f,0.f};
    #pragma unroll
    for (int kk=0; kk<4; kk++){
      const bf16x8 af = *(const bf16x8*)&Qs[wv*16+lm][kk*32+lq*8];
      #pragma unroll
      for (int j=0;j<4;j++){
        const bf16x8 bf = *(const bf16x8*)&Ks[j*16+lm][kk*32+lq*8];
        sacc[j] = __builtin_amdgcn_mfma_f32_16x16x32_bf16(af, bf, sacc[j], 0, 0, 0);
      }
    }
    float wkj[4], s[4][4];
    #pragma unroll
    for (int j=0;j<4;j++) wkj[j] = wt[j*16+lm];
    #pragma unroll
    for (int j=0;j<4;j++)
      #pragma unroll
      for (int r=0;r<4;r++){
        const bool keep = (kq[r] > 0.f) && (wkj[j] > 0.f);
        s[j][r] = keep ? sacc[j][r]*scale : -9.0e15f;
      }
    float alpha[4];
    #pragma unroll
    for (int r=0;r<4;r++){
      float rm = fmaxf(fmaxf(s[0][r], s[1][r]), fmaxf(s[2][r], s[3][r]));
      rm = fmaxf(rm, __shfl_xor(rm, 1));
      rm = fmaxf(rm, __shfl_xor(rm, 2));
      rm = fmaxf(rm, __shfl_xor(rm, 4));
      rm = fmaxf(rm, __shfl_xor(rm, 8));
      const float newm = fmaxf(mrow[r], rm);
      alpha[r] = expf(mrow[r] - newm);
      float ls = 0.f;
      #pragma unroll
      for (int j=0;j<4;j++){
        const float pv = wkj[j]*expf(s[j][r]-newm);
        s[j][r] = pv; ls += pv;
      }
      ls += __shfl_xor(ls, 1);
      ls += __shfl_xor(ls, 2);
      ls += __shfl_xor(ls, 4);
      ls += __shfl_xor(ls, 8);
      lrow[r] = lrow[r]*alpha[r] + ls;
      mrow[r] = newm;
    }
    #pragma unroll
    for (int j=0;j<4;j++)
      #pragma unroll
      for (int r=0;r<4;r++)
        Ps[wv*16 + lq*4 + r][j*16+lm] = f2bf(s[j][r]);
    #pragma unroll
    for (int j=0;j<8;j++)
      #pragma unroll
      for (int r=0;r<4;r++) oacc[j][r] *= alpha[r];
    __syncthreads();

    #pragma unroll
    for (int kk=0; kk<2; kk++){
      const bf16x8 pf = *(const bf16x8*)&Ps[wv*16+lm][kk*32+lq*8];
      #pragma unroll
      for (int j=0;j<8;j++){
        const bf16x8 vf = *(const bf16x8*)&Vts[j*16+lm][kk*32+lq*8];
        oacc[j] = __builtin_amdgcn_mfma_f32_16x16x32_bf16(pf, vf, oacc[j], 0, 0, 0);
      }
    }
  }
  #pragma unroll
  for (int r=0;r<4;r++){
    const float inv = 1.0f / lrow[r];
    u16* orow = vals_c + ((size_t)(bl*SEQ + q0 + wv*16 + lq*4 + r))*EHH + h*EE;
    #pragma unroll
    for (int j=0;j<8;j++) orow[j*16+lm] = f2bf(oacc[j][r]*inv);
  }
}

// =================== pool phase 1: partial weighted sums ===================
__global__ __launch_bounds__(128) void pool1_k(
    const float* __restrict__ x, const float* __restrict__ x_init,
    const float* __restrict__ w, float* __restrict__ part)
{
  const int bc = blockIdx.x;          // b*4 + c
  const int b = bc >> 2, c = bc & 3;
  const int e = threadIdx.x;
  float acc = 0.f;
  const int n0 = c*128;
  for (int n=0;n<128;n++){
    const int tok = b*SEQ + n0 + n;
    const size_t idx = (size_t)tok*EE + e;
    acc = fmaf(w[tok], x[idx]+x_init[idx], acc);
  }
  part[(size_t)bc*EE + e] = acc;
}

// =================== pool phase 2: sum parts + LN + head ===================
__global__ __launch_bounds__(128) void pool2_k(
    const float* __restrict__ part, const float* __restrict__ g2,
    const float* __restrict__ b2, const float* __restrict__ head_W,
    const float* __restrict__ head_b, float* __restrict__ out)
{
  const int b = blockIdx.x;
  const int e = threadIdx.x;
  __shared__ float red[128];
  float acc = part[(size_t)(b*4+0)*EE+e] + part[(size_t)(b*4+1)*EE+e]
            + part[(size_t)(b*4+2)*EE+e] + part[(size_t)(b*4+3)*EE+e];
  red[e]=acc; __syncthreads();
  for (int s=64;s>0;s>>=1){ if(e<s) red[e]+=red[e+s]; __syncthreads(); }
  const float mean = red[0]*(1.0f/128.0f);
  __syncthreads();
  const float d = acc-mean;
  red[e]=d*d; __syncthreads();
  for (int s=64;s>0;s>>=1){ if(e<s) red[e]+=red[e+s]; __syncthreads(); }
  const float var = red[0]*(1.0f/128.0f);
  const float p = d*rsqrtf(var+1e-5f)*g2[e]+b2[e];
  __syncthreads();
  red[e] = p*head_W[e]; __syncthreads();
  for (int s=64;s>0;s>>=1){ if(e<s) red[e]+=red[e+s]; __syncthreads(); }
  if (e==0) out[b] = red[0] + head_b[0];
}

// =================== launch ===================
extern "C" void kernel_launch(void* const* d_in, const int* in_sizes, int n_in,
                              void* d_out, int out_size, void* d_ws, size_t ws_size,
                              hipStream_t stream)
{
  const float* str_fea   = (const float*)d_in[0];
  const int*   comp_fea  = (const int*)  d_in[1];
  // d_in[2] cell_fea unused by reference
  const float* atom_table= (const float*)d_in[3];
  const float* comp_W    = (const float*)d_in[4];
  const float* comp_b    = (const float*)d_in[5];
  const float* pdd_W     = (const float*)d_in[6];
  const float* pdd_b     = (const float*)d_in[7];
  const float* enc_ln_g  = (const float*)d_in[8];
  const float* enc_ln_b  = (const float*)d_in[9];
  const float* qkv_W     = (const float*)d_in[10];
  const float* qkv_b     = (const float*)d_in[11];
  const float* o_W       = (const float*)d_in[12];
  const float* o_b       = (const float*)d_in[13];
  const float* out_W     = (const float*)d_in[14];
  const float* out_b     = (const float*)d_in[15];
  const float* ffn_W     = (const float*)d_in[16];
  const float* ffn_b     = (const float*)d_in[17];
  const float* ln2_g     = (const float*)d_in[18];
  const float* ln2_b     = (const float*)d_in[19];
  const float* head_W    = (const float*)d_in[20];
  const float* head_b    = (const float*)d_in[21];
  float* out = (float*)d_out;

  // ---- diagnostic 1: input layout model ----
  bool sizes_ok = (n_in >= 22);
  if (sizes_ok){
    sizes_ok = in_sizes[0]==BB*SEQ*KF && in_sizes[1]==NTOK &&
               in_sizes[3]==NATOM*ADIM && in_sizes[4]==ADIM*EE &&
               in_sizes[10]==LL*EE*3*EHH && in_sizes[12]==LL*EHH*EHH &&
               in_sizes[14]==LL*EHH*EE   && in_sizes[16]==LL*EE*EE &&
               in_sizes[20]==EE;
  }
  if (!sizes_ok){
    sentinel_k<<<(out_size+63)/64,64,0,stream>>>(out, 99999.0f, out_size);
    return;
  }

  // ---- workspace layout (~107.2 MB; <= 109.7 MB proven) ----
  char* p = (char*)d_ws;
  size_t off = 0;
  auto alloc = [&](size_t bytes)->void*{
    off = (off + 255) & ~(size_t)255;
    void* r = p + off; off += bytes; return r;
  };
  float* w        = (float*)alloc((size_t)NTOK*4);
  float* x        = (float*)alloc((size_t)NTOK*EE*4);
  float* x_init   = (float*)alloc((size_t)NTOK*EE*4);
  u16*   xn_bf    = (u16*)  alloc((size_t)NTOK*EE*2);
  float* out1     = (float*)alloc((size_t)NTOK*EE*4);
  float* out2     = (float*)alloc((size_t)NTOK*EE*4);
  u16*   qkvc     = (u16*)  alloc((size_t)CTOK*3*EHH*2);   // 25.2 MB chunk
  u16*   vals_bf  = (u16*)  alloc((size_t)NTOK*EHH*2);     // 33.6 MB
  u16*   qkvWT_a  = (u16*)  alloc((size_t)LL*3*EHH*EE*2);  // 2.36 MB
  u16*   fwT_a    = (u16*)  alloc((size_t)LL*EE*EHH*2);    // 0.79 MB
  u16*   ffnWT_a  = (u16*)  alloc((size_t)LL*EE*EE*2);
  u16*   oWb_a    = (u16*)  alloc((size_t)LL*EHH*EHH*2);   // 6.29 MB
  u16*   outWT_a  = (u16*)  alloc((size_t)LL*EE*EHH*2);
  float* fb_a     = (float*)alloc((size_t)LL*EE*4);
  float* atom_emb = (float*)alloc((size_t)NATOM*EE*4);
  float* part     = (float*)alloc((size_t)BB*4*EE*4);

  // ---- diagnostic 2: workspace size ----
  if (off > ws_size){
    sentinel_k<<<(out_size+63)/64,64,0,stream>>>(out, 12345.0f, out_size);
    return;
  }

  // ---- hoisted weight prep (all layers, batched) ----
  tconvT_k<<<dim3(3*EHH/32, EE/32, LL),256,0,stream>>>(
      qkv_W, qkvWT_a, EE, 3*EHH, (size_t)EE*3*EHH, (size_t)3*EHH*EE);
  tconvT_k<<<dim3(EE/32, EE/32, LL),256,0,stream>>>(
      ffn_W, ffnWT_a, EE, EE, (size_t)EE*EE, (size_t)EE*EE);
  cconv_k<<<(LL*EHH*EHH+255)/256,256,0,stream>>>(o_W, oWb_a, LL*EHH*EHH);
  tconvT_k<<<dim3(EE/32, EHH/32, LL),256,0,stream>>>(
      out_W, outWT_a, EHH, EE, (size_t)EHH*EE, (size_t)EE*EHH);
  // fwT = (o_W @ out_W)^T per layer (EPI4 transposed store), grid.z = layers
  mgemm_k<4,32,128><<<dim3(1, EHH/32, LL),256,0,stream>>>(
      oWb_a, outWT_a, nullptr, nullptr, fwT_a, EE, EHH, EHH,
      nullptr, nullptr, nullptr,
      (size_t)EHH*EHH, (size_t)EE*EHH, (size_t)EE*EHH*2);
  fuse_b_k<<<LL,128,0,stream>>>(o_b, out_W, out_b, fb_a);

  atomemb_k<<<NATOM,128,0,stream>>>(atom_table, comp_W, comp_b, pdd_b, atom_emb);
  embed_k<<<NTOK,128,0,stream>>>(str_fea, comp_fea, atom_emb, pdd_W, x, x_init, w);

  for (int i=0;i<LL;i++){
    const float* gi = enc_ln_g + i*EE;
    const float* bi = enc_ln_b + i*EE;
    if (i==0) ln_k<true><<<NTOK/4,256,0,stream>>>(x, nullptr, gi, bi, xn_bf);
    for (int cb=0; cb<NCHUNK; cb++){
      const int t0 = cb*CTOK;
      const int b0 = cb*CB;
      mgemm_k<0,128,128><<<dim3(3*EHH/128, CTOK/128),256,0,stream>>>(
          xn_bf + (size_t)t0*EE, qkvWT_a + (size_t)i*3*EHH*EE,
          qkv_b + (size_t)i*3*EHH, nullptr,
          qkvc, 3*EHH, EE, 0, nullptr, nullptr, nullptr, 0, 0, 0);
      attn_mf_k<<<dim3(CB, HH, SEQ/64),256,0,stream>>>(
          qkvc, w, vals_bf + (size_t)t0*EHH, b0);
    }
    // proj + resid + fused LN -> out1 (f32) + xn_bf   [BM=32, grid 512]
    mgemm_k<5,32,128><<<dim3(1, NTOK/32),256,0,stream>>>(
        vals_bf, fwT_a + (size_t)i*EE*EHH, fb_a + (size_t)i*EE, x,
        out1, EE, EHH, 0, xn_bf, gi, bi, 0, 0, 0);
    // ffn + mish -> out2   [BM=32, grid 512]
    mgemm_k<3,32,128><<<dim3(1, NTOK/32),256,0,stream>>>(
        xn_bf, ffnWT_a + (size_t)i*EE*EE, ffn_b + (size_t)i*EE, nullptr,
        out2, EE, EE, 0, nullptr, nullptr, nullptr, 0, 0, 0);
    const float* gn = (i<LL-1) ? enc_ln_g + (i+1)*EE : gi;
    const float* bn = (i<LL-1) ? enc_ln_b + (i+1)*EE : bi;
    ln_dual_k<<<NTOK/4,256,0,stream>>>(out1, out2, gi, bi, gn, bn, x, xn_bf);
  }
  pool1_k<<<BB*4,128,0,stream>>>(x, x_init, w, part);
  pool2_k<<<BB,128,0,stream>>>(part, ln2_g, ln2_b, head_W, head_b, out);
}